// Round 6
// baseline (1597.490 us; speedup 1.0000x reference)
//
#include <hip/hip_runtime.h>
#include <hip/hip_bf16.h>

typedef __hip_bfloat16 bf16;
#define TPB 256

__device__ __forceinline__ float toF(float v){ return v; }
__device__ __forceinline__ float toF(bf16 v){ return __bfloat162float(v); }
__device__ __forceinline__ float bfu(unsigned short u){
    unsigned int x = ((unsigned int)u) << 16;
    return __uint_as_float(x);
}
template<typename T> __device__ __forceinline__ void stT(T* p, long i, float v);
template<> __device__ __forceinline__ void stT<float>(float* p, long i, float v){ p[i] = v; }
template<> __device__ __forceinline__ void stT<bf16>(bf16* p, long i, float v){ p[i] = __float2bfloat16(v); }

__device__ __forceinline__ void st4bf(bf16* p, const float* a){
    bf16 t0 = __float2bfloat16(a[0]);
    bf16 t1 = __float2bfloat16(a[1]);
    bf16 t2 = __float2bfloat16(a[2]);
    bf16 t3 = __float2bfloat16(a[3]);
    ushort4 pk;
    pk.x = *(unsigned short*)&t0;
    pk.y = *(unsigned short*)&t1;
    pk.z = *(unsigned short*)&t2;
    pk.w = *(unsigned short*)&t3;
    *(ushort4*)p = pk;
}

static inline int nblk(long n){ return (int)((n + TPB - 1) / TPB); }

// ================= dtype detection + stat zero =================
__global__ void k_detect(const void* hr, int n, int* flag, float* stat)
{
    if (threadIdx.x < 64) stat[threadIdx.x] = 0.f;
    const unsigned short* u = (const unsigned short*)hr;
    int nan = 0, oz = 0, ot = 0;
    for (int i = threadIdx.x; i < n; i += TPB) {
        unsigned short a = u[i] & 0x7FFF;
        if (a >= 0x7F80) nan++;
        if (i & 1) { ot++; if (a == 0) oz++; }
    }
    __shared__ int s1[TPB], s2[TPB], s3[TPB];
    s1[threadIdx.x] = nan; s2[threadIdx.x] = oz; s3[threadIdx.x] = ot;
    __syncthreads();
    if (threadIdx.x == 0) {
        int a = 0, b = 0, c = 0;
        for (int i = 0; i < TPB; i++) { a += s1[i]; b += s2[i]; c += s3[i]; }
        *flag = (a >= 6 || (long)b * 10 >= (long)c * 9) ? 1 : 0;
    }
}

// ================= weight prep: fp32 + transpose to [ci][co][taps] =================
#define P_W_HRC 0
#define P_B_HRC 16384
#define P_W_LRC 16448
#define P_B_LRC 32832
#define P_W_ENC 32896
#define P_B_ENC 47296
#define P_W_ENC2 47321
#define P_B_ENC2 52505
#define P_GNHW 52514
#define P_GNHB 52578
#define P_GNLW 52642
#define P_GNLB 52706
#define P_W_OFF 52770
#define P_B_OFF 55074
#define P_W_HOFF 55106
#define P_B_HOFF 55682
#define P_W_DS 55690
#define P_B_DS 74122
#define P_W_HDS 74154
#define P_B_HDS 78762
#define P_TOT 78770

__constant__ int c_segsz[20]  = {16384,64,16384,64,14400,25,5184,9,64,64,64,64,2304,32,576,8,18432,32,4608,8};
__constant__ int c_segbase[20]= {P_W_HRC,P_B_HRC,P_W_LRC,P_B_LRC,P_W_ENC,P_B_ENC,P_W_ENC2,P_B_ENC2,
                                 P_GNHW,P_GNHB,P_GNLW,P_GNLB,P_W_OFF,P_B_OFF,P_W_HOFF,P_B_HOFF,
                                 P_W_DS,P_B_DS,P_W_HDS,P_B_HDS};
__constant__ int c_segcin[20] = {256,0,256,0, 64,0, 64,0, 0,0,0,0, 8,0, 8,0, 64,0, 64,0};
__constant__ int c_segcout[20]= { 64,0, 64,0, 25,0,  9,0, 0,0,0,0,32,0, 8,0, 32,0,  8,0};
__constant__ int c_segtap[20] = {  1,0,  1,0,  9,0,  9,0, 0,0,0,0, 9,0, 9,0,  9,0,  9,0};

__global__ void k_prep(const void* p0,const void* p1,const void* p2,const void* p3,
                       const void* p4,const void* p5,const void* p6,const void* p7,
                       const void* p8,const void* p9,const void* p10,const void* p11,
                       const void* p12,const void* p13,const void* p14,const void* p15,
                       const void* p16,const void* p17,const void* p18,const void* p19,
                       float* dst, const int* flag)
{
    int idx = blockIdx.x * TPB + threadIdx.x;
    if (idx >= P_TOT) return;
    int s = 0, off = idx;
    while (off >= c_segsz[s]) { off -= c_segsz[s]; s++; }
    const void* sp;
    switch (s) {
        case 0: sp=p0; break;  case 1: sp=p1; break;  case 2: sp=p2; break;  case 3: sp=p3; break;
        case 4: sp=p4; break;  case 5: sp=p5; break;  case 6: sp=p6; break;  case 7: sp=p7; break;
        case 8: sp=p8; break;  case 9: sp=p9; break;  case 10: sp=p10; break; case 11: sp=p11; break;
        case 12: sp=p12; break; case 13: sp=p13; break; case 14: sp=p14; break; case 15: sp=p15; break;
        case 16: sp=p16; break; case 17: sp=p17; break; case 18: sp=p18; break; default: sp=p19; break;
    }
    float v = (*flag) ? ((const float*)sp)[off] : toF(((const bf16*)sp)[off]);
    int doff = off;
    int cin = c_segcin[s];
    if (cin) {
        int t = c_segtap[s], cout = c_segcout[s];
        int co = off / (cin * t);
        int r  = off % (cin * t);
        int ci = r / t, k = r % t;
        doff = (ci * cout + co) * t + k;
    }
    dst[c_segbase[s] + doff] = v;
}

// ================= lr_feat transpose: [b][256][4096] -> bf16 [b][4096][256] =============
template<typename T>
__device__ void transpLR_body(const T* __restrict__ x, bf16* __restrict__ xT, int Bn)
{
    __shared__ float tile[64][65];
    int bid = blockIdx.x;                 // b * 4 cgroup * 64 pgroup
    int pg = bid & 63;
    int cg = (bid >> 6) & 3;
    int b  = bid >> 8;
    int tid = threadIdx.x;
    int tr = tid >> 6, tc = tid & 63;
    for (int i = 0; i < 16; i++) {
        int c = tr + i * 4;
        tile[c][tc] = toF(x[(((long)(b * 256 + cg * 64 + c)) << 12) + (pg << 6) + tc]);
    }
    __syncthreads();
    for (int i = 0; i < 16; i++) {
        int p = tr + i * 4;
        xT[((((long)b << 12) + (pg << 6) + p) << 8) + (cg << 6) + tc] = __float2bfloat16(tile[tc][p]);
    }
}
__global__ void k_transpLR(const void* x, bf16* xT, int Bn, const int* flag)
{
    if (*flag) transpLR_body<float>((const float*)x, xT, Bn);
    else       transpLR_body<bf16 >((const bf16*)x,  xT, Bn);
}

// ===== carafe5-up channels-last: wave = (b, ipix), lane = 4-channel group =====
__global__ void k_carafe5T(const bf16* __restrict__ featT, const float* __restrict__ mask,
                           bf16* __restrict__ outT, int Bn)
{
    int lane = threadIdx.x & 63;
    int nwg = gridDim.x;
    int bid = blockIdx.x;
    int swz = (nwg & 7) ? bid : ((bid & 7) * (nwg >> 3) + (bid >> 3));
    int wid = (swz << 2) | (threadIdx.x >> 6);
    wid = __builtin_amdgcn_readfirstlane(wid);
    if (wid >= Bn * 4096) return;
    int ipix = wid & 4095;
    int b    = wid >> 12;
    int h = ipix >> 6, w = ipix & 63;
    const bf16*  fb = featT + (((long)b << 12) << 8) + (lane << 2);
    const float* mb = mask + (((long)b * 25) << 14) + (h << 8) + (w << 1);
    float a00[4], a01[4], a10[4], a11[4];
    #pragma unroll
    for (int t = 0; t < 4; t++) { a00[t]=0.f; a01[t]=0.f; a10[t]=0.f; a11[t]=0.f; }
    #pragma unroll
    for (int k = 0; k < 25; k++) {
        const int i = k / 5, j = k % 5;
        int yy = h + i - 2, xx = w + j - 2;
        bool v = (yy >= 0 && yy < 64 && xx >= 0 && xx < 64);
        int yc = v ? yy : 0, xc = v ? xx : 0;
        ushort4 u = *(const ushort4*)(fb + ((long)((yc << 6) + xc) << 8));
        float2 mr0 = *(const float2*)(mb + ((long)k << 14));
        float2 mr1 = *(const float2*)(mb + ((long)k << 14) + 128);
        float m00 = v ? mr0.x : 0.f, m01 = v ? mr0.y : 0.f;
        float m10 = v ? mr1.x : 0.f, m11 = v ? mr1.y : 0.f;
        float f0 = bfu(u.x), f1 = bfu(u.y), f2 = bfu(u.z), f3 = bfu(u.w);
        a00[0] += f0*m00; a00[1] += f1*m00; a00[2] += f2*m00; a00[3] += f3*m00;
        a01[0] += f0*m01; a01[1] += f1*m01; a01[2] += f2*m01; a01[3] += f3*m01;
        a10[0] += f0*m10; a10[1] += f1*m10; a10[2] += f2*m10; a10[3] += f3*m10;
        a11[0] += f0*m11; a11[1] += f1*m11; a11[2] += f2*m11; a11[3] += f3*m11;
    }
    bf16* op = outT + (((long)(b << 14) + (h << 8) + (w << 1)) << 8) + (lane << 2);
    st4bf(op, a00);                       // (2h,   2w)
    st4bf(op + 256, a01);                 // (2h,   2w+1)
    st4bf(op + (128 << 8), a10);          // (2h+1, 2w)
    st4bf(op + (128 << 8) + 256, a11);    // (2h+1, 2w+1)
}

// ================= 3x3 conv partials (kept for CIN=8 steps 20/21) =================
template<int COUT>
__global__ void k_conv3x3p(const float* __restrict__ x, const float* __restrict__ wf,
                           float* __restrict__ pbuf, int Bn, int CIN, int H, int W, int CS)
{
    int HW = H * W;
    int idx = blockIdx.x * TPB + threadIdx.x;
    if (idx >= Bn * HW) return;
    int chunk = blockIdx.y;
    int pix = idx % HW, b = idx / HW;
    int wx = pix % W, hy = pix / W;
    int off[9]; float msk[9];
    #pragma unroll
    for (int i = 0; i < 3; i++) {
        int yy = hy + i - 1; bool vy = (yy >= 0 && yy < H); int yc = vy ? yy : hy;
        #pragma unroll
        for (int j = 0; j < 3; j++) {
            int xx = wx + j - 1; bool v = vy && (xx >= 0 && xx < W);
            int xc = (xx >= 0 && xx < W) ? xx : wx;
            off[i*3+j] = yc * W + xc; msk[i*3+j] = v ? 1.f : 0.f;
        }
    }
    float acc[COUT];
    #pragma unroll
    for (int co = 0; co < COUT; co++) acc[co] = 0.f;
    int c0 = chunk * CS;
    const float* xb = x + ((long)b * CIN + c0) * HW;
    const float* wb = wf + (long)c0 * COUT * 9;
    #pragma unroll 2
    for (int ci = 0; ci < CS; ci++) {
        const float* xc = xb + (long)ci * HW;
        float t[9];
        #pragma unroll
        for (int k = 0; k < 9; k++) t[k] = xc[off[k]] * msk[k];
        const float* wr = wb + (long)ci * COUT * 9;
        #pragma unroll
        for (int co = 0; co < COUT; co++) {
            const float* wp = wr + co * 9;
            acc[co] += t[0]*wp[0] + t[1]*wp[1] + t[2]*wp[2] + t[3]*wp[3] + t[4]*wp[4]
                     + t[5]*wp[5] + t[6]*wp[6] + t[7]*wp[7] + t[8]*wp[8];
        }
    }
    long pb = ((long)chunk * Bn + b) * COUT * (long)HW + pix;
    #pragma unroll
    for (int co = 0; co < COUT; co++) pbuf[pb + (long)co * HW] = acc[co];
}

// ================= conv reduce: out = bias + sum_chunks partial =================
__global__ void k_convr(const float* __restrict__ pbuf, const float* __restrict__ bias,
                        float* __restrict__ out, int Bn, int COUT, int HW, int nChunk)
{
    long idx = (long)blockIdx.x * TPB + threadIdx.x;
    if (idx >= (long)Bn * COUT * HW) return;
    int pix = idx % HW;
    int co  = (idx / HW) % COUT;
    int b   = idx / ((long)HW * COUT);
    float v = bias[co];
    for (int ch = 0; ch < nChunk; ch++)
        v += pbuf[(((long)ch * Bn + b) * COUT + co) * HW + pix];
    out[idx] = v;
}

// ===== LDS-staged single-pass 3x3 conv, CIN=64, square 16x16 tile, double-buffered =====
// Staging is split into batched register loads (one waitcnt for all 21) and LDS
// writes; the next chunk's loads are issued BEFORE computing the current chunk,
// so HBM/L2 latency hides under the 16-ci FMA block (T14 async-STAGE split).
template<int CG>
__global__ void k_conv3x3t(const float* __restrict__ x, const float* __restrict__ wf,
                           const float* __restrict__ bias, float* __restrict__ out,
                           int H, int W, int COUT)
{
    constexpr int CB = 16;
    constexpr int NE = CB * 324;          // 5184
    constexpr int NL = (NE + 255) / 256;  // 21
    __shared__ float s[2][CB][18][18];
    int tpr = W >> 4;
    int tpi = (H >> 4) * tpr;
    int tile = blockIdx.x;
    int b  = tile / tpi;
    int t  = tile % tpi;
    int r0  = (t / tpr) << 4;
    int c0p = (t % tpr) << 4;
    int cog = blockIdx.y;
    int HW = H * W;
    int tid = threadIdx.x;
    int row = tid >> 4, col = tid & 15;
    const float* xb = x + (long)b * 64 * HW;

    // Precompute per-thread staging geometry (constant divisors -> magic mul)
    int eci[NL], eoff[NL]; bool evld[NL], einr[NL];
    #pragma unroll
    for (int k = 0; k < NL; k++) {
        int e = tid + k * 256;
        bool inr = e < NE;
        int ee = inr ? e : 0;
        int ci  = ee / 324;
        int rem = ee - ci * 324;
        int rr = rem / 18, cc = rem - rr * 18;
        int gr = r0 - 1 + rr, gc = c0p - 1 + cc;
        bool v = inr && (gr >= 0 && gr < H && gc >= 0 && gc < W);
        eci[k]  = ci;
        eoff[k] = (v ? gr : 0) * W + (v ? gc : 0);
        evld[k] = v;
        einr[k] = inr;
    }

    float r[NL];
    float acc[CG];
    #pragma unroll
    for (int c = 0; c < CG; c++) acc[c] = 0.f;

    // prologue: load + write chunk 0
    #pragma unroll
    for (int k = 0; k < NL; k++)
        r[k] = evld[k] ? xb[(long)eci[k] * HW + eoff[k]] : 0.f;
    #pragma unroll
    for (int k = 0; k < NL; k++)
        if (einr[k]) ((float*)s[0])[tid + k * 256] = r[k];
    __syncthreads();

    #pragma unroll
    for (int st = 0; st < 4; st++) {
        // issue next chunk's loads (latency hides under compute below)
        if (st < 3) {
            int cbase = (st + 1) * CB;
            #pragma unroll
            for (int k = 0; k < NL; k++)
                r[k] = evld[k] ? xb[(long)(cbase + eci[k]) * HW + eoff[k]] : 0.f;
        }
        int buf = st & 1;
        #pragma unroll
        for (int ci = 0; ci < CB; ci++) {
            float t0 = s[buf][ci][row  ][col  ], t1 = s[buf][ci][row  ][col+1], t2 = s[buf][ci][row  ][col+2];
            float t3 = s[buf][ci][row+1][col  ], t4 = s[buf][ci][row+1][col+1], t5 = s[buf][ci][row+1][col+2];
            float t6 = s[buf][ci][row+2][col  ], t7 = s[buf][ci][row+2][col+1], t8 = s[buf][ci][row+2][col+2];
            const float* wr = wf + ((long)(st * CB + ci) * COUT + cog * CG) * 9;
            #pragma unroll
            for (int c = 0; c < CG; c++) {
                const float* wp = wr + c * 9;
                acc[c] += t0*wp[0] + t1*wp[1] + t2*wp[2] + t3*wp[3] + t4*wp[4]
                        + t5*wp[5] + t6*wp[6] + t7*wp[7] + t8*wp[8];
            }
        }
        if (st < 3) {
            __syncthreads();
            #pragma unroll
            for (int k = 0; k < NL; k++)
                if (einr[k]) ((float*)s[buf ^ 1])[tid + k * 256] = r[k];
            __syncthreads();
        }
    }

    int pp = (r0 + row) * W + c0p + col;
    #pragma unroll
    for (int c = 0; c < CG; c++) {
        int co = cog * CG + c;
        out[((long)b * COUT + co) * HW + pp] = acc[c] + bias[co];
    }
}

// ===== LDS-staged single-pass 1x1 conv: CIN=256 -> COUT=64 =====
// block = 64 pixels x 4 waves; wave w (readfirstlane -> SGPR) computes NCO
// consecutive co starting at (gy*4+w)*NCO. Weight reads are s_load_dwordxN;
// inner loop = 1 ds_read + NCO v_fmac.
template<typename T, int NCO>
__device__ void conv1x1f_body(const T* __restrict__ x, const float* __restrict__ wf,
                              const float* __restrict__ bias, float* __restrict__ out,
                              int HW)
{
    __shared__ float s[64][64];
    int tile = blockIdx.x;
    int tid = threadIdx.x;
    int pix = tid & 63;
    int grp = __builtin_amdgcn_readfirstlane(tid >> 6);   // wave id -> SGPR
    int co0 = (blockIdx.y * 4 + grp) * NCO;
    int g0 = tile * 64;
    int b  = g0 / HW, pp0 = g0 % HW;
    const T* xb = x + (long)b * 256 * HW + pp0;
    float acc[NCO];
    #pragma unroll
    for (int c = 0; c < NCO; c++) acc[c] = 0.f;
    for (int c0 = 0; c0 < 256; c0 += 64) {
        __syncthreads();
        #pragma unroll
        for (int k = 0; k < 16; k++) {
            int ci = grp + k * 4;
            s[ci][pix] = toF(xb[(long)(c0 + ci) * HW + pix]);
        }
        __syncthreads();
        #pragma unroll 8
        for (int ci = 0; ci < 64; ci++) {
            float v = s[ci][pix];
            const float* wr = wf + (c0 + ci) * 64 + co0;
            #pragma unroll
            for (int c = 0; c < NCO; c++) acc[c] += v * wr[c];
        }
    }
    long ob = ((long)b * 64 + co0) * HW + pp0 + pix;
    #pragma unroll
    for (int c = 0; c < NCO; c++) out[ob + (long)c * HW] = acc[c] + bias[co0 + c];
}
template<int NCO>
__global__ void k_conv1x1f(const void* x, const float* wf, const float* bias, float* out,
                           int HW, const int* flag)
{
    if (*flag) conv1x1f_body<float, NCO>((const float*)x, wf, bias, out, HW);
    else       conv1x1f_body<bf16, NCO>((const bf16*)x,  wf, bias, out, HW);
}

// ================= kernel_normalizer (planar in/out) =================
template<int K, typename OT>
__device__ void knorm_body(const float* __restrict__ mask, float* __restrict__ out,
                           OT* __restrict__ outb, int B, int H, int W)
{
    const int K2 = K * K;
    int HWi = H * W;
    int idx = blockIdx.x * TPB + threadIdx.x;
    if (idx >= B * HWi) return;
    int pix = idx % HWi;
    int b   = idx / HWi;
    long HW = (long)HWi;
    long base = (long)b * K2 * HW + pix;
    float v[K2];
    float m = -1e30f;
    for (int k = 0; k < K2; k++) { v[k] = mask[base + k*HW]; m = fmaxf(m, v[k]); }
    float s2 = 0.f;
    for (int k = 0; k < K2; k++) {
        int i = k / K, j = k % K;
        float hi = (K == 3) ? ((i==1)?1.f:0.08f) : ((i==2)?1.f:((i==1||i==3)?0.54f:0.08f));
        float hj = (K == 3) ? ((j==1)?1.f:0.08f) : ((j==2)?1.f:((j==1||j==3)?0.54f:0.08f));
        v[k] = expf(v[k] - m) * hi * hj;
        s2 += v[k];
    }
    float inv = 1.f / s2;
    for (int k = 0; k < K2; k++) {
        float r = v[k] * inv;
        out[base + k*HW] = r;
        if (outb) stT<OT>(outb, base + k*HW, r);
    }
}
template<int K>
__global__ void k_knorm(const float* mask, float* out, void* outb, int B, int H, int W, const int* flag)
{
    if (*flag) knorm_body<K, float>(mask, out, (float*)outb, B, H, W);
    else       knorm_body<K, bf16>(mask, out, (bf16*)outb, B, H, W);
}

// ================= carafe3 (2*f - carafe), planar mask, 8 channels/thread ============
template<typename TF, typename TO, int NC>
__device__ void carafe3c_body(const TF* __restrict__ feat, const float* __restrict__ mask,
                              TO* __restrict__ out, int Bn)
{
    constexpr int CH = NC / 8;
    int idx = blockIdx.x * TPB + threadIdx.x;
    if (idx >= Bn * CH * 16384) return;
    int px = idx & 16383;
    int cc = (idx >> 14) % CH;
    int b  = (idx >> 14) / CH;
    int wx = px & 127, hy = px >> 7;
    float mk[9]; int off[9];
    #pragma unroll
    for (int i = 0; i < 3; i++) {
        int yy = hy + i - 1; bool vy = (yy >= 0 && yy < 128); int yc = vy ? yy : hy;
        #pragma unroll
        for (int j = 0; j < 3; j++) {
            int xx = wx + j - 1; bool v = vy && (xx >= 0 && xx < 128);
            int xc = (xx >= 0 && xx < 128) ? xx : wx;
            int k = i*3 + j;
            float m = mask[(((long)b*9 + k) << 14) + px];
            mk[k] = v ? m : 0.f;
            off[k] = (yc << 7) + xc;
        }
    }
    long base = ((long)(b * NC + cc * 8) << 14);
    for (int c = 0; c < 8; c++) {
        const TF* fp = feat + base + ((long)c << 14);
        float ctr = 0.f, acc = 0.f;
        #pragma unroll
        for (int k = 0; k < 9; k++) {
            float v = toF(fp[off[k]]);
            if (k == 4) ctr = v;
            acc += v * mk[k];
        }
        stT<TO>(out, base + ((long)c << 14) + px, 2.f * ctr - acc);
    }
}
__global__ void k_carafe3c_ws(const float* feat, const float* mask, float* out, int Bn)
{
    carafe3c_body<float, float, 64>(feat, mask, out, Bn);
}
__global__ void k_carafe3c_io(const void* feat, const float* mask, void* out, long outOff,
                              int Bn, const int* flag)
{
    if (*flag) carafe3c_body<float, float, 256>((const float*)feat, mask, (float*)out + outOff, Bn);
    else       carafe3c_body<bf16, bf16, 256>((const bf16*)feat, mask, (bf16*)out + outOff, Bn);
}

// ===== carafe5 s=2 ws variant: thread = output pixel x channel-group; planar mask =====
template<typename TF, typename TO, bool ADD, int CG>
__device__ void carafe5_body(const TF* __restrict__ feat, const float* __restrict__ mask,
                             const float* __restrict__ add, TO* __restrict__ out,
                             int Bn, int C)
{
    int ng = C / CG;
    int idx = blockIdx.x * TPB + threadIdx.x;
    if (idx >= Bn * ng * 16384) return;
    int px = idx & 16383;
    int gi = (idx >> 14) % ng;
    int b  = (idx >> 14) / ng;
    int X = px & 127, Y = px >> 7;
    int h = Y >> 1, w = X >> 1;
    float mk[25]; int off[25];
    const float* mb = mask + (((long)b * 25) << 14) + px;
    #pragma unroll
    for (int i = 0; i < 5; i++) {
        int yy = h + i - 2; bool vy = (yy >= 0 && yy < 64); int yc = vy ? yy : 0;
        #pragma unroll
        for (int j = 0; j < 5; j++) {
            int xx = w + j - 2; bool v = vy && (xx >= 0 && xx < 64);
            int xc = (xx >= 0 && xx < 64) ? xx : 0;
            int k = i*5 + j;
            mk[k] = v ? mb[(long)k << 14] : 0.f;
            off[k] = (yc << 6) + xc;
        }
    }
    int c0 = gi * CG;
    for (int c = 0; c < CG; c++) {
        long fb = ((long)(b * C + c0 + c) << 12);
        long ob = ((long)(b * C + c0 + c) << 14) + px;
        const TF* fp = feat + fb;
        float acc = ADD ? add[ob] : 0.f;
        #pragma unroll
        for (int k = 0; k < 25; k++) acc += toF(fp[off[k]]) * mk[k];
        stT<TO>(out, ob, acc);
    }
}
template<int CG>
__global__ void k_carafe5_ws(const float* feat, const float* mask, const float* add,
                             float* out, int Bn, int C)
{
    carafe5_body<float, float, true, CG>(feat, mask, add, out, Bn, C);
}

// ================= group norm: slice partial stats (atomic) + apply =================
__global__ void k_gnstat(const float* __restrict__ x, float* __restrict__ stat, int statBase,
                         int S, int N)
{
    int bid = blockIdx.x;
    int bg = bid / S, sl = bid % S;
    int seg = N / S;
    long base = (long)bg * N + (long)sl * seg;
    float s = 0.f, ss = 0.f;
    for (int i = threadIdx.x; i < seg; i += TPB) {
        float v = x[base + i]; s += v; ss += v * v;
    }
    __shared__ float sh[8];
    for (int off = 32; off; off >>= 1) { s += __shfl_down(s, off); ss += __shfl_down(ss, off); }
    int wave = threadIdx.x >> 6, lane = threadIdx.x & 63;
    if (lane == 0) { sh[wave] = s; sh[4 + wave] = ss; }
    __syncthreads();
    if (threadIdx.x == 0) {
        float ts = 0.f, tss = 0.f;
        for (int i = 0; i < TPB/64; i++) { ts += sh[i]; tss += sh[4 + i]; }
        atomicAdd(&stat[statBase + bg*2], ts);
        atomicAdd(&stat[statBase + bg*2 + 1], tss);
    }
}
__global__ void k_gnapply(const float* __restrict__ x, const float* __restrict__ stat, int statBase,
                          const float* __restrict__ gamma, const float* __restrict__ beta,
                          float* __restrict__ out, int G, int Cg, int HW, int Bn)
{
    long idx = (long)blockIdx.x * TPB + threadIdx.x;
    long total = (long)Bn * G * Cg * HW;
    if (idx >= total) return;
    int bgN = Cg * HW;
    int bg = idx / bgN;
    int r  = idx % bgN;
    int g = bg % G;
    int c = g * Cg + r / HW;
    float s = stat[statBase + bg*2], ss = stat[statBase + bg*2 + 1];
    float mean = s / bgN;
    float inv = rsqrtf(ss / bgN - mean * mean + 1e-5f);
    out[idx] = (x[idx] - mean) * inv * gamma[c] + beta[c];
}

// ================= cosine sim partials (dilation 2) + finalize =================
__global__ void k_simp(const float* __restrict__ x, float* __restrict__ pbuf,
                       int Bn, int H, int W, int CS)
{
    int HW = H * W;
    int idx = blockIdx.x * TPB + threadIdx.x;
    if (idx >= Bn * HW) return;
    int chunk = blockIdx.y;
    int pix = idx % HW, b = idx / HW;
    int wx = pix % W, hy = pix / W;
    const int dyv[8] = {-2,-2,-2, 0, 0, 2, 2, 2};
    const int dxv[8] = {-2, 0, 2,-2, 2,-2, 0, 2};
    int off[8]; float msk[8];
    #pragma unroll
    for (int n = 0; n < 8; n++) {
        int yy = hy + dyv[n], xx = wx + dxv[n];
        bool v = (yy >= 0 && yy < H && xx >= 0 && xx < W);
        off[n] = v ? yy * W + xx : pix;
        msk[n] = v ? 1.f : 0.f;
    }
    float dc = 0.f, num[8], dn[8];
    #pragma unroll
    for (int n = 0; n < 8; n++) { num[n] = 0.f; dn[n] = 0.f; }
    const float* xb = x + ((long)b * 64 + chunk * CS) * HW;
    #pragma unroll 2
    for (int ci = 0; ci < CS; ci++) {
        const float* xc = xb + (long)ci * HW;
        float c0 = xc[pix];
        dc += c0 * c0;
        #pragma unroll
        for (int n = 0; n < 8; n++) {
            float v = xc[off[n]] * msk[n];
            num[n] += c0 * v; dn[n] += v * v;
        }
    }
    long base = ((long)chunk * Bn + b) * 17 * (long)HW + pix;
    pbuf[base] = dc;
    #pragma unroll
    for (int n = 0; n < 8; n++) {
        pbuf[base + (long)(1 + n) * HW] = num[n];
        pbuf[base + (long)(9 + n) * HW] = dn[n];
    }
}
__global__ void k_simr(const float* __restrict__ pbuf, float* __restrict__ out,
                       int Bn, int HW, int nChunk)
{
    int idx = blockIdx.x * TPB + threadIdx.x;
    if (idx >= Bn * HW) return;
    int pix = idx % HW, b = idx / HW;
    float dc = 0.f, num[8], dn[8];
    #pragma unroll
    for (int n = 0; n < 8; n++) { num[n] = 0.f; dn[n] = 0.f; }
    for (int ch = 0; ch < nChunk; ch++) {
        long base = ((long)ch * Bn + b) * 17 * (long)HW + pix;
        dc += pbuf[base];
        #pragma unroll
        for (int n = 0; n < 8; n++) {
            num[n] += pbuf[base + (long)(1 + n) * HW];
            dn[n]  += pbuf[base + (long)(9 + n) * HW];
        }
    }
    float nc = fmaxf(sqrtf(dc), 1e-8f);
    #pragma unroll
    for (int n = 0; n < 8; n++)
        out[((long)(b*8 + n)) * HW + pix] = num[n] / (nc * fmaxf(sqrtf(dn[n]), 1e-8f));
}

// ================= offset assembly =================
__global__ void k_offset(const float* __restrict__ lro, const float* __restrict__ hro,
                         const float* __restrict__ lrd, const float* __restrict__ hrd,
                         float* __restrict__ outoff, int B)
{
    int idx = blockIdx.x * TPB + threadIdx.x;
    int total = B * 32 * 64 * 64;
    if (idx >= total) return;
    int wx = idx & 63;
    int hy = (idx >> 6) & 63;
    int o  = (idx >> 12) & 31;
    int b  = idx >> 17;
    int c = o >> 2, p = (o >> 1) & 1, q = o & 1;
    long hridx = ((long)(b*8 + c) * 128 + 2*hy + p) * 128 + 2*wx + q;
    float off = lro[idx] + hro[hridx];
    float dsv = lrd[idx] + hrd[hridx];
    float sg = 1.f / (1.f + expf(-dsv));
    int comp = o >> 4;
    float ip = (comp == 0) ? (q ? 0.25f : -0.25f) : (p ? 0.25f : -0.25f);
    outoff[idx] = off * sg + ip;
}

// ===== grid sample from transposed lrupT[b][pix][256], grid.y = channel half =====
template<typename OT>
__device__ void gridsampleT_body(const unsigned short* __restrict__ lrupT,
                                 const float* __restrict__ offb, OT* __restrict__ out, int Bn)
{
    int idx = blockIdx.x * TPB + threadIdx.x;
    if (idx >= Bn * 4 * 16384) return;
    int ch0 = blockIdx.y << 5;            // 2 halves of 32 channels
    int opix = idx & 16383;
    int g = (idx >> 14) & 3, b = idx >> 16;
    int X = opix & 127, Y = opix >> 7;
    int h = Y >> 1, p = Y & 1, w = X >> 1, q = X & 1;
    int r = g*4 + p*2 + q;
    float offx = offb[((long)(b*32 + r)      << 12) + (h << 6) + w];
    float offy = offb[((long)(b*32 + 16 + r) << 12) + (h << 6) + w];
    float gx = fminf(fmaxf(2.f * (w + 0.5f + offx) - 0.5f, 0.f), 127.f);
    float gy = fminf(fmaxf(2.f * (h + 0.5f + offy) - 0.5f, 0.f), 127.f);
    float x0f = floorf(gx), y0f = floorf(gy);
    float tx = gx - x0f, ty = gy - y0f;
    int x0 = (int)x0f, y0 = (int)y0f;
    int x1 = min(x0 + 1, 127), y1 = min(y0 + 1, 127);
    float w11 = tx * ty, w10 = ty - w11, w01 = tx - w11, w00 = 1.f - tx - ty + w11;
    const unsigned short* base = lrupT + (((long)b << 14) << 8) + (g << 6) + ch0;
    long a00 = ((long)((y0 << 7) + x0)) << 8, a01 = ((long)((y0 << 7) + x1)) << 8;
    long a10 = ((long)((y1 << 7) + x0)) << 8, a11 = ((long)((y1 << 7) + x1)) << 8;
    OT* op = out + ((long)(b * 256 + g * 64 + ch0) << 14) + opix;
    #pragma unroll
    for (int c8 = 0; c8 < 4; c8++) {
        uint4 v00 = *(const uint4*)(base + a00 + c8*8);
        uint4 v01 = *(const uint4*)(base + a01 + c8*8);
        uint4 v10 = *(const uint4*)(base + a10 + c8*8);
        uint4 v11 = *(const uint4*)(base + a11 + c8*8);
        const unsigned short* u00 = (const unsigned short*)&v00;
        const unsigned short* u01 = (const unsigned short*)&v01;
        const unsigned short* u10 = (const unsigned short*)&v10;
        const unsigned short* u11 = (const unsigned short*)&v11;
        #pragma unroll
        for (int t = 0; t < 8; t++) {
            float res = bfu(u00[t])*w00 + bfu(u01[t])*w01 + bfu(u10[t])*w10 + bfu(u11[t])*w11;
            stT<OT>(op, ((long)(c8*8 + t) << 14), res);
        }
    }
}
__global__ void k_gridsampleT(const bf16* lrupT, const float* offb, void* out, long outOff,
                              int Bn, const int* flag)
{
    if (*flag) gridsampleT_body<float>((const unsigned short*)lrupT, offb, (float*)out + outOff, Bn);
    else       gridsampleT_body<bf16 >((const unsigned short*)lrupT, offb, (bf16*)out + outOff, Bn);
}

extern "C" void kernel_launch(void* const* d_in, const int* in_sizes, int n_in,
                              void* d_out, int out_size, void* d_ws, size_t ws_size,
                              hipStream_t stream) {
    const void* hr_feat = d_in[0];
    const void* lr_feat = d_in[1];

    const int B = 2, HH = 128, HL = 64;
    const int HWH = HH*HH, HWL = HL*HL;

    int*   flag = (int*)d_ws;
    float* stat = (float*)d_ws + 4;
    float* P    = (float*)d_ws + 80;
    float* ws   = P + ((P_TOT + 63) & ~63);

    size_t o = 0;
    float* ch0    = ws + o; o += (size_t)B*64*HWH;
    float* clb    = ws + o; o += (size_t)B*64*HWL;
    float* maskHH = ws + o; o += (size_t)B*9*HWH;
    float* tmp9   = ws + o; o += (size_t)B*9*HWH;
    float* chn    = ws + o; o += (size_t)B*64*HWH;
    float* m25a   = ws + o; o += (size_t)B*25*HWH;
    float* m25b   = ws + o; o += (size_t)B*25*HWH;
    float* m25c   = ws + o; o += (size_t)B*25*HWH;
    float* enccl  = ws + o; o += (size_t)B*25*HWL;
    float* enc2cl = ws + o; o += (size_t)B*9*HWL;
    bf16*  lrupT  = (bf16*)(ws + o); o += (size_t)B*256*HWH/2;   // transposed lr_up [b][pix][256]
    float* lrx    = ws + o; o += (size_t)B*64*HWL;
    float* hrsim  = ws + o; o += (size_t)B*8*HWH;
    float* lrsim  = ws + o; o += (size_t)B*8*HWL;
    float* qhro   = ws + o; o += (size_t)B*8*HWH;
    float* qlro   = ws + o; o += (size_t)B*32*HWL;
    float* qhrd   = ws + o; o += (size_t)B*8*HWH;
    float* qlrd   = ws + o; o += (size_t)B*32*HWL;
    float* offb   = ws + o; o += (size_t)B*32*HWL;
    float* hrx   = ch0;     // ch0 dead after step 5
    float* maskH = m25b;    // m25b dead after step 9
    // partial/scratch aliases over verified-dead zones:
    float* pbufT  = chn;             // steps 18-21 (chn dead after gnstat/gnapply)
    bf16*  lrfT   = (bf16*)hrsim;    // lr_feat transposed [b][4096][256] bf16
    (void)ws_size; (void)n_in;

    long out1Off = (long)B*25*HWH;
    long out2Off = out1Off + (long)B*256*HWH;

    const float* pw_hrc = P + P_W_HRC;  const float* pb_hrc = P + P_B_HRC;
    const float* pw_lrc = P + P_W_LRC;  const float* pb_lrc = P + P_B_LRC;
    const float* pw_enc = P + P_W_ENC;  const float* pb_enc = P + P_B_ENC;
    const float* pw_enc2= P + P_W_ENC2; const float* pb_enc2= P + P_B_ENC2;
    const float* pgnhw  = P + P_GNHW;   const float* pgnhb  = P + P_GNHB;
    const float* pgnlw  = P + P_GNLW;   const float* pgnlb  = P + P_GNLB;
    const float* pw_off = P + P_W_OFF;  const float* pb_off = P + P_B_OFF;
    const float* pw_hoff= P + P_W_HOFF; const float* pb_hoff= P + P_B_HOFF;
    const float* pw_ds  = P + P_W_DS;   const float* pb_ds  = P + P_B_DS;
    const float* pw_hds = P + P_W_HDS;  const float* pb_hds = P + P_B_HDS;

    // 0. dtype detect + weight prep + lr_feat transpose (channels-last)
    int nDet = in_sizes[0] < 16384 ? in_sizes[0] : 16384;
    k_detect<<<1, TPB, 0, stream>>>(hr_feat, nDet, flag, stat);
    k_prep<<<nblk(P_TOT), TPB, 0, stream>>>(d_in[2],d_in[3],d_in[4],d_in[5],d_in[6],d_in[7],
        d_in[8],d_in[9],d_in[10],d_in[11],d_in[12],d_in[13],d_in[14],d_in[15],d_in[16],
        d_in[17],d_in[18],d_in[19],d_in[20],d_in[21], P, flag);
    k_transpLR<<<B*4*64, TPB, 0, stream>>>(lr_feat, lrfT, B, flag);

    // 1. ch0 = 1x1(hr_feat): scalar-weight LDS pass, 512 blocks, wave=16co
    k_conv1x1f<16><<<dim3((B*HWH)/64,1), TPB, 0, stream>>>(hr_feat, pw_hrc, pb_hrc, ch0, HWH, flag);
    // 2. clb = 1x1(lr_feat): co-split x4 (wave=4co), 128x4=512 blocks
    k_conv1x1f<4><<<dim3((B*HWL)/64,4), TPB, 0, stream>>>(lr_feat, pw_lrc, pb_lrc, clb, HWL, flag);
    // 3. mask_hr_hr = 3x3(ch0) -> 9co, 16x16 tiles, 3 co-groups of 3
    k_conv3x3t<3><<<dim3(B*64,3), TPB, 0, stream>>>(ch0, pw_enc2, pb_enc2, maskHH, HH, HH, 9);
    // 4-5. mh_init, ch = 2*ch0 - carafe3(ch0)
    k_knorm<3><<<nblk((long)B*HWH), TPB, 0, stream>>>(maskHH, tmp9, nullptr, B, HH, HH, flag);
    k_carafe3c_ws<<<nblk((long)B*8*16384), TPB, 0, stream>>>(ch0, tmp9, chn, B);
    // 6. mask_lr_hr = 3x3(chn) -> 25co, 5 co-groups of 5
    k_conv3x3t<5><<<dim3(B*64,5), TPB, 0, stream>>>(chn, pw_enc, pb_enc, m25a, HH, HH, 25);
    // 7. ml_init -> m25b
    k_knorm<5><<<nblk((long)B*HWH), TPB, 0, stream>>>(m25a, m25b, nullptr, B, HH, HH, flag);
    // 8. enccl = 3x3(clb) -> 25co
    k_conv3x3t<5><<<dim3(B*16,5), TPB, 0, stream>>>(clb, pw_enc, pb_enc, enccl, HL, HL, 25);
    // 9. mask_lr = mask_lr_hr + carafe5(enccl, ml_init): C=25, CG=5
    k_carafe5_ws<5><<<nblk((long)B*5*16384), TPB, 0, stream>>>(enccl, m25b, m25a, m25c, B, 25);
    // 10. mask_lr_n -> m25a + bf16 output 0
    k_knorm<5><<<nblk((long)B*HWH), TPB, 0, stream>>>(m25c, m25a, d_out, B, HH, HH, flag);
    // 11. enc2cl = 3x3(clb) -> 9co
    k_conv3x3t<3><<<dim3(B*16,3), TPB, 0, stream>>>(clb, pw_enc2, pb_enc2, enc2cl, HL, HL, 9);
    // 12. mask_hr = mask_hr_hr + carafe5(enc2cl, mask_lr_n): C=9, CG=3
    k_carafe5_ws<3><<<nblk((long)B*3*16384), TPB, 0, stream>>>(enc2cl, m25a, maskHH, maskH, B, 9);
    // 13-14. mask_hr_n, hr_out -> output 1
    k_knorm<3><<<nblk((long)B*HWH), TPB, 0, stream>>>(maskH, tmp9, nullptr, B, HH, HH, flag);
    k_carafe3c_io<<<nblk((long)B*32*16384), TPB, 0, stream>>>(hr_feat, tmp9, d_out, out1Off, B, flag);
    // 15. lr_up (transposed): wave=(b,ipix), lane=4-channel group; XCD-swizzled
    k_carafe5T<<<B*4096/4, TPB, 0, stream>>>(lrfT, m25a, lrupT, B);
    // 16-17. group norms
    k_gnstat<<<16*32, TPB, 0, stream>>>(chn, stat, 0, 32, 8*HWH);
    k_gnapply<<<nblk((long)B*64*HWH), TPB, 0, stream>>>(chn, stat, 0, pgnhw, pgnhb, hrx, 8, 8, HWH, B);
    k_gnstat<<<16*8, TPB, 0, stream>>>(clb, stat, 32, 8, 8*HWL);
    k_gnapply<<<nblk((long)B*64*HWL), TPB, 0, stream>>>(clb, stat, 32, pgnlw, pgnlb, lrx, 8, 8, HWL, B);
    // 18. hrsim: 8 chunks x CS8
    k_simp<<<dim3(nblk((long)B*HWH),8), TPB, 0, stream>>>(hrx, pbufT, B, HH, HH, 8);
    k_simr<<<nblk((long)B*HWH), TPB, 0, stream>>>(pbufT, hrsim, B, HWH, 8);
    // 19. lrsim: 16 chunks x CS4
    k_simp<<<dim3(nblk((long)B*HWL),16), TPB, 0, stream>>>(lrx, pbufT, B, HL, HL, 4);
    k_simr<<<nblk((long)B*HWL), TPB, 0, stream>>>(pbufT, lrsim, B, HWL, 16);
    // 20. qhro: 4 chunks x CS2 (CIN=8, keep partial path)
    k_conv3x3p<8><<<dim3(nblk((long)B*HWH),4), TPB, 0, stream>>>(hrsim, pw_hoff, pbufT, B, 8, HH, HH, 2);
    k_convr<<<nblk((long)B*8*HWH), TPB, 0, stream>>>(pbufT, pb_hoff, qhro, B, 8, HWH, 4);
    // 21. qlro: 8 chunks x CS1 (CIN=8, keep partial path)
    k_conv3x3p<32><<<dim3(nblk((long)B*HWL),8), TPB, 0, stream>>>(lrsim, pw_off, pbufT, B, 8, HL, HL, 1);
    k_convr<<<nblk((long)B*32*HWL), TPB, 0, stream>>>(pbufT, pb_off, qlro, B, 32, HWL, 8);
    // 22. qhrd = 3x3(hrx) -> 8co, 4 co-groups of 2
    k_conv3x3t<2><<<dim3(B*64,4), TPB, 0, stream>>>(hrx, pw_hds, pb_hds, qhrd, HH, HH, 8);
    // 23. qlrd = 3x3(lrx) -> 32co, 16 co-groups of 2
    k_conv3x3t<2><<<dim3(B*16,16), TPB, 0, stream>>>(lrx, pw_ds, pb_ds, qlrd, HL, HL, 32);
    // 24. offset assembly
    k_offset<<<nblk((long)B*32*HWL), TPB, 0, stream>>>(qlro, qhro, qlrd, qhrd, offb, B);
    // 25. grid sample from lrupT -> output 2 (2 channel halves)
    k_gridsampleT<<<dim3(nblk((long)B*4*HWH),2), TPB, 0, stream>>>(lrupT, offb, d_out, out2Off, B, flag);
}

// Round 7
// 971.897 us; speedup vs baseline: 1.6437x; 1.6437x over previous
//
#include <hip/hip_runtime.h>
#include <hip/hip_bf16.h>

typedef __hip_bfloat16 bf16;
#define TPB 256

__device__ __forceinline__ float toF(float v){ return v; }
__device__ __forceinline__ float toF(bf16 v){ return __bfloat162float(v); }
__device__ __forceinline__ float bfu(unsigned short u){
    unsigned int x = ((unsigned int)u) << 16;
    return __uint_as_float(x);
}
template<typename T> __device__ __forceinline__ void stT(T* p, long i, float v);
template<> __device__ __forceinline__ void stT<float>(float* p, long i, float v){ p[i] = v; }
template<> __device__ __forceinline__ void stT<bf16>(bf16* p, long i, float v){ p[i] = __float2bfloat16(v); }

__device__ __forceinline__ void st4bf(bf16* p, const float* a){
    bf16 t0 = __float2bfloat16(a[0]);
    bf16 t1 = __float2bfloat16(a[1]);
    bf16 t2 = __float2bfloat16(a[2]);
    bf16 t3 = __float2bfloat16(a[3]);
    ushort4 pk;
    pk.x = *(unsigned short*)&t0;
    pk.y = *(unsigned short*)&t1;
    pk.z = *(unsigned short*)&t2;
    pk.w = *(unsigned short*)&t3;
    *(ushort4*)p = pk;
}

static inline int nblk(long n){ return (int)((n + TPB - 1) / TPB); }

// ================= dtype detection + stat zero =================
__global__ void k_detect(const void* hr, int n, int* flag, float* stat)
{
    if (threadIdx.x < 64) stat[threadIdx.x] = 0.f;
    const unsigned short* u = (const unsigned short*)hr;
    int nan = 0, oz = 0, ot = 0;
    for (int i = threadIdx.x; i < n; i += TPB) {
        unsigned short a = u[i] & 0x7FFF;
        if (a >= 0x7F80) nan++;
        if (i & 1) { ot++; if (a == 0) oz++; }
    }
    __shared__ int s1[TPB], s2[TPB], s3[TPB];
    s1[threadIdx.x] = nan; s2[threadIdx.x] = oz; s3[threadIdx.x] = ot;
    __syncthreads();
    if (threadIdx.x == 0) {
        int a = 0, b = 0, c = 0;
        for (int i = 0; i < TPB; i++) { a += s1[i]; b += s2[i]; c += s3[i]; }
        *flag = (a >= 6 || (long)b * 10 >= (long)c * 9) ? 1 : 0;
    }
}

// ================= weight prep: fp32 + transpose to [ci][co][taps] =================
#define P_W_HRC 0
#define P_B_HRC 16384
#define P_W_LRC 16448
#define P_B_LRC 32832
#define P_W_ENC 32896
#define P_B_ENC 47296
#define P_W_ENC2 47321
#define P_B_ENC2 52505
#define P_GNHW 52514
#define P_GNHB 52578
#define P_GNLW 52642
#define P_GNLB 52706
#define P_W_OFF 52770
#define P_B_OFF 55074
#define P_W_HOFF 55106
#define P_B_HOFF 55682
#define P_W_DS 55690
#define P_B_DS 74122
#define P_W_HDS 74154
#define P_B_HDS 78762
#define P_TOT 78770

__constant__ int c_segsz[20]  = {16384,64,16384,64,14400,25,5184,9,64,64,64,64,2304,32,576,8,18432,32,4608,8};
__constant__ int c_segbase[20]= {P_W_HRC,P_B_HRC,P_W_LRC,P_B_LRC,P_W_ENC,P_B_ENC,P_W_ENC2,P_B_ENC2,
                                 P_GNHW,P_GNHB,P_GNLW,P_GNLB,P_W_OFF,P_B_OFF,P_W_HOFF,P_B_HOFF,
                                 P_W_DS,P_B_DS,P_W_HDS,P_B_HDS};
__constant__ int c_segcin[20] = {256,0,256,0, 64,0, 64,0, 0,0,0,0, 8,0, 8,0, 64,0, 64,0};
__constant__ int c_segcout[20]= { 64,0, 64,0, 25,0,  9,0, 0,0,0,0,32,0, 8,0, 32,0,  8,0};
__constant__ int c_segtap[20] = {  1,0,  1,0,  9,0,  9,0, 0,0,0,0, 9,0, 9,0,  9,0,  9,0};

__global__ void k_prep(const void* p0,const void* p1,const void* p2,const void* p3,
                       const void* p4,const void* p5,const void* p6,const void* p7,
                       const void* p8,const void* p9,const void* p10,const void* p11,
                       const void* p12,const void* p13,const void* p14,const void* p15,
                       const void* p16,const void* p17,const void* p18,const void* p19,
                       float* dst, const int* flag)
{
    int idx = blockIdx.x * TPB + threadIdx.x;
    if (idx >= P_TOT) return;
    int s = 0, off = idx;
    while (off >= c_segsz[s]) { off -= c_segsz[s]; s++; }
    const void* sp;
    switch (s) {
        case 0: sp=p0; break;  case 1: sp=p1; break;  case 2: sp=p2; break;  case 3: sp=p3; break;
        case 4: sp=p4; break;  case 5: sp=p5; break;  case 6: sp=p6; break;  case 7: sp=p7; break;
        case 8: sp=p8; break;  case 9: sp=p9; break;  case 10: sp=p10; break; case 11: sp=p11; break;
        case 12: sp=p12; break; case 13: sp=p13; break; case 14: sp=p14; break; case 15: sp=p15; break;
        case 16: sp=p16; break; case 17: sp=p17; break; case 18: sp=p18; break; default: sp=p19; break;
    }
    float v = (*flag) ? ((const float*)sp)[off] : toF(((const bf16*)sp)[off]);
    int doff = off;
    int cin = c_segcin[s];
    if (cin) {
        int t = c_segtap[s], cout = c_segcout[s];
        int co = off / (cin * t);
        int r  = off % (cin * t);
        int ci = r / t, k = r % t;
        doff = (ci * cout + co) * t + k;
    }
    dst[c_segbase[s] + doff] = v;
}

// ================= lr_feat transpose: [b][256][4096] -> bf16 [b][4096][256] =============
template<typename T>
__device__ void transpLR_body(const T* __restrict__ x, bf16* __restrict__ xT, int Bn)
{
    __shared__ float tile[64][65];
    int bid = blockIdx.x;                 // b * 4 cgroup * 64 pgroup
    int pg = bid & 63;
    int cg = (bid >> 6) & 3;
    int b  = bid >> 8;
    int tid = threadIdx.x;
    int tr = tid >> 6, tc = tid & 63;
    for (int i = 0; i < 16; i++) {
        int c = tr + i * 4;
        tile[c][tc] = toF(x[(((long)(b * 256 + cg * 64 + c)) << 12) + (pg << 6) + tc]);
    }
    __syncthreads();
    for (int i = 0; i < 16; i++) {
        int p = tr + i * 4;
        xT[((((long)b << 12) + (pg << 6) + p) << 8) + (cg << 6) + tc] = __float2bfloat16(tile[tc][p]);
    }
}
__global__ void k_transpLR(const void* x, bf16* xT, int Bn, const int* flag)
{
    if (*flag) transpLR_body<float>((const float*)x, xT, Bn);
    else       transpLR_body<bf16 >((const bf16*)x,  xT, Bn);
}

// ===== carafe5-up channels-last: wave = (b, ipix), lane = 4-channel group =====
__global__ void k_carafe5T(const bf16* __restrict__ featT, const float* __restrict__ mask,
                           bf16* __restrict__ outT, int Bn)
{
    int lane = threadIdx.x & 63;
    int nwg = gridDim.x;
    int bid = blockIdx.x;
    int swz = (nwg & 7) ? bid : ((bid & 7) * (nwg >> 3) + (bid >> 3));
    int wid = (swz << 2) | (threadIdx.x >> 6);
    wid = __builtin_amdgcn_readfirstlane(wid);
    if (wid >= Bn * 4096) return;
    int ipix = wid & 4095;
    int b    = wid >> 12;
    int h = ipix >> 6, w = ipix & 63;
    const bf16*  fb = featT + (((long)b << 12) << 8) + (lane << 2);
    const float* mb = mask + (((long)b * 25) << 14) + (h << 8) + (w << 1);
    float a00[4], a01[4], a10[4], a11[4];
    #pragma unroll
    for (int t = 0; t < 4; t++) { a00[t]=0.f; a01[t]=0.f; a10[t]=0.f; a11[t]=0.f; }
    #pragma unroll
    for (int k = 0; k < 25; k++) {
        const int i = k / 5, j = k % 5;
        int yy = h + i - 2, xx = w + j - 2;
        bool v = (yy >= 0 && yy < 64 && xx >= 0 && xx < 64);
        int yc = v ? yy : 0, xc = v ? xx : 0;
        ushort4 u = *(const ushort4*)(fb + ((long)((yc << 6) + xc) << 8));
        float2 mr0 = *(const float2*)(mb + ((long)k << 14));
        float2 mr1 = *(const float2*)(mb + ((long)k << 14) + 128);
        float m00 = v ? mr0.x : 0.f, m01 = v ? mr0.y : 0.f;
        float m10 = v ? mr1.x : 0.f, m11 = v ? mr1.y : 0.f;
        float f0 = bfu(u.x), f1 = bfu(u.y), f2 = bfu(u.z), f3 = bfu(u.w);
        a00[0] += f0*m00; a00[1] += f1*m00; a00[2] += f2*m00; a00[3] += f3*m00;
        a01[0] += f0*m01; a01[1] += f1*m01; a01[2] += f2*m01; a01[3] += f3*m01;
        a10[0] += f0*m10; a10[1] += f1*m10; a10[2] += f2*m10; a10[3] += f3*m10;
        a11[0] += f0*m11; a11[1] += f1*m11; a11[2] += f2*m11; a11[3] += f3*m11;
    }
    bf16* op = outT + (((long)(b << 14) + (h << 8) + (w << 1)) << 8) + (lane << 2);
    st4bf(op, a00);                       // (2h,   2w)
    st4bf(op + 256, a01);                 // (2h,   2w+1)
    st4bf(op + (128 << 8), a10);          // (2h+1, 2w)
    st4bf(op + (128 << 8) + 256, a11);    // (2h+1, 2w+1)
}

// ================= 3x3 conv partials: grid.y = ci-chunk =================
template<int COUT>
__global__ void k_conv3x3p(const float* __restrict__ x, const float* __restrict__ wf,
                           float* __restrict__ pbuf, int Bn, int CIN, int H, int W, int CS)
{
    int HW = H * W;
    int idx = blockIdx.x * TPB + threadIdx.x;
    if (idx >= Bn * HW) return;
    int chunk = blockIdx.y;
    int pix = idx % HW, b = idx / HW;
    int wx = pix % W, hy = pix / W;
    int off[9]; float msk[9];
    #pragma unroll
    for (int i = 0; i < 3; i++) {
        int yy = hy + i - 1; bool vy = (yy >= 0 && yy < H); int yc = vy ? yy : hy;
        #pragma unroll
        for (int j = 0; j < 3; j++) {
            int xx = wx + j - 1; bool v = vy && (xx >= 0 && xx < W);
            int xc = (xx >= 0 && xx < W) ? xx : wx;
            off[i*3+j] = yc * W + xc; msk[i*3+j] = v ? 1.f : 0.f;
        }
    }
    float acc[COUT];
    #pragma unroll
    for (int co = 0; co < COUT; co++) acc[co] = 0.f;
    int c0 = chunk * CS;
    const float* xb = x + ((long)b * CIN + c0) * HW;
    const float* wb = wf + (long)c0 * COUT * 9;
    #pragma unroll 2
    for (int ci = 0; ci < CS; ci++) {
        const float* xc = xb + (long)ci * HW;
        float t[9];
        #pragma unroll
        for (int k = 0; k < 9; k++) t[k] = xc[off[k]] * msk[k];
        const float* wr = wb + (long)ci * COUT * 9;
        #pragma unroll
        for (int co = 0; co < COUT; co++) {
            const float* wp = wr + co * 9;
            acc[co] += t[0]*wp[0] + t[1]*wp[1] + t[2]*wp[2] + t[3]*wp[3] + t[4]*wp[4]
                     + t[5]*wp[5] + t[6]*wp[6] + t[7]*wp[7] + t[8]*wp[8];
        }
    }
    long pb = ((long)chunk * Bn + b) * COUT * (long)HW + pix;
    #pragma unroll
    for (int co = 0; co < COUT; co++) pbuf[pb + (long)co * HW] = acc[co];
}

// ================= conv reduce: out = bias + sum_chunks partial =================
__global__ void k_convr(const float* __restrict__ pbuf, const float* __restrict__ bias,
                        float* __restrict__ out, int Bn, int COUT, int HW, int nChunk)
{
    long idx = (long)blockIdx.x * TPB + threadIdx.x;
    if (idx >= (long)Bn * COUT * HW) return;
    int pix = idx % HW;
    int co  = (idx / HW) % COUT;
    int b   = idx / ((long)HW * COUT);
    float v = bias[co];
    for (int ch = 0; ch < nChunk; ch++)
        v += pbuf[(((long)ch * Bn + b) * COUT + co) * HW + pix];
    out[idx] = v;
}

// ===== 1x1 conv partials (COUT=64), grid.y = chunk (R1-proven path) =====
template<typename T>
__device__ void conv1x1p_body(const T* __restrict__ x, const float* __restrict__ wf,
                              float* __restrict__ pbuf, int Bn, int CIN, int HW, int CS)
{
    int idx = blockIdx.x * TPB + threadIdx.x;
    if (idx >= Bn * HW) return;
    int chunk = blockIdx.y;
    int pix = idx % HW, b = idx / HW;
    float acc[64];
    #pragma unroll
    for (int co = 0; co < 64; co++) acc[co] = 0.f;
    int c0 = chunk * CS;
    const T* xp = x + ((long)b * CIN + c0) * HW + pix;
    const float* wb = wf + (long)c0 * 64;
    #pragma unroll 2
    for (int ci = 0; ci < CS; ci++) {
        float v = toF(xp[(long)ci * HW]);
        const float* wr = wb + ci * 64;
        #pragma unroll
        for (int co = 0; co < 64; co++) acc[co] += v * wr[co];
    }
    long pb = ((long)chunk * Bn + b) * 64 * (long)HW + pix;
    #pragma unroll
    for (int co = 0; co < 64; co++) pbuf[pb + (long)co * HW] = acc[co];
}
__global__ void k_conv1x1p(const void* x, const float* wf, float* pbuf,
                           int Bn, int CIN, int HW, int CS, const int* flag)
{
    if (*flag) conv1x1p_body<float>((const float*)x, wf, pbuf, Bn, CIN, HW, CS);
    else       conv1x1p_body<bf16 >((const bf16*)x,  wf, pbuf, Bn, CIN, HW, CS);
}

// ===== LDS-staged single-pass 3x3 conv, CIN=64, 16x16 tile, lean dbuf =====
// CB=8 -> r[11] only; geometry recomputed inline (no index arrays -> no spill);
// __launch_bounds__(256,2) caps VGPR at 256 so the compiler never force-spills.
// Next chunk's 11 loads are issued before computing the current chunk (one
// waitcnt group), so L2/HBM latency hides under the 8ci x 9 x CG FMA block.
template<int CG>
__global__ __launch_bounds__(256, 2)
void k_conv3x3t(const float* __restrict__ x, const float* __restrict__ wf,
                const float* __restrict__ bias, float* __restrict__ out,
                int H, int W, int COUT)
{
    constexpr int CB = 8;
    constexpr int NE = CB * 324;          // 2592
    constexpr int NL = (NE + 255) / 256;  // 11
    __shared__ float s[2][CB][18][18];
    int tpr = W >> 4;
    int tpi = (H >> 4) * tpr;
    int tile = blockIdx.x;
    int b  = tile / tpi;
    int t  = tile % tpi;
    int r0  = (t / tpr) << 4;
    int c0p = (t % tpr) << 4;
    int cog = blockIdx.y;
    int HW = H * W;
    int tid = threadIdx.x;
    int row = tid >> 4, col = tid & 15;
    const float* xb = x + (long)b * 64 * HW;

    float r[NL];
    float acc[CG];
    #pragma unroll
    for (int c = 0; c < CG; c++) acc[c] = 0.f;

    auto LOAD = [&](int cbase) {
        #pragma unroll
        for (int k = 0; k < NL; k++) {
            int e = tid + (k << 8);
            int ci  = e / 324;
            int rem = e - ci * 324;
            int rr = rem / 18, cc = rem - rr * 18;
            int gr = r0 - 1 + rr, gc = c0p - 1 + cc;
            bool v = (e < NE) && (gr >= 0) && (gr < H) && (gc >= 0) && (gc < W);
            r[k] = v ? xb[(long)(cbase + ci) * HW + gr * W + gc] : 0.f;
        }
    };
    auto WRITE = [&](int buf) {
        #pragma unroll
        for (int k = 0; k < NL; k++) {
            int e = tid + (k << 8);
            if (e < NE) ((float*)s[buf])[e] = r[k];
        }
    };

    LOAD(0);
    WRITE(0);
    __syncthreads();

    #pragma unroll
    for (int st = 0; st < 8; st++) {
        if (st < 7) LOAD((st + 1) * CB);          // prefetch next chunk
        int buf = st & 1;
        #pragma unroll
        for (int ci = 0; ci < CB; ci++) {
            float t0 = s[buf][ci][row  ][col  ], t1 = s[buf][ci][row  ][col+1], t2 = s[buf][ci][row  ][col+2];
            float t3 = s[buf][ci][row+1][col  ], t4 = s[buf][ci][row+1][col+1], t5 = s[buf][ci][row+1][col+2];
            float t6 = s[buf][ci][row+2][col  ], t7 = s[buf][ci][row+2][col+1], t8 = s[buf][ci][row+2][col+2];
            const float* wr = wf + ((long)(st * CB + ci) * COUT + cog * CG) * 9;
            #pragma unroll
            for (int c = 0; c < CG; c++) {
                const float* wp = wr + c * 9;
                acc[c] += t0*wp[0] + t1*wp[1] + t2*wp[2] + t3*wp[3] + t4*wp[4]
                        + t5*wp[5] + t6*wp[6] + t7*wp[7] + t8*wp[8];
            }
        }
        if (st < 7) {
            __syncthreads();
            WRITE(buf ^ 1);
            __syncthreads();
        }
    }

    int pp = (r0 + row) * W + c0p + col;
    #pragma unroll
    for (int c = 0; c < CG; c++) {
        int co = cog * CG + c;
        out[((long)b * COUT + co) * HW + pp] = acc[c] + bias[co];
    }
}

// ================= kernel_normalizer (planar in/out) =================
template<int K, typename OT>
__device__ void knorm_body(const float* __restrict__ mask, float* __restrict__ out,
                           OT* __restrict__ outb, int B, int H, int W)
{
    const int K2 = K * K;
    int HWi = H * W;
    int idx = blockIdx.x * TPB + threadIdx.x;
    if (idx >= B * HWi) return;
    int pix = idx % HWi;
    int b   = idx / HWi;
    long HW = (long)HWi;
    long base = (long)b * K2 * HW + pix;
    float v[K2];
    float m = -1e30f;
    for (int k = 0; k < K2; k++) { v[k] = mask[base + k*HW]; m = fmaxf(m, v[k]); }
    float s2 = 0.f;
    for (int k = 0; k < K2; k++) {
        int i = k / K, j = k % K;
        float hi = (K == 3) ? ((i==1)?1.f:0.08f) : ((i==2)?1.f:((i==1||i==3)?0.54f:0.08f));
        float hj = (K == 3) ? ((j==1)?1.f:0.08f) : ((j==2)?1.f:((j==1||j==3)?0.54f:0.08f));
        v[k] = expf(v[k] - m) * hi * hj;
        s2 += v[k];
    }
    float inv = 1.f / s2;
    for (int k = 0; k < K2; k++) {
        float r = v[k] * inv;
        out[base + k*HW] = r;
        if (outb) stT<OT>(outb, base + k*HW, r);
    }
}
template<int K>
__global__ void k_knorm(const float* mask, float* out, void* outb, int B, int H, int W, const int* flag)
{
    if (*flag) knorm_body<K, float>(mask, out, (float*)outb, B, H, W);
    else       knorm_body<K, bf16>(mask, out, (bf16*)outb, B, H, W);
}

// ================= carafe3 (2*f - carafe), planar mask, 8 channels/thread ============
template<typename TF, typename TO, int NC>
__device__ void carafe3c_body(const TF* __restrict__ feat, const float* __restrict__ mask,
                              TO* __restrict__ out, int Bn)
{
    constexpr int CH = NC / 8;
    int idx = blockIdx.x * TPB + threadIdx.x;
    if (idx >= Bn * CH * 16384) return;
    int px = idx & 16383;
    int cc = (idx >> 14) % CH;
    int b  = (idx >> 14) / CH;
    int wx = px & 127, hy = px >> 7;
    float mk[9]; int off[9];
    #pragma unroll
    for (int i = 0; i < 3; i++) {
        int yy = hy + i - 1; bool vy = (yy >= 0 && yy < 128); int yc = vy ? yy : hy;
        #pragma unroll
        for (int j = 0; j < 3; j++) {
            int xx = wx + j - 1; bool v = vy && (xx >= 0 && xx < 128);
            int xc = (xx >= 0 && xx < 128) ? xx : wx;
            int k = i*3 + j;
            float m = mask[(((long)b*9 + k) << 14) + px];
            mk[k] = v ? m : 0.f;
            off[k] = (yc << 7) + xc;
        }
    }
    long base = ((long)(b * NC + cc * 8) << 14);
    for (int c = 0; c < 8; c++) {
        const TF* fp = feat + base + ((long)c << 14);
        float ctr = 0.f, acc = 0.f;
        #pragma unroll
        for (int k = 0; k < 9; k++) {
            float v = toF(fp[off[k]]);
            if (k == 4) ctr = v;
            acc += v * mk[k];
        }
        stT<TO>(out, base + ((long)c << 14) + px, 2.f * ctr - acc);
    }
}
__global__ void k_carafe3c_ws(const float* feat, const float* mask, float* out, int Bn)
{
    carafe3c_body<float, float, 64>(feat, mask, out, Bn);
}
__global__ void k_carafe3c_io(const void* feat, const float* mask, void* out, long outOff,
                              int Bn, const int* flag)
{
    if (*flag) carafe3c_body<float, float, 256>((const float*)feat, mask, (float*)out + outOff, Bn);
    else       carafe3c_body<bf16, bf16, 256>((const bf16*)feat, mask, (bf16*)out + outOff, Bn);
}

// ===== carafe5 s=2 ws variant: thread = output pixel x channel-group; planar mask =====
template<typename TF, typename TO, bool ADD, int CG>
__device__ void carafe5_body(const TF* __restrict__ feat, const float* __restrict__ mask,
                             const float* __restrict__ add, TO* __restrict__ out,
                             int Bn, int C)
{
    int ng = C / CG;
    int idx = blockIdx.x * TPB + threadIdx.x;
    if (idx >= Bn * ng * 16384) return;
    int px = idx & 16383;
    int gi = (idx >> 14) % ng;
    int b  = (idx >> 14) / ng;
    int X = px & 127, Y = px >> 7;
    int h = Y >> 1, w = X >> 1;
    float mk[25]; int off[25];
    const float* mb = mask + (((long)b * 25) << 14) + px;
    #pragma unroll
    for (int i = 0; i < 5; i++) {
        int yy = h + i - 2; bool vy = (yy >= 0 && yy < 64); int yc = vy ? yy : 0;
        #pragma unroll
        for (int j = 0; j < 5; j++) {
            int xx = w + j - 2; bool v = vy && (xx >= 0 && xx < 64);
            int xc = (xx >= 0 && xx < 64) ? xx : 0;
            int k = i*5 + j;
            mk[k] = v ? mb[(long)k << 14] : 0.f;
            off[k] = (yc << 6) + xc;
        }
    }
    int c0 = gi * CG;
    for (int c = 0; c < CG; c++) {
        long fb = ((long)(b * C + c0 + c) << 12);
        long ob = ((long)(b * C + c0 + c) << 14) + px;
        const TF* fp = feat + fb;
        float acc = ADD ? add[ob] : 0.f;
        #pragma unroll
        for (int k = 0; k < 25; k++) acc += toF(fp[off[k]]) * mk[k];
        stT<TO>(out, ob, acc);
    }
}
template<int CG>
__global__ void k_carafe5_ws(const float* feat, const float* mask, const float* add,
                             float* out, int Bn, int C)
{
    carafe5_body<float, float, true, CG>(feat, mask, add, out, Bn, C);
}

// ================= group norm: slice partial stats (atomic) + apply =================
__global__ void k_gnstat(const float* __restrict__ x, float* __restrict__ stat, int statBase,
                         int S, int N)
{
    int bid = blockIdx.x;
    int bg = bid / S, sl = bid % S;
    int seg = N / S;
    long base = (long)bg * N + (long)sl * seg;
    float s = 0.f, ss = 0.f;
    for (int i = threadIdx.x; i < seg; i += TPB) {
        float v = x[base + i]; s += v; ss += v * v;
    }
    __shared__ float sh[8];
    for (int off = 32; off; off >>= 1) { s += __shfl_down(s, off); ss += __shfl_down(ss, off); }
    int wave = threadIdx.x >> 6, lane = threadIdx.x & 63;
    if (lane == 0) { sh[wave] = s; sh[4 + wave] = ss; }
    __syncthreads();
    if (threadIdx.x == 0) {
        float ts = 0.f, tss = 0.f;
        for (int i = 0; i < TPB/64; i++) { ts += sh[i]; tss += sh[4 + i]; }
        atomicAdd(&stat[statBase + bg*2], ts);
        atomicAdd(&stat[statBase + bg*2 + 1], tss);
    }
}
__global__ void k_gnapply(const float* __restrict__ x, const float* __restrict__ stat, int statBase,
                          const float* __restrict__ gamma, const float* __restrict__ beta,
                          float* __restrict__ out, int G, int Cg, int HW, int Bn)
{
    long idx = (long)blockIdx.x * TPB + threadIdx.x;
    long total = (long)Bn * G * Cg * HW;
    if (idx >= total) return;
    int bgN = Cg * HW;
    int bg = idx / bgN;
    int r  = idx % bgN;
    int g = bg % G;
    int c = g * Cg + r / HW;
    float s = stat[statBase + bg*2], ss = stat[statBase + bg*2 + 1];
    float mean = s / bgN;
    float inv = rsqrtf(ss / bgN - mean * mean + 1e-5f);
    out[idx] = (x[idx] - mean) * inv * gamma[c] + beta[c];
}

// ================= cosine sim partials (dilation 2) + finalize =================
__global__ void k_simp(const float* __restrict__ x, float* __restrict__ pbuf,
                       int Bn, int H, int W, int CS)
{
    int HW = H * W;
    int idx = blockIdx.x * TPB + threadIdx.x;
    if (idx >= Bn * HW) return;
    int chunk = blockIdx.y;
    int pix = idx % HW, b = idx / HW;
    int wx = pix % W, hy = pix / W;
    const int dyv[8] = {-2,-2,-2, 0, 0, 2, 2, 2};
    const int dxv[8] = {-2, 0, 2,-2, 2,-2, 0, 2};
    int off[8]; float msk[8];
    #pragma unroll
    for (int n = 0; n < 8; n++) {
        int yy = hy + dyv[n], xx = wx + dxv[n];
        bool v = (yy >= 0 && yy < H && xx >= 0 && xx < W);
        off[n] = v ? yy * W + xx : pix;
        msk[n] = v ? 1.f : 0.f;
    }
    float dc = 0.f, num[8], dn[8];
    #pragma unroll
    for (int n = 0; n < 8; n++) { num[n] = 0.f; dn[n] = 0.f; }
    const float* xb = x + ((long)b * 64 + chunk * CS) * HW;
    #pragma unroll 2
    for (int ci = 0; ci < CS; ci++) {
        const float* xc = xb + (long)ci * HW;
        float c0 = xc[pix];
        dc += c0 * c0;
        #pragma unroll
        for (int n = 0; n < 8; n++) {
            float v = xc[off[n]] * msk[n];
            num[n] += c0 * v; dn[n] += v * v;
        }
    }
    long base = ((long)chunk * Bn + b) * 17 * (long)HW + pix;
    pbuf[base] = dc;
    #pragma unroll
    for (int n = 0; n < 8; n++) {
        pbuf[base + (long)(1 + n) * HW] = num[n];
        pbuf[base + (long)(9 + n) * HW] = dn[n];
    }
}
__global__ void k_simr(const float* __restrict__ pbuf, float* __restrict__ out,
                       int Bn, int HW, int nChunk)
{
    int idx = blockIdx.x * TPB + threadIdx.x;
    if (idx >= Bn * HW) return;
    int pix = idx % HW, b = idx / HW;
    float dc = 0.f, num[8], dn[8];
    #pragma unroll
    for (int n = 0; n < 8; n++) { num[n] = 0.f; dn[n] = 0.f; }
    for (int ch = 0; ch < nChunk; ch++) {
        long base = ((long)ch * Bn + b) * 17 * (long)HW + pix;
        dc += pbuf[base];
        #pragma unroll
        for (int n = 0; n < 8; n++) {
            num[n] += pbuf[base + (long)(1 + n) * HW];
            dn[n]  += pbuf[base + (long)(9 + n) * HW];
        }
    }
    float nc = fmaxf(sqrtf(dc), 1e-8f);
    #pragma unroll
    for (int n = 0; n < 8; n++)
        out[((long)(b*8 + n)) * HW + pix] = num[n] / (nc * fmaxf(sqrtf(dn[n]), 1e-8f));
}

// ================= offset assembly =================
__global__ void k_offset(const float* __restrict__ lro, const float* __restrict__ hro,
                         const float* __restrict__ lrd, const float* __restrict__ hrd,
                         float* __restrict__ outoff, int B)
{
    int idx = blockIdx.x * TPB + threadIdx.x;
    int total = B * 32 * 64 * 64;
    if (idx >= total) return;
    int wx = idx & 63;
    int hy = (idx >> 6) & 63;
    int o  = (idx >> 12) & 31;
    int b  = idx >> 17;
    int c = o >> 2, p = (o >> 1) & 1, q = o & 1;
    long hridx = ((long)(b*8 + c) * 128 + 2*hy + p) * 128 + 2*wx + q;
    float off = lro[idx] + hro[hridx];
    float dsv = lrd[idx] + hrd[hridx];
    float sg = 1.f / (1.f + expf(-dsv));
    int comp = o >> 4;
    float ip = (comp == 0) ? (q ? 0.25f : -0.25f) : (p ? 0.25f : -0.25f);
    outoff[idx] = off * sg + ip;
}

// ===== grid sample from transposed lrupT[b][pix][256], grid.y = channel half =====
template<typename OT>
__device__ void gridsampleT_body(const unsigned short* __restrict__ lrupT,
                                 const float* __restrict__ offb, OT* __restrict__ out, int Bn)
{
    int idx = blockIdx.x * TPB + threadIdx.x;
    if (idx >= Bn * 4 * 16384) return;
    int ch0 = blockIdx.y << 5;            // 2 halves of 32 channels
    int opix = idx & 16383;
    int g = (idx >> 14) & 3, b = idx >> 16;
    int X = opix & 127, Y = opix >> 7;
    int h = Y >> 1, p = Y & 1, w = X >> 1, q = X & 1;
    int r = g*4 + p*2 + q;
    float offx = offb[((long)(b*32 + r)      << 12) + (h << 6) + w];
    float offy = offb[((long)(b*32 + 16 + r) << 12) + (h << 6) + w];
    float gx = fminf(fmaxf(2.f * (w + 0.5f + offx) - 0.5f, 0.f), 127.f);
    float gy = fminf(fmaxf(2.f * (h + 0.5f + offy) - 0.5f, 0.f), 127.f);
    float x0f = floorf(gx), y0f = floorf(gy);
    float tx = gx - x0f, ty = gy - y0f;
    int x0 = (int)x0f, y0 = (int)y0f;
    int x1 = min(x0 + 1, 127), y1 = min(y0 + 1, 127);
    float w11 = tx * ty, w10 = ty - w11, w01 = tx - w11, w00 = 1.f - tx - ty + w11;
    const unsigned short* base = lrupT + (((long)b << 14) << 8) + (g << 6) + ch0;
    long a00 = ((long)((y0 << 7) + x0)) << 8, a01 = ((long)((y0 << 7) + x1)) << 8;
    long a10 = ((long)((y1 << 7) + x0)) << 8, a11 = ((long)((y1 << 7) + x1)) << 8;
    OT* op = out + ((long)(b * 256 + g * 64 + ch0) << 14) + opix;
    #pragma unroll
    for (int c8 = 0; c8 < 4; c8++) {
        uint4 v00 = *(const uint4*)(base + a00 + c8*8);
        uint4 v01 = *(const uint4*)(base + a01 + c8*8);
        uint4 v10 = *(const uint4*)(base + a10 + c8*8);
        uint4 v11 = *(const uint4*)(base + a11 + c8*8);
        const unsigned short* u00 = (const unsigned short*)&v00;
        const unsigned short* u01 = (const unsigned short*)&v01;
        const unsigned short* u10 = (const unsigned short*)&v10;
        const unsigned short* u11 = (const unsigned short*)&v11;
        #pragma unroll
        for (int t = 0; t < 8; t++) {
            float res = bfu(u00[t])*w00 + bfu(u01[t])*w01 + bfu(u10[t])*w10 + bfu(u11[t])*w11;
            stT<OT>(op, ((long)(c8*8 + t) << 14), res);
        }
    }
}
__global__ void k_gridsampleT(const bf16* lrupT, const float* offb, void* out, long outOff,
                              int Bn, const int* flag)
{
    if (*flag) gridsampleT_body<float>((const unsigned short*)lrupT, offb, (float*)out + outOff, Bn);
    else       gridsampleT_body<bf16 >((const unsigned short*)lrupT, offb, (bf16*)out + outOff, Bn);
}

extern "C" void kernel_launch(void* const* d_in, const int* in_sizes, int n_in,
                              void* d_out, int out_size, void* d_ws, size_t ws_size,
                              hipStream_t stream) {
    const void* hr_feat = d_in[0];
    const void* lr_feat = d_in[1];

    const int B = 2, HH = 128, HL = 64;
    const int HWH = HH*HH, HWL = HL*HL;

    int*   flag = (int*)d_ws;
    float* stat = (float*)d_ws + 4;
    float* P    = (float*)d_ws + 80;
    float* ws   = P + ((P_TOT + 63) & ~63);

    size_t o = 0;
    float* ch0    = ws + o; o += (size_t)B*64*HWH;
    float* clb    = ws + o; o += (size_t)B*64*HWL;
    float* maskHH = ws + o; o += (size_t)B*9*HWH;
    float* tmp9   = ws + o; o += (size_t)B*9*HWH;
    float* chn    = ws + o; o += (size_t)B*64*HWH;
    float* m25a   = ws + o; o += (size_t)B*25*HWH;
    float* m25b   = ws + o; o += (size_t)B*25*HWH;
    float* m25c   = ws + o; o += (size_t)B*25*HWH;
    float* enccl  = ws + o; o += (size_t)B*25*HWL;
    float* enc2cl = ws + o; o += (size_t)B*9*HWL;
    bf16*  lrupT  = (bf16*)(ws + o); o += (size_t)B*256*HWH/2;   // transposed lr_up [b][pix][256]
    float* lrx    = ws + o; o += (size_t)B*64*HWL;
    float* hrsim  = ws + o; o += (size_t)B*8*HWH;
    float* lrsim  = ws + o; o += (size_t)B*8*HWL;
    float* qhro   = ws + o; o += (size_t)B*8*HWH;
    float* qlro   = ws + o; o += (size_t)B*32*HWL;
    float* qhrd   = ws + o; o += (size_t)B*8*HWH;
    float* qlrd   = ws + o; o += (size_t)B*32*HWL;
    float* offb   = ws + o; o += (size_t)B*32*HWL;
    float* hrx   = ch0;     // ch0 dead after step 5
    float* maskH = m25b;    // m25b dead after step 9
    // partial/scratch aliases over verified-dead zones:
    float* pbufA  = maskHH;          // steps 1-2
    float* pbufL8 = (float*)lrupT;   // steps 8,11 (before step 15 writes lrupT)
    float* pbufT  = chn;             // steps 18-21,23
    bf16*  lrfT   = (bf16*)hrsim;    // lr_feat transposed [b][4096][256] bf16
    (void)ws_size; (void)n_in;

    long out1Off = (long)B*25*HWH;
    long out2Off = out1Off + (long)B*256*HWH;

    const float* pw_hrc = P + P_W_HRC;  const float* pb_hrc = P + P_B_HRC;
    const float* pw_lrc = P + P_W_LRC;  const float* pb_lrc = P + P_B_LRC;
    const float* pw_enc = P + P_W_ENC;  const float* pb_enc = P + P_B_ENC;
    const float* pw_enc2= P + P_W_ENC2; const float* pb_enc2= P + P_B_ENC2;
    const float* pgnhw  = P + P_GNHW;   const float* pgnhb  = P + P_GNHB;
    const float* pgnlw  = P + P_GNLW;   const float* pgnlb  = P + P_GNLB;
    const float* pw_off = P + P_W_OFF;  const float* pb_off = P + P_B_OFF;
    const float* pw_hoff= P + P_W_HOFF; const float* pb_hoff= P + P_B_HOFF;
    const float* pw_ds  = P + P_W_DS;   const float* pb_ds  = P + P_B_DS;
    const float* pw_hds = P + P_W_HDS;  const float* pb_hds = P + P_B_HDS;

    // 0. dtype detect + weight prep + lr_feat transpose (channels-last)
    int nDet = in_sizes[0] < 16384 ? in_sizes[0] : 16384;
    k_detect<<<1, TPB, 0, stream>>>(hr_feat, nDet, flag, stat);
    k_prep<<<nblk(P_TOT), TPB, 0, stream>>>(d_in[2],d_in[3],d_in[4],d_in[5],d_in[6],d_in[7],
        d_in[8],d_in[9],d_in[10],d_in[11],d_in[12],d_in[13],d_in[14],d_in[15],d_in[16],
        d_in[17],d_in[18],d_in[19],d_in[20],d_in[21], P, flag);
    k_transpLR<<<B*4*64, TPB, 0, stream>>>(lr_feat, lrfT, B, flag);

    // 1. ch0 = 1x1(hr_feat): 4 chunks x CS64 (R1 path)
    k_conv1x1p<<<dim3(nblk((long)B*HWH),4), TPB, 0, stream>>>(hr_feat, pw_hrc, pbufA, B, 256, HWH, 64, flag);
    k_convr<<<nblk((long)B*64*HWH), TPB, 0, stream>>>(pbufA, pb_hrc, ch0, B, 64, HWH, 4);
    // 2. clb = 1x1(lr_feat): 16 chunks x CS16 (R1 path)
    k_conv1x1p<<<dim3(nblk((long)B*HWL),16), TPB, 0, stream>>>(lr_feat, pw_lrc, pbufA, B, 256, HWL, 16, flag);
    k_convr<<<nblk((long)B*64*HWL), TPB, 0, stream>>>(pbufA, pb_lrc, clb, B, 64, HWL, 16);
    // 3. mask_hr_hr = 3x3(ch0) -> 9co: lean LDS conv, 3 co-groups of 3
    k_conv3x3t<3><<<dim3(B*64,3), TPB, 0, stream>>>(ch0, pw_enc2, pb_enc2, maskHH, HH, HH, 9);
    // 4-5. mh_init, ch = 2*ch0 - carafe3(ch0)
    k_knorm<3><<<nblk((long)B*HWH), TPB, 0, stream>>>(maskHH, tmp9, nullptr, B, HH, HH, flag);
    k_carafe3c_ws<<<nblk((long)B*8*16384), TPB, 0, stream>>>(ch0, tmp9, chn, B);
    // 6. mask_lr_hr = 3x3(chn) -> 25co: lean LDS conv, 5 co-groups of 5
    k_conv3x3t<5><<<dim3(B*64,5), TPB, 0, stream>>>(chn, pw_enc, pb_enc, m25a, HH, HH, 25);
    // 7. ml_init -> m25b
    k_knorm<5><<<nblk((long)B*HWH), TPB, 0, stream>>>(m25a, m25b, nullptr, B, HH, HH, flag);
    // 8. enccl: 16 chunks x CS4 (R1 path)
    k_conv3x3p<25><<<dim3(nblk((long)B*HWL),16), TPB, 0, stream>>>(clb, pw_enc, pbufL8, B, 64, HL, HL, 4);
    k_convr<<<nblk((long)B*25*HWL), TPB, 0, stream>>>(pbufL8, pb_enc, enccl, B, 25, HWL, 16);
    // 9. mask_lr = mask_lr_hr + carafe5(enccl, ml_init): C=25, CG=5
    k_carafe5_ws<5><<<nblk((long)B*5*16384), TPB, 0, stream>>>(enccl, m25b, m25a, m25c, B, 25);
    // 10. mask_lr_n -> m25a + bf16 output 0
    k_knorm<5><<<nblk((long)B*HWH), TPB, 0, stream>>>(m25c, m25a, d_out, B, HH, HH, flag);
    // 11. enc2cl: 16 chunks x CS4 (R1 path)
    k_conv3x3p<9><<<dim3(nblk((long)B*HWL),16), TPB, 0, stream>>>(clb, pw_enc2, pbufL8, B, 64, HL, HL, 4);
    k_convr<<<nblk((long)B*9*HWL), TPB, 0, stream>>>(pbufL8, pb_enc2, enc2cl, B, 9, HWL, 16);
    // 12. mask_hr = mask_hr_hr + carafe5(enc2cl, mask_lr_n): C=9, CG=3
    k_carafe5_ws<3><<<nblk((long)B*3*16384), TPB, 0, stream>>>(enc2cl, m25a, maskHH, maskH, B, 9);
    // 13-14. mask_hr_n, hr_out -> output 1
    k_knorm<3><<<nblk((long)B*HWH), TPB, 0, stream>>>(maskH, tmp9, nullptr, B, HH, HH, flag);
    k_carafe3c_io<<<nblk((long)B*32*16384), TPB, 0, stream>>>(hr_feat, tmp9, d_out, out1Off, B, flag);
    // 15. lr_up (transposed): wave=(b,ipix), lane=4-channel group; XCD-swizzled
    k_carafe5T<<<B*4096/4, TPB, 0, stream>>>(lrfT, m25a, lrupT, B);
    // 16-17. group norms
    k_gnstat<<<16*32, TPB, 0, stream>>>(chn, stat, 0, 32, 8*HWH);
    k_gnapply<<<nblk((long)B*64*HWH), TPB, 0, stream>>>(chn, stat, 0, pgnhw, pgnhb, hrx, 8, 8, HWH, B);
    k_gnstat<<<16*8, TPB, 0, stream>>>(clb, stat, 32, 8, 8*HWL);
    k_gnapply<<<nblk((long)B*64*HWL), TPB, 0, stream>>>(clb, stat, 32, pgnlw, pgnlb, lrx, 8, 8, HWL, B);
    // 18. hrsim: 8 chunks x CS8
    k_simp<<<dim3(nblk((long)B*HWH),8), TPB, 0, stream>>>(hrx, pbufT, B, HH, HH, 8);
    k_simr<<<nblk((long)B*HWH), TPB, 0, stream>>>(pbufT, hrsim, B, HWH, 8);
    // 19. lrsim: 16 chunks x CS4
    k_simp<<<dim3(nblk((long)B*HWL),16), TPB, 0, stream>>>(lrx, pbufT, B, HL, HL, 4);
    k_simr<<<nblk((long)B*HWL), TPB, 0, stream>>>(pbufT, lrsim, B, HWL, 16);
    // 20. qhro: 4 chunks x CS2 (CIN=8, R1 path)
    k_conv3x3p<8><<<dim3(nblk((long)B*HWH),4), TPB, 0, stream>>>(hrsim, pw_hoff, pbufT, B, 8, HH, HH, 2);
    k_convr<<<nblk((long)B*8*HWH), TPB, 0, stream>>>(pbufT, pb_hoff, qhro, B, 8, HWH, 4);
    // 21. qlro: 8 chunks x CS1 (CIN=8, R1 path)
    k_conv3x3p<32><<<dim3(nblk((long)B*HWL),8), TPB, 0, stream>>>(lrsim, pw_off, pbufT, B, 8, HL, HL, 1);
    k_convr<<<nblk((long)B*32*HWL), TPB, 0, stream>>>(pbufT, pb_off, qlro, B, 32, HWL, 8);
    // 22. qhrd = 3x3(hrx) -> 8co: lean LDS conv, 4 co-groups of 2
    k_conv3x3t<2><<<dim3(B*64,4), TPB, 0, stream>>>(hrx, pw_hds, pb_hds, qhrd, HH, HH, 8);
    // 23. qlrd: 16 chunks x CS4 (R1 path)
    k_conv3x3p<32><<<dim3(nblk((long)B*HWL),16), TPB, 0, stream>>>(lrx, pw_ds, pbufT, B, 64, HL, HL, 4);
    k_convr<<<nblk((long)B*32*HWL), TPB, 0, stream>>>(pbufT, pb_ds, qlrd, B, 32, HWL, 16);
    // 24. offset assembly
    k_offset<<<nblk((long)B*32*HWL), TPB, 0, stream>>>(qlro, qhro, qlrd, qhrd, offb, B);
    // 25. grid sample from lrupT -> output 2 (2 channel halves)
    k_gridsampleT<<<dim3(nblk((long)B*4*HWH),2), TPB, 0, stream>>>(lrupT, offb, d_out, out2Off, B, flag);
}

// Round 8
// 571.186 us; speedup vs baseline: 2.7968x; 1.7015x over previous
//
#include <hip/hip_runtime.h>
#include <hip/hip_bf16.h>

typedef __hip_bfloat16 bf16;
#define TPB 256

__device__ __forceinline__ float toF(float v){ return v; }
__device__ __forceinline__ float toF(bf16 v){ return __bfloat162float(v); }
__device__ __forceinline__ float bfu(unsigned short u){
    unsigned int x = ((unsigned int)u) << 16;
    return __uint_as_float(x);
}
template<typename T> __device__ __forceinline__ void stT(T* p, long i, float v);
template<> __device__ __forceinline__ void stT<float>(float* p, long i, float v){ p[i] = v; }
template<> __device__ __forceinline__ void stT<bf16>(bf16* p, long i, float v){ p[i] = __float2bfloat16(v); }

__device__ __forceinline__ void st4bf(bf16* p, const float* a){
    bf16 t0 = __float2bfloat16(a[0]);
    bf16 t1 = __float2bfloat16(a[1]);
    bf16 t2 = __float2bfloat16(a[2]);
    bf16 t3 = __float2bfloat16(a[3]);
    ushort4 pk;
    pk.x = *(unsigned short*)&t0;
    pk.y = *(unsigned short*)&t1;
    pk.z = *(unsigned short*)&t2;
    pk.w = *(unsigned short*)&t3;
    *(ushort4*)p = pk;
}

static inline int nblk(long n){ return (int)((n + TPB - 1) / TPB); }

// ================= dtype detection + stat zero =================
__global__ void k_detect(const void* hr, int n, int* flag, float* stat)
{
    if (threadIdx.x < 64) stat[threadIdx.x] = 0.f;
    const unsigned short* u = (const unsigned short*)hr;
    int nan = 0, oz = 0, ot = 0;
    for (int i = threadIdx.x; i < n; i += TPB) {
        unsigned short a = u[i] & 0x7FFF;
        if (a >= 0x7F80) nan++;
        if (i & 1) { ot++; if (a == 0) oz++; }
    }
    __shared__ int s1[TPB], s2[TPB], s3[TPB];
    s1[threadIdx.x] = nan; s2[threadIdx.x] = oz; s3[threadIdx.x] = ot;
    __syncthreads();
    if (threadIdx.x == 0) {
        int a = 0, b = 0, c = 0;
        for (int i = 0; i < TPB; i++) { a += s1[i]; b += s2[i]; c += s3[i]; }
        *flag = (a >= 6 || (long)b * 10 >= (long)c * 9) ? 1 : 0;
    }
}

// ================= weight prep: fp32 + transpose to [ci][co][taps] =================
#define P_W_HRC 0
#define P_B_HRC 16384
#define P_W_LRC 16448
#define P_B_LRC 32832
#define P_W_ENC 32896
#define P_B_ENC 47296
#define P_W_ENC2 47321
#define P_B_ENC2 52505
#define P_GNHW 52514
#define P_GNHB 52578
#define P_GNLW 52642
#define P_GNLB 52706
#define P_W_OFF 52770
#define P_B_OFF 55074
#define P_W_HOFF 55106
#define P_B_HOFF 55682
#define P_W_DS 55690
#define P_B_DS 74122
#define P_W_HDS 74154
#define P_B_HDS 78762
#define P_TOT 78770

__constant__ int c_segsz[20]  = {16384,64,16384,64,14400,25,5184,9,64,64,64,64,2304,32,576,8,18432,32,4608,8};
__constant__ int c_segbase[20]= {P_W_HRC,P_B_HRC,P_W_LRC,P_B_LRC,P_W_ENC,P_B_ENC,P_W_ENC2,P_B_ENC2,
                                 P_GNHW,P_GNHB,P_GNLW,P_GNLB,P_W_OFF,P_B_OFF,P_W_HOFF,P_B_HOFF,
                                 P_W_DS,P_B_DS,P_W_HDS,P_B_HDS};
__constant__ int c_segcin[20] = {256,0,256,0, 64,0, 64,0, 0,0,0,0, 8,0, 8,0, 64,0, 64,0};
__constant__ int c_segcout[20]= { 64,0, 64,0, 25,0,  9,0, 0,0,0,0,32,0, 8,0, 32,0,  8,0};
__constant__ int c_segtap[20] = {  1,0,  1,0,  9,0,  9,0, 0,0,0,0, 9,0, 9,0,  9,0,  9,0};

__global__ void k_prep(const void* p0,const void* p1,const void* p2,const void* p3,
                       const void* p4,const void* p5,const void* p6,const void* p7,
                       const void* p8,const void* p9,const void* p10,const void* p11,
                       const void* p12,const void* p13,const void* p14,const void* p15,
                       const void* p16,const void* p17,const void* p18,const void* p19,
                       float* dst, const int* flag)
{
    int idx = blockIdx.x * TPB + threadIdx.x;
    if (idx >= P_TOT) return;
    int s = 0, off = idx;
    while (off >= c_segsz[s]) { off -= c_segsz[s]; s++; }
    const void* sp;
    switch (s) {
        case 0: sp=p0; break;  case 1: sp=p1; break;  case 2: sp=p2; break;  case 3: sp=p3; break;
        case 4: sp=p4; break;  case 5: sp=p5; break;  case 6: sp=p6; break;  case 7: sp=p7; break;
        case 8: sp=p8; break;  case 9: sp=p9; break;  case 10: sp=p10; break; case 11: sp=p11; break;
        case 12: sp=p12; break; case 13: sp=p13; break; case 14: sp=p14; break; case 15: sp=p15; break;
        case 16: sp=p16; break; case 17: sp=p17; break; case 18: sp=p18; break; default: sp=p19; break;
    }
    float v = (*flag) ? ((const float*)sp)[off] : toF(((const bf16*)sp)[off]);
    int doff = off;
    int cin = c_segcin[s];
    if (cin) {
        int t = c_segtap[s], cout = c_segcout[s];
        int co = off / (cin * t);
        int r  = off % (cin * t);
        int ci = r / t, k = r % t;
        doff = (ci * cout + co) * t + k;
    }
    dst[c_segbase[s] + doff] = v;
}

// ================= lr_feat transpose: [b][256][4096] -> bf16 [b][4096][256] =============
template<typename T>
__device__ void transpLR_body(const T* __restrict__ x, bf16* __restrict__ xT, int Bn)
{
    __shared__ float tile[64][65];
    int bid = blockIdx.x;                 // b * 4 cgroup * 64 pgroup
    int pg = bid & 63;
    int cg = (bid >> 6) & 3;
    int b  = bid >> 8;
    int tid = threadIdx.x;
    int tr = tid >> 6, tc = tid & 63;
    for (int i = 0; i < 16; i++) {
        int c = tr + i * 4;
        tile[c][tc] = toF(x[(((long)(b * 256 + cg * 64 + c)) << 12) + (pg << 6) + tc]);
    }
    __syncthreads();
    for (int i = 0; i < 16; i++) {
        int p = tr + i * 4;
        xT[((((long)b << 12) + (pg << 6) + p) << 8) + (cg << 6) + tc] = __float2bfloat16(tile[tc][p]);
    }
}
__global__ void k_transpLR(const void* x, bf16* xT, int Bn, const int* flag)
{
    if (*flag) transpLR_body<float>((const float*)x, xT, Bn);
    else       transpLR_body<bf16 >((const bf16*)x,  xT, Bn);
}

// ===== carafe5-up channels-last: wave = (b, ipix), lane = 4-channel group =====
__global__ void k_carafe5T(const bf16* __restrict__ featT, const float* __restrict__ mask,
                           bf16* __restrict__ outT, int Bn)
{
    int lane = threadIdx.x & 63;
    int nwg = gridDim.x;
    int bid = blockIdx.x;
    int swz = (nwg & 7) ? bid : ((bid & 7) * (nwg >> 3) + (bid >> 3));
    int wid = (swz << 2) | (threadIdx.x >> 6);
    wid = __builtin_amdgcn_readfirstlane(wid);
    if (wid >= Bn * 4096) return;
    int ipix = wid & 4095;
    int b    = wid >> 12;
    int h = ipix >> 6, w = ipix & 63;
    const bf16*  fb = featT + (((long)b << 12) << 8) + (lane << 2);
    const float* mb = mask + (((long)b * 25) << 14) + (h << 8) + (w << 1);
    float a00[4], a01[4], a10[4], a11[4];
    #pragma unroll
    for (int t = 0; t < 4; t++) { a00[t]=0.f; a01[t]=0.f; a10[t]=0.f; a11[t]=0.f; }
    #pragma unroll
    for (int k = 0; k < 25; k++) {
        const int i = k / 5, j = k % 5;
        int yy = h + i - 2, xx = w + j - 2;
        bool v = (yy >= 0 && yy < 64 && xx >= 0 && xx < 64);
        int yc = v ? yy : 0, xc = v ? xx : 0;
        ushort4 u = *(const ushort4*)(fb + ((long)((yc << 6) + xc) << 8));
        float2 mr0 = *(const float2*)(mb + ((long)k << 14));
        float2 mr1 = *(const float2*)(mb + ((long)k << 14) + 128);
        float m00 = v ? mr0.x : 0.f, m01 = v ? mr0.y : 0.f;
        float m10 = v ? mr1.x : 0.f, m11 = v ? mr1.y : 0.f;
        float f0 = bfu(u.x), f1 = bfu(u.y), f2 = bfu(u.z), f3 = bfu(u.w);
        a00[0] += f0*m00; a00[1] += f1*m00; a00[2] += f2*m00; a00[3] += f3*m00;
        a01[0] += f0*m01; a01[1] += f1*m01; a01[2] += f2*m01; a01[3] += f3*m01;
        a10[0] += f0*m10; a10[1] += f1*m10; a10[2] += f2*m10; a10[3] += f3*m10;
        a11[0] += f0*m11; a11[1] += f1*m11; a11[2] += f2*m11; a11[3] += f3*m11;
    }
    bf16* op = outT + (((long)(b << 14) + (h << 8) + (w << 1)) << 8) + (lane << 2);
    st4bf(op, a00);                       // (2h,   2w)
    st4bf(op + 256, a01);                 // (2h,   2w+1)
    st4bf(op + (128 << 8), a10);          // (2h+1, 2w)
    st4bf(op + (128 << 8) + 256, a11);    // (2h+1, 2w+1)
}

// ================= 3x3 conv partials: grid.y = ci-chunk =================
template<int COUT>
__global__ void k_conv3x3p(const float* __restrict__ x, const float* __restrict__ wf,
                           float* __restrict__ pbuf, int Bn, int CIN, int H, int W, int CS)
{
    int HW = H * W;
    int idx = blockIdx.x * TPB + threadIdx.x;
    if (idx >= Bn * HW) return;
    int chunk = blockIdx.y;
    int pix = idx % HW, b = idx / HW;
    int wx = pix % W, hy = pix / W;
    int off[9]; float msk[9];
    #pragma unroll
    for (int i = 0; i < 3; i++) {
        int yy = hy + i - 1; bool vy = (yy >= 0 && yy < H); int yc = vy ? yy : hy;
        #pragma unroll
        for (int j = 0; j < 3; j++) {
            int xx = wx + j - 1; bool v = vy && (xx >= 0 && xx < W);
            int xc = (xx >= 0 && xx < W) ? xx : wx;
            off[i*3+j] = yc * W + xc; msk[i*3+j] = v ? 1.f : 0.f;
        }
    }
    float acc[COUT];
    #pragma unroll
    for (int co = 0; co < COUT; co++) acc[co] = 0.f;
    int c0 = chunk * CS;
    const float* xb = x + ((long)b * CIN + c0) * HW;
    const float* wb = wf + (long)c0 * COUT * 9;
    #pragma unroll 2
    for (int ci = 0; ci < CS; ci++) {
        const float* xc = xb + (long)ci * HW;
        float t[9];
        #pragma unroll
        for (int k = 0; k < 9; k++) t[k] = xc[off[k]] * msk[k];
        const float* wr = wb + (long)ci * COUT * 9;
        #pragma unroll
        for (int co = 0; co < COUT; co++) {
            const float* wp = wr + co * 9;
            acc[co] += t[0]*wp[0] + t[1]*wp[1] + t[2]*wp[2] + t[3]*wp[3] + t[4]*wp[4]
                     + t[5]*wp[5] + t[6]*wp[6] + t[7]*wp[7] + t[8]*wp[8];
        }
    }
    long pb = ((long)chunk * Bn + b) * COUT * (long)HW + pix;
    #pragma unroll
    for (int co = 0; co < COUT; co++) pbuf[pb + (long)co * HW] = acc[co];
}

// ================= conv reduce: out = bias + sum_chunks partial =================
__global__ void k_convr(const float* __restrict__ pbuf, const float* __restrict__ bias,
                        float* __restrict__ out, int Bn, int COUT, int HW, int nChunk)
{
    long idx = (long)blockIdx.x * TPB + threadIdx.x;
    if (idx >= (long)Bn * COUT * HW) return;
    int pix = idx % HW;
    int co  = (idx / HW) % COUT;
    int b   = idx / ((long)HW * COUT);
    float v = bias[co];
    for (int ch = 0; ch < nChunk; ch++)
        v += pbuf[(((long)ch * Bn + b) * COUT + co) * HW + pix];
    out[idx] = v;
}

// ================= 1x1 conv partials (COUT=64), grid.y = chunk =================
template<typename T>
__device__ void conv1x1p_body(const T* __restrict__ x, const float* __restrict__ wf,
                              float* __restrict__ pbuf, int Bn, int CIN, int HW, int CS)
{
    int idx = blockIdx.x * TPB + threadIdx.x;
    if (idx >= Bn * HW) return;
    int chunk = blockIdx.y;
    int pix = idx % HW, b = idx / HW;
    float acc[64];
    #pragma unroll
    for (int co = 0; co < 64; co++) acc[co] = 0.f;
    int c0 = chunk * CS;
    const T* xp = x + ((long)b * CIN + c0) * HW + pix;
    const float* wb = wf + (long)c0 * 64;
    #pragma unroll 2
    for (int ci = 0; ci < CS; ci++) {
        float v = toF(xp[(long)ci * HW]);
        const float* wr = wb + ci * 64;
        #pragma unroll
        for (int co = 0; co < 64; co++) acc[co] += v * wr[co];
    }
    long pb = ((long)chunk * Bn + b) * 64 * (long)HW + pix;
    #pragma unroll
    for (int co = 0; co < 64; co++) pbuf[pb + (long)co * HW] = acc[co];
}
__global__ void k_conv1x1p(const void* x, const float* wf, float* pbuf,
                           int Bn, int CIN, int HW, int CS, const int* flag)
{
    if (*flag) conv1x1p_body<float>((const float*)x, wf, pbuf, Bn, CIN, HW, CS);
    else       conv1x1p_body<bf16 >((const bf16*)x,  wf, pbuf, Bn, CIN, HW, CS);
}

// ================= kernel_normalizer (planar in/out) =================
template<int K, typename OT>
__device__ void knorm_body(const float* __restrict__ mask, float* __restrict__ out,
                           OT* __restrict__ outb, int B, int H, int W)
{
    const int K2 = K * K;
    int HWi = H * W;
    int idx = blockIdx.x * TPB + threadIdx.x;
    if (idx >= B * HWi) return;
    int pix = idx % HWi;
    int b   = idx / HWi;
    long HW = (long)HWi;
    long base = (long)b * K2 * HW + pix;
    float v[K2];
    float m = -1e30f;
    for (int k = 0; k < K2; k++) { v[k] = mask[base + k*HW]; m = fmaxf(m, v[k]); }
    float s2 = 0.f;
    for (int k = 0; k < K2; k++) {
        int i = k / K, j = k % K;
        float hi = (K == 3) ? ((i==1)?1.f:0.08f) : ((i==2)?1.f:((i==1||i==3)?0.54f:0.08f));
        float hj = (K == 3) ? ((j==1)?1.f:0.08f) : ((j==2)?1.f:((j==1||j==3)?0.54f:0.08f));
        v[k] = expf(v[k] - m) * hi * hj;
        s2 += v[k];
    }
    float inv = 1.f / s2;
    for (int k = 0; k < K2; k++) {
        float r = v[k] * inv;
        out[base + k*HW] = r;
        if (outb) stT<OT>(outb, base + k*HW, r);
    }
}
template<int K>
__global__ void k_knorm(const float* mask, float* out, void* outb, int B, int H, int W, const int* flag)
{
    if (*flag) knorm_body<K, float>(mask, out, (float*)outb, B, H, W);
    else       knorm_body<K, bf16>(mask, out, (bf16*)outb, B, H, W);
}

// ================= carafe3 (2*f - carafe), planar mask, 8 channels/thread ============
template<typename TF, typename TO, int NC>
__device__ void carafe3c_body(const TF* __restrict__ feat, const float* __restrict__ mask,
                              TO* __restrict__ out, int Bn)
{
    constexpr int CH = NC / 8;
    int idx = blockIdx.x * TPB + threadIdx.x;
    if (idx >= Bn * CH * 16384) return;
    int px = idx & 16383;
    int cc = (idx >> 14) % CH;
    int b  = (idx >> 14) / CH;
    int wx = px & 127, hy = px >> 7;
    float mk[9]; int off[9];
    #pragma unroll
    for (int i = 0; i < 3; i++) {
        int yy = hy + i - 1; bool vy = (yy >= 0 && yy < 128); int yc = vy ? yy : hy;
        #pragma unroll
        for (int j = 0; j < 3; j++) {
            int xx = wx + j - 1; bool v = vy && (xx >= 0 && xx < 128);
            int xc = (xx >= 0 && xx < 128) ? xx : wx;
            int k = i*3 + j;
            float m = mask[(((long)b*9 + k) << 14) + px];
            mk[k] = v ? m : 0.f;
            off[k] = (yc << 7) + xc;
        }
    }
    long base = ((long)(b * NC + cc * 8) << 14);
    for (int c = 0; c < 8; c++) {
        const TF* fp = feat + base + ((long)c << 14);
        float ctr = 0.f, acc = 0.f;
        #pragma unroll
        for (int k = 0; k < 9; k++) {
            float v = toF(fp[off[k]]);
            if (k == 4) ctr = v;
            acc += v * mk[k];
        }
        stT<TO>(out, base + ((long)c << 14) + px, 2.f * ctr - acc);
    }
}
__global__ void k_carafe3c_ws(const float* feat, const float* mask, float* out, int Bn)
{
    carafe3c_body<float, float, 64>(feat, mask, out, Bn);
}
__global__ void k_carafe3c_io(const void* feat, const float* mask, void* out, long outOff,
                              int Bn, const int* flag)
{
    if (*flag) carafe3c_body<float, float, 256>((const float*)feat, mask, (float*)out + outOff, Bn);
    else       carafe3c_body<bf16, bf16, 256>((const bf16*)feat, mask, (bf16*)out + outOff, Bn);
}

// ===== carafe5 s=2 ws variant: thread = output pixel x channel-group; planar mask =====
template<typename TF, typename TO, bool ADD, int CG>
__device__ void carafe5_body(const TF* __restrict__ feat, const float* __restrict__ mask,
                             const float* __restrict__ add, TO* __restrict__ out,
                             int Bn, int C)
{
    int ng = C / CG;
    int idx = blockIdx.x * TPB + threadIdx.x;
    if (idx >= Bn * ng * 16384) return;
    int px = idx & 16383;
    int gi = (idx >> 14) % ng;
    int b  = (idx >> 14) / ng;
    int X = px & 127, Y = px >> 7;
    int h = Y >> 1, w = X >> 1;
    float mk[25]; int off[25];
    const float* mb = mask + (((long)b * 25) << 14) + px;
    #pragma unroll
    for (int i = 0; i < 5; i++) {
        int yy = h + i - 2; bool vy = (yy >= 0 && yy < 64); int yc = vy ? yy : 0;
        #pragma unroll
        for (int j = 0; j < 5; j++) {
            int xx = w + j - 2; bool v = vy && (xx >= 0 && xx < 64);
            int xc = (xx >= 0 && xx < 64) ? xx : 0;
            int k = i*5 + j;
            mk[k] = v ? mb[(long)k << 14] : 0.f;
            off[k] = (yc << 6) + xc;
        }
    }
    int c0 = gi * CG;
    for (int c = 0; c < CG; c++) {
        long fb = ((long)(b * C + c0 + c) << 12);
        long ob = ((long)(b * C + c0 + c) << 14) + px;
        const TF* fp = feat + fb;
        float acc = ADD ? add[ob] : 0.f;
        #pragma unroll
        for (int k = 0; k < 25; k++) acc += toF(fp[off[k]]) * mk[k];
        stT<TO>(out, ob, acc);
    }
}
template<int CG>
__global__ void k_carafe5_ws(const float* feat, const float* mask, const float* add,
                             float* out, int Bn, int C)
{
    carafe5_body<float, float, true, CG>(feat, mask, add, out, Bn, C);
}

// ================= group norm: slice partial stats (atomic) + apply =================
__global__ void k_gnstat(const float* __restrict__ x, float* __restrict__ stat, int statBase,
                         int S, int N)
{
    int bid = blockIdx.x;
    int bg = bid / S, sl = bid % S;
    int seg = N / S;
    long base = (long)bg * N + (long)sl * seg;
    float s = 0.f, ss = 0.f;
    for (int i = threadIdx.x; i < seg; i += TPB) {
        float v = x[base + i]; s += v; ss += v * v;
    }
    __shared__ float sh[8];
    for (int off = 32; off; off >>= 1) { s += __shfl_down(s, off); ss += __shfl_down(ss, off); }
    int wave = threadIdx.x >> 6, lane = threadIdx.x & 63;
    if (lane == 0) { sh[wave] = s; sh[4 + wave] = ss; }
    __syncthreads();
    if (threadIdx.x == 0) {
        float ts = 0.f, tss = 0.f;
        for (int i = 0; i < TPB/64; i++) { ts += sh[i]; tss += sh[4 + i]; }
        atomicAdd(&stat[statBase + bg*2], ts);
        atomicAdd(&stat[statBase + bg*2 + 1], tss);
    }
}
__global__ void k_gnapply(const float* __restrict__ x, const float* __restrict__ stat, int statBase,
                          const float* __restrict__ gamma, const float* __restrict__ beta,
                          float* __restrict__ out, int G, int Cg, int HW, int Bn)
{
    long idx = (long)blockIdx.x * TPB + threadIdx.x;
    long total = (long)Bn * G * Cg * HW;
    if (idx >= total) return;
    int bgN = Cg * HW;
    int bg = idx / bgN;
    int r  = idx % bgN;
    int g = bg % G;
    int c = g * Cg + r / HW;
    float s = stat[statBase + bg*2], ss = stat[statBase + bg*2 + 1];
    float mean = s / bgN;
    float inv = rsqrtf(ss / bgN - mean * mean + 1e-5f);
    out[idx] = (x[idx] - mean) * inv * gamma[c] + beta[c];
}

// ================= cosine sim partials (dilation 2) + finalize =================
__global__ void k_simp(const float* __restrict__ x, float* __restrict__ pbuf,
                       int Bn, int H, int W, int CS)
{
    int HW = H * W;
    int idx = blockIdx.x * TPB + threadIdx.x;
    if (idx >= Bn * HW) return;
    int chunk = blockIdx.y;
    int pix = idx % HW, b = idx / HW;
    int wx = pix % W, hy = pix / W;
    const int dyv[8] = {-2,-2,-2, 0, 0, 2, 2, 2};
    const int dxv[8] = {-2, 0, 2,-2, 2,-2, 0, 2};
    int off[8]; float msk[8];
    #pragma unroll
    for (int n = 0; n < 8; n++) {
        int yy = hy + dyv[n], xx = wx + dxv[n];
        bool v = (yy >= 0 && yy < H && xx >= 0 && xx < W);
        off[n] = v ? yy * W + xx : pix;
        msk[n] = v ? 1.f : 0.f;
    }
    float dc = 0.f, num[8], dn[8];
    #pragma unroll
    for (int n = 0; n < 8; n++) { num[n] = 0.f; dn[n] = 0.f; }
    const float* xb = x + ((long)b * 64 + chunk * CS) * HW;
    #pragma unroll 2
    for (int ci = 0; ci < CS; ci++) {
        const float* xc = xb + (long)ci * HW;
        float c0 = xc[pix];
        dc += c0 * c0;
        #pragma unroll
        for (int n = 0; n < 8; n++) {
            float v = xc[off[n]] * msk[n];
            num[n] += c0 * v; dn[n] += v * v;
        }
    }
    long base = ((long)chunk * Bn + b) * 17 * (long)HW + pix;
    pbuf[base] = dc;
    #pragma unroll
    for (int n = 0; n < 8; n++) {
        pbuf[base + (long)(1 + n) * HW] = num[n];
        pbuf[base + (long)(9 + n) * HW] = dn[n];
    }
}
__global__ void k_simr(const float* __restrict__ pbuf, float* __restrict__ out,
                       int Bn, int HW, int nChunk)
{
    int idx = blockIdx.x * TPB + threadIdx.x;
    if (idx >= Bn * HW) return;
    int pix = idx % HW, b = idx / HW;
    float dc = 0.f, num[8], dn[8];
    #pragma unroll
    for (int n = 0; n < 8; n++) { num[n] = 0.f; dn[n] = 0.f; }
    for (int ch = 0; ch < nChunk; ch++) {
        long base = ((long)ch * Bn + b) * 17 * (long)HW + pix;
        dc += pbuf[base];
        #pragma unroll
        for (int n = 0; n < 8; n++) {
            num[n] += pbuf[base + (long)(1 + n) * HW];
            dn[n]  += pbuf[base + (long)(9 + n) * HW];
        }
    }
    float nc = fmaxf(sqrtf(dc), 1e-8f);
    #pragma unroll
    for (int n = 0; n < 8; n++)
        out[((long)(b*8 + n)) * HW + pix] = num[n] / (nc * fmaxf(sqrtf(dn[n]), 1e-8f));
}

// ================= offset assembly =================
__global__ void k_offset(const float* __restrict__ lro, const float* __restrict__ hro,
                         const float* __restrict__ lrd, const float* __restrict__ hrd,
                         float* __restrict__ outoff, int B)
{
    int idx = blockIdx.x * TPB + threadIdx.x;
    int total = B * 32 * 64 * 64;
    if (idx >= total) return;
    int wx = idx & 63;
    int hy = (idx >> 6) & 63;
    int o  = (idx >> 12) & 31;
    int b  = idx >> 17;
    int c = o >> 2, p = (o >> 1) & 1, q = o & 1;
    long hridx = ((long)(b*8 + c) * 128 + 2*hy + p) * 128 + 2*wx + q;
    float off = lro[idx] + hro[hridx];
    float dsv = lrd[idx] + hrd[hridx];
    float sg = 1.f / (1.f + expf(-dsv));
    int comp = o >> 4;
    float ip = (comp == 0) ? (q ? 0.25f : -0.25f) : (p ? 0.25f : -0.25f);
    outoff[idx] = off * sg + ip;
}

// ===== grid sample from transposed lrupT[b][pix][256], grid.y = channel half =====
template<typename OT>
__device__ void gridsampleT_body(const unsigned short* __restrict__ lrupT,
                                 const float* __restrict__ offb, OT* __restrict__ out, int Bn)
{
    int idx = blockIdx.x * TPB + threadIdx.x;
    if (idx >= Bn * 4 * 16384) return;
    int ch0 = blockIdx.y << 5;            // 2 halves of 32 channels
    int opix = idx & 16383;
    int g = (idx >> 14) & 3, b = idx >> 16;
    int X = opix & 127, Y = opix >> 7;
    int h = Y >> 1, p = Y & 1, w = X >> 1, q = X & 1;
    int r = g*4 + p*2 + q;
    float offx = offb[((long)(b*32 + r)      << 12) + (h << 6) + w];
    float offy = offb[((long)(b*32 + 16 + r) << 12) + (h << 6) + w];
    float gx = fminf(fmaxf(2.f * (w + 0.5f + offx) - 0.5f, 0.f), 127.f);
    float gy = fminf(fmaxf(2.f * (h + 0.5f + offy) - 0.5f, 0.f), 127.f);
    float x0f = floorf(gx), y0f = floorf(gy);
    float tx = gx - x0f, ty = gy - y0f;
    int x0 = (int)x0f, y0 = (int)y0f;
    int x1 = min(x0 + 1, 127), y1 = min(y0 + 1, 127);
    float w11 = tx * ty, w10 = ty - w11, w01 = tx - w11, w00 = 1.f - tx - ty + w11;
    const unsigned short* base = lrupT + (((long)b << 14) << 8) + (g << 6) + ch0;
    long a00 = ((long)((y0 << 7) + x0)) << 8, a01 = ((long)((y0 << 7) + x1)) << 8;
    long a10 = ((long)((y1 << 7) + x0)) << 8, a11 = ((long)((y1 << 7) + x1)) << 8;
    OT* op = out + ((long)(b * 256 + g * 64 + ch0) << 14) + opix;
    #pragma unroll
    for (int c8 = 0; c8 < 4; c8++) {
        uint4 v00 = *(const uint4*)(base + a00 + c8*8);
        uint4 v01 = *(const uint4*)(base + a01 + c8*8);
        uint4 v10 = *(const uint4*)(base + a10 + c8*8);
        uint4 v11 = *(const uint4*)(base + a11 + c8*8);
        const unsigned short* u00 = (const unsigned short*)&v00;
        const unsigned short* u01 = (const unsigned short*)&v01;
        const unsigned short* u10 = (const unsigned short*)&v10;
        const unsigned short* u11 = (const unsigned short*)&v11;
        #pragma unroll
        for (int t = 0; t < 8; t++) {
            float res = bfu(u00[t])*w00 + bfu(u01[t])*w01 + bfu(u10[t])*w10 + bfu(u11[t])*w11;
            stT<OT>(op, ((long)(c8*8 + t) << 14), res);
        }
    }
}
__global__ void k_gridsampleT(const bf16* lrupT, const float* offb, void* out, long outOff,
                              int Bn, const int* flag)
{
    if (*flag) gridsampleT_body<float>((const unsigned short*)lrupT, offb, (float*)out + outOff, Bn);
    else       gridsampleT_body<bf16 >((const unsigned short*)lrupT, offb, (bf16*)out + outOff, Bn);
}

extern "C" void kernel_launch(void* const* d_in, const int* in_sizes, int n_in,
                              void* d_out, int out_size, void* d_ws, size_t ws_size,
                              hipStream_t stream) {
    const void* hr_feat = d_in[0];
    const void* lr_feat = d_in[1];

    const int B = 2, HH = 128, HL = 64;
    const int HWH = HH*HH, HWL = HL*HL;

    int*   flag = (int*)d_ws;
    float* stat = (float*)d_ws + 4;
    float* P    = (float*)d_ws + 80;
    float* ws   = P + ((P_TOT + 63) & ~63);

    size_t o = 0;
    float* ch0    = ws + o; o += (size_t)B*64*HWH;
    float* clb    = ws + o; o += (size_t)B*64*HWL;
    float* maskHH = ws + o; o += (size_t)B*9*HWH;
    float* tmp9   = ws + o; o += (size_t)B*9*HWH;
    float* chn    = ws + o; o += (size_t)B*64*HWH;
    float* m25a   = ws + o; o += (size_t)B*25*HWH;
    float* m25b   = ws + o; o += (size_t)B*25*HWH;
    float* m25c   = ws + o; o += (size_t)B*25*HWH;
    float* enccl  = ws + o; o += (size_t)B*25*HWL;
    float* enc2cl = ws + o; o += (size_t)B*9*HWL;
    bf16*  lrupT  = (bf16*)(ws + o); o += (size_t)B*256*HWH/2;   // transposed lr_up [b][pix][256]
    float* lrx    = ws + o; o += (size_t)B*64*HWL;
    float* hrsim  = ws + o; o += (size_t)B*8*HWH;
    float* lrsim  = ws + o; o += (size_t)B*8*HWL;
    float* qhro   = ws + o; o += (size_t)B*8*HWH;
    float* qlro   = ws + o; o += (size_t)B*32*HWL;
    float* qhrd   = ws + o; o += (size_t)B*8*HWH;
    float* qlrd   = ws + o; o += (size_t)B*32*HWL;
    float* offb   = ws + o; o += (size_t)B*32*HWL;
    float* hrx   = ch0;     // ch0 dead after step 5
    float* maskH = m25b;    // m25b dead after step 9
    // partial/scratch aliases over verified-dead zones:
    float* pbufA  = maskHH;          // steps 1-2
    float* pbuf3  = tmp9;            // step 3
    float* pbuf6  = m25b;            // step 6
    float* pbufL8 = (float*)lrupT;   // steps 8,11 (before step 15 writes lrupT)
    float* pbufT  = chn;             // steps 18-23
    bf16*  lrfT   = (bf16*)hrsim;    // lr_feat transposed [b][4096][256] bf16 (2.1M ushort
                                     // = 1.05M floats; hrsim..qhro zone dead until step 18)
    (void)ws_size; (void)n_in;

    long out1Off = (long)B*25*HWH;
    long out2Off = out1Off + (long)B*256*HWH;

    const float* pw_hrc = P + P_W_HRC;  const float* pb_hrc = P + P_B_HRC;
    const float* pw_lrc = P + P_W_LRC;  const float* pb_lrc = P + P_B_LRC;
    const float* pw_enc = P + P_W_ENC;  const float* pb_enc = P + P_B_ENC;
    const float* pw_enc2= P + P_W_ENC2; const float* pb_enc2= P + P_B_ENC2;
    const float* pgnhw  = P + P_GNHW;   const float* pgnhb  = P + P_GNHB;
    const float* pgnlw  = P + P_GNLW;   const float* pgnlb  = P + P_GNLB;
    const float* pw_off = P + P_W_OFF;  const float* pb_off = P + P_B_OFF;
    const float* pw_hoff= P + P_W_HOFF; const float* pb_hoff= P + P_B_HOFF;
    const float* pw_ds  = P + P_W_DS;   const float* pb_ds  = P + P_B_DS;
    const float* pw_hds = P + P_W_HDS;  const float* pb_hds = P + P_B_HDS;

    // 0. dtype detect + weight prep + lr_feat transpose (channels-last)
    int nDet = in_sizes[0] < 16384 ? in_sizes[0] : 16384;
    k_detect<<<1, TPB, 0, stream>>>(hr_feat, nDet, flag, stat);
    k_prep<<<nblk(P_TOT), TPB, 0, stream>>>(d_in[2],d_in[3],d_in[4],d_in[5],d_in[6],d_in[7],
        d_in[8],d_in[9],d_in[10],d_in[11],d_in[12],d_in[13],d_in[14],d_in[15],d_in[16],
        d_in[17],d_in[18],d_in[19],d_in[20],d_in[21], P, flag);
    k_transpLR<<<B*4*64, TPB, 0, stream>>>(lr_feat, lrfT, B, flag);

    // 1. ch0 = 1x1(hr_feat): 4 chunks x CS64
    k_conv1x1p<<<dim3(nblk((long)B*HWH),4), TPB, 0, stream>>>(hr_feat, pw_hrc, pbufA, B, 256, HWH, 64, flag);
    k_convr<<<nblk((long)B*64*HWH), TPB, 0, stream>>>(pbufA, pb_hrc, ch0, B, 64, HWH, 4);
    // 2. clb = 1x1(lr_feat): 16 chunks x CS16
    k_conv1x1p<<<dim3(nblk((long)B*HWL),16), TPB, 0, stream>>>(lr_feat, pw_lrc, pbufA, B, 256, HWL, 16, flag);
    k_convr<<<nblk((long)B*64*HWL), TPB, 0, stream>>>(pbufA, pb_lrc, clb, B, 64, HWL, 16);
    // 3. mask_hr_hr: 8 chunks x CS8
    k_conv3x3p<9><<<dim3(nblk((long)B*HWH),8), TPB, 0, stream>>>(ch0, pw_enc2, pbuf3, B, 64, HH, HH, 8);
    k_convr<<<nblk((long)B*9*HWH), TPB, 0, stream>>>(pbuf3, pb_enc2, maskHH, B, 9, HWH, 8);
    // 4-5. mh_init, ch = 2*ch0 - carafe3(ch0)
    k_knorm<3><<<nblk((long)B*HWH), TPB, 0, stream>>>(maskHH, tmp9, nullptr, B, HH, HH, flag);
    k_carafe3c_ws<<<nblk((long)B*8*16384), TPB, 0, stream>>>(ch0, tmp9, chn, B);
    // 6. mask_lr_hr: 8 chunks x CS8
    k_conv3x3p<25><<<dim3(nblk((long)B*HWH),8), TPB, 0, stream>>>(chn, pw_enc, pbuf6, B, 64, HH, HH, 8);
    k_convr<<<nblk((long)B*25*HWH), TPB, 0, stream>>>(pbuf6, pb_enc, m25a, B, 25, HWH, 8);
    // 7. ml_init -> m25b
    k_knorm<5><<<nblk((long)B*HWH), TPB, 0, stream>>>(m25a, m25b, nullptr, B, HH, HH, flag);
    // 8. enccl: 16 chunks x CS4
    k_conv3x3p<25><<<dim3(nblk((long)B*HWL),16), TPB, 0, stream>>>(clb, pw_enc, pbufL8, B, 64, HL, HL, 4);
    k_convr<<<nblk((long)B*25*HWL), TPB, 0, stream>>>(pbufL8, pb_enc, enccl, B, 25, HWL, 16);
    // 9. mask_lr = mask_lr_hr + carafe5(enccl, ml_init): C=25, CG=5
    k_carafe5_ws<5><<<nblk((long)B*5*16384), TPB, 0, stream>>>(enccl, m25b, m25a, m25c, B, 25);
    // 10. mask_lr_n -> m25a + bf16 output 0
    k_knorm<5><<<nblk((long)B*HWH), TPB, 0, stream>>>(m25c, m25a, d_out, B, HH, HH, flag);
    // 11. enc2cl: 16 chunks x CS4
    k_conv3x3p<9><<<dim3(nblk((long)B*HWL),16), TPB, 0, stream>>>(clb, pw_enc2, pbufL8, B, 64, HL, HL, 4);
    k_convr<<<nblk((long)B*9*HWL), TPB, 0, stream>>>(pbufL8, pb_enc2, enc2cl, B, 9, HWL, 16);
    // 12. mask_hr = mask_hr_hr + carafe5(enc2cl, mask_lr_n): C=9, CG=3
    k_carafe5_ws<3><<<nblk((long)B*3*16384), TPB, 0, stream>>>(enc2cl, m25a, maskHH, maskH, B, 9);
    // 13-14. mask_hr_n, hr_out -> output 1
    k_knorm<3><<<nblk((long)B*HWH), TPB, 0, stream>>>(maskH, tmp9, nullptr, B, HH, HH, flag);
    k_carafe3c_io<<<nblk((long)B*32*16384), TPB, 0, stream>>>(hr_feat, tmp9, d_out, out1Off, B, flag);
    // 15. lr_up (transposed): wave=(b,ipix), lane=4-channel group; XCD-swizzled
    k_carafe5T<<<B*4096/4, TPB, 0, stream>>>(lrfT, m25a, lrupT, B);
    // 16-17. group norms
    k_gnstat<<<16*32, TPB, 0, stream>>>(chn, stat, 0, 32, 8*HWH);
    k_gnapply<<<nblk((long)B*64*HWH), TPB, 0, stream>>>(chn, stat, 0, pgnhw, pgnhb, hrx, 8, 8, HWH, B);
    k_gnstat<<<16*8, TPB, 0, stream>>>(clb, stat, 32, 8, 8*HWL);
    k_gnapply<<<nblk((long)B*64*HWL), TPB, 0, stream>>>(clb, stat, 32, pgnlw, pgnlb, lrx, 8, 8, HWL, B);
    // 18. hrsim: 8 chunks x CS8
    k_simp<<<dim3(nblk((long)B*HWH),8), TPB, 0, stream>>>(hrx, pbufT, B, HH, HH, 8);
    k_simr<<<nblk((long)B*HWH), TPB, 0, stream>>>(pbufT, hrsim, B, HWH, 8);
    // 19. lrsim: 16 chunks x CS4
    k_simp<<<dim3(nblk((long)B*HWL),16), TPB, 0, stream>>>(lrx, pbufT, B, HL, HL, 4);
    k_simr<<<nblk((long)B*HWL), TPB, 0, stream>>>(pbufT, lrsim, B, HWL, 16);
    // 20. qhro: 4 chunks x CS2
    k_conv3x3p<8><<<dim3(nblk((long)B*HWH),4), TPB, 0, stream>>>(hrsim, pw_hoff, pbufT, B, 8, HH, HH, 2);
    k_convr<<<nblk((long)B*8*HWH), TPB, 0, stream>>>(pbufT, pb_hoff, qhro, B, 8, HWH, 4);
    // 21. qlro: 8 chunks x CS1
    k_conv3x3p<32><<<dim3(nblk((long)B*HWL),8), TPB, 0, stream>>>(lrsim, pw_off, pbufT, B, 8, HL, HL, 1);
    k_convr<<<nblk((long)B*32*HWL), TPB, 0, stream>>>(pbufT, pb_off, qlro, B, 32, HWL, 8);
    // 22. qhrd: 8 chunks x CS8
    k_conv3x3p<8><<<dim3(nblk((long)B*HWH),8), TPB, 0, stream>>>(hrx, pw_hds, pbufT, B, 64, HH, HH, 8);
    k_convr<<<nblk((long)B*8*HWH), TPB, 0, stream>>>(pbufT, pb_hds, qhrd, B, 8, HWH, 8);
    // 23. qlrd: 16 chunks x CS4
    k_conv3x3p<32><<<dim3(nblk((long)B*HWL),16), TPB, 0, stream>>>(lrx, pw_ds, pbufT, B, 64, HL, HL, 4);
    k_convr<<<nblk((long)B*32*HWL), TPB, 0, stream>>>(pbufT, pb_ds, qlrd, B, 32, HWL, 16);
    // 24. offset assembly
    k_offset<<<nblk((long)B*32*HWL), TPB, 0, stream>>>(qlro, qhro, qlrd, qhrd, offb, B);
    // 25. grid sample from lrupT -> output 2 (2 channel halves)
    k_gridsampleT<<<dim3(nblk((long)B*4*HWH),2), TPB, 0, stream>>>(lrupT, offb, d_out, out2Off, B, flag);
}

// Round 9
// 555.036 us; speedup vs baseline: 2.8782x; 1.0291x over previous
//
#include <hip/hip_runtime.h>
#include <hip/hip_bf16.h>

typedef __hip_bfloat16 bf16;
#define TPB 256

__device__ __forceinline__ float toF(float v){ return v; }
__device__ __forceinline__ float toF(bf16 v){ return __bfloat162float(v); }
__device__ __forceinline__ float bfu(unsigned short u){
    unsigned int x = ((unsigned int)u) << 16;
    return __uint_as_float(x);
}
template<typename T> __device__ __forceinline__ void stT(T* p, long i, float v);
template<> __device__ __forceinline__ void stT<float>(float* p, long i, float v){ p[i] = v; }
template<> __device__ __forceinline__ void stT<bf16>(bf16* p, long i, float v){ p[i] = __float2bfloat16(v); }

__device__ __forceinline__ void st4bf(bf16* p, const float* a){
    bf16 t0 = __float2bfloat16(a[0]);
    bf16 t1 = __float2bfloat16(a[1]);
    bf16 t2 = __float2bfloat16(a[2]);
    bf16 t3 = __float2bfloat16(a[3]);
    ushort4 pk;
    pk.x = *(unsigned short*)&t0;
    pk.y = *(unsigned short*)&t1;
    pk.z = *(unsigned short*)&t2;
    pk.w = *(unsigned short*)&t3;
    *(ushort4*)p = pk;
}

static inline int nblk(long n){ return (int)((n + TPB - 1) / TPB); }

// ================= dtype detection + stat zero =================
__global__ void k_detect(const void* hr, int n, int* flag, float* stat)
{
    if (threadIdx.x < 64) stat[threadIdx.x] = 0.f;
    const unsigned short* u = (const unsigned short*)hr;
    int nan = 0, oz = 0, ot = 0;
    for (int i = threadIdx.x; i < n; i += TPB) {
        unsigned short a = u[i] & 0x7FFF;
        if (a >= 0x7F80) nan++;
        if (i & 1) { ot++; if (a == 0) oz++; }
    }
    __shared__ int s1[TPB], s2[TPB], s3[TPB];
    s1[threadIdx.x] = nan; s2[threadIdx.x] = oz; s3[threadIdx.x] = ot;
    __syncthreads();
    if (threadIdx.x == 0) {
        int a = 0, b = 0, c = 0;
        for (int i = 0; i < TPB; i++) { a += s1[i]; b += s2[i]; c += s3[i]; }
        *flag = (a >= 6 || (long)b * 10 >= (long)c * 9) ? 1 : 0;
    }
}

// ================= weight prep: fp32 + transpose to [ci][co][taps] =================
#define P_W_HRC 0
#define P_B_HRC 16384
#define P_W_LRC 16448
#define P_B_LRC 32832
#define P_W_ENC 32896
#define P_B_ENC 47296
#define P_W_ENC2 47321
#define P_B_ENC2 52505
#define P_GNHW 52514
#define P_GNHB 52578
#define P_GNLW 52642
#define P_GNLB 52706
#define P_W_OFF 52770
#define P_B_OFF 55074
#define P_W_HOFF 55106
#define P_B_HOFF 55682
#define P_W_DS 55690
#define P_B_DS 74122
#define P_W_HDS 74154
#define P_B_HDS 78762
#define P_TOT 78770

__constant__ int c_segsz[20]  = {16384,64,16384,64,14400,25,5184,9,64,64,64,64,2304,32,576,8,18432,32,4608,8};
__constant__ int c_segbase[20]= {P_W_HRC,P_B_HRC,P_W_LRC,P_B_LRC,P_W_ENC,P_B_ENC,P_W_ENC2,P_B_ENC2,
                                 P_GNHW,P_GNHB,P_GNLW,P_GNLB,P_W_OFF,P_B_OFF,P_W_HOFF,P_B_HOFF,
                                 P_W_DS,P_B_DS,P_W_HDS,P_B_HDS};
__constant__ int c_segcin[20] = {256,0,256,0, 64,0, 64,0, 0,0,0,0, 8,0, 8,0, 64,0, 64,0};
__constant__ int c_segcout[20]= { 64,0, 64,0, 25,0,  9,0, 0,0,0,0,32,0, 8,0, 32,0,  8,0};
__constant__ int c_segtap[20] = {  1,0,  1,0,  9,0,  9,0, 0,0,0,0, 9,0, 9,0,  9,0,  9,0};

__global__ void k_prep(const void* p0,const void* p1,const void* p2,const void* p3,
                       const void* p4,const void* p5,const void* p6,const void* p7,
                       const void* p8,const void* p9,const void* p10,const void* p11,
                       const void* p12,const void* p13,const void* p14,const void* p15,
                       const void* p16,const void* p17,const void* p18,const void* p19,
                       float* dst, const int* flag)
{
    int idx = blockIdx.x * TPB + threadIdx.x;
    if (idx >= P_TOT) return;
    int s = 0, off = idx;
    while (off >= c_segsz[s]) { off -= c_segsz[s]; s++; }
    const void* sp;
    switch (s) {
        case 0: sp=p0; break;  case 1: sp=p1; break;  case 2: sp=p2; break;  case 3: sp=p3; break;
        case 4: sp=p4; break;  case 5: sp=p5; break;  case 6: sp=p6; break;  case 7: sp=p7; break;
        case 8: sp=p8; break;  case 9: sp=p9; break;  case 10: sp=p10; break; case 11: sp=p11; break;
        case 12: sp=p12; break; case 13: sp=p13; break; case 14: sp=p14; break; case 15: sp=p15; break;
        case 16: sp=p16; break; case 17: sp=p17; break; case 18: sp=p18; break; default: sp=p19; break;
    }
    float v = (*flag) ? ((const float*)sp)[off] : toF(((const bf16*)sp)[off]);
    int doff = off;
    int cin = c_segcin[s];
    if (cin) {
        int t = c_segtap[s], cout = c_segcout[s];
        int co = off / (cin * t);
        int r  = off % (cin * t);
        int ci = r / t, k = r % t;
        doff = (ci * cout + co) * t + k;
    }
    dst[c_segbase[s] + doff] = v;
}

// ================= lr_feat transpose: [b][256][4096] -> bf16 [b][4096][256] =============
template<typename T>
__device__ void transpLR_body(const T* __restrict__ x, bf16* __restrict__ xT, int Bn)
{
    __shared__ float tile[64][65];
    int bid = blockIdx.x;                 // b * 4 cgroup * 64 pgroup
    int pg = bid & 63;
    int cg = (bid >> 6) & 3;
    int b  = bid >> 8;
    int tid = threadIdx.x;
    int tr = tid >> 6, tc = tid & 63;
    for (int i = 0; i < 16; i++) {
        int c = tr + i * 4;
        tile[c][tc] = toF(x[(((long)(b * 256 + cg * 64 + c)) << 12) + (pg << 6) + tc]);
    }
    __syncthreads();
    for (int i = 0; i < 16; i++) {
        int p = tr + i * 4;
        xT[((((long)b << 12) + (pg << 6) + p) << 8) + (cg << 6) + tc] = __float2bfloat16(tile[tc][p]);
    }
}
__global__ void k_transpLR(const void* x, bf16* xT, int Bn, const int* flag)
{
    if (*flag) transpLR_body<float>((const float*)x, xT, Bn);
    else       transpLR_body<bf16 >((const bf16*)x,  xT, Bn);
}

// ===== carafe5-up channels-last: wave = (b, ipix), lane = 4-channel group =====
__global__ void k_carafe5T(const bf16* __restrict__ featT, const float* __restrict__ mask,
                           bf16* __restrict__ outT, int Bn)
{
    int lane = threadIdx.x & 63;
    int nwg = gridDim.x;
    int bid = blockIdx.x;
    int swz = (nwg & 7) ? bid : ((bid & 7) * (nwg >> 3) + (bid >> 3));
    int wid = (swz << 2) | (threadIdx.x >> 6);
    wid = __builtin_amdgcn_readfirstlane(wid);
    if (wid >= Bn * 4096) return;
    int ipix = wid & 4095;
    int b    = wid >> 12;
    int h = ipix >> 6, w = ipix & 63;
    const bf16*  fb = featT + (((long)b << 12) << 8) + (lane << 2);
    const float* mb = mask + (((long)b * 25) << 14) + (h << 8) + (w << 1);
    float a00[4], a01[4], a10[4], a11[4];
    #pragma unroll
    for (int t = 0; t < 4; t++) { a00[t]=0.f; a01[t]=0.f; a10[t]=0.f; a11[t]=0.f; }
    #pragma unroll
    for (int k = 0; k < 25; k++) {
        const int i = k / 5, j = k % 5;
        int yy = h + i - 2, xx = w + j - 2;
        bool v = (yy >= 0 && yy < 64 && xx >= 0 && xx < 64);
        int yc = v ? yy : 0, xc = v ? xx : 0;
        ushort4 u = *(const ushort4*)(fb + ((long)((yc << 6) + xc) << 8));
        float2 mr0 = *(const float2*)(mb + ((long)k << 14));
        float2 mr1 = *(const float2*)(mb + ((long)k << 14) + 128);
        float m00 = v ? mr0.x : 0.f, m01 = v ? mr0.y : 0.f;
        float m10 = v ? mr1.x : 0.f, m11 = v ? mr1.y : 0.f;
        float f0 = bfu(u.x), f1 = bfu(u.y), f2 = bfu(u.z), f3 = bfu(u.w);
        a00[0] += f0*m00; a00[1] += f1*m00; a00[2] += f2*m00; a00[3] += f3*m00;
        a01[0] += f0*m01; a01[1] += f1*m01; a01[2] += f2*m01; a01[3] += f3*m01;
        a10[0] += f0*m10; a10[1] += f1*m10; a10[2] += f2*m10; a10[3] += f3*m10;
        a11[0] += f0*m11; a11[1] += f1*m11; a11[2] += f2*m11; a11[3] += f3*m11;
    }
    bf16* op = outT + (((long)(b << 14) + (h << 8) + (w << 1)) << 8) + (lane << 2);
    st4bf(op, a00);                       // (2h,   2w)
    st4bf(op + 256, a01);                 // (2h,   2w+1)
    st4bf(op + (128 << 8), a10);          // (2h+1, 2w)
    st4bf(op + (128 << 8) + 256, a11);    // (2h+1, 2w+1)
}

// ================= 3x3 conv partials: grid.y = ci-chunk =================
template<int COUT>
__global__ void k_conv3x3p(const float* __restrict__ x, const float* __restrict__ wf,
                           float* __restrict__ pbuf, int Bn, int CIN, int H, int W, int CS)
{
    int HW = H * W;
    int idx = blockIdx.x * TPB + threadIdx.x;
    if (idx >= Bn * HW) return;
    int chunk = blockIdx.y;
    int pix = idx % HW, b = idx / HW;
    int wx = pix % W, hy = pix / W;
    int off[9]; float msk[9];
    #pragma unroll
    for (int i = 0; i < 3; i++) {
        int yy = hy + i - 1; bool vy = (yy >= 0 && yy < H); int yc = vy ? yy : hy;
        #pragma unroll
        for (int j = 0; j < 3; j++) {
            int xx = wx + j - 1; bool v = vy && (xx >= 0 && xx < W);
            int xc = (xx >= 0 && xx < W) ? xx : wx;
            off[i*3+j] = yc * W + xc; msk[i*3+j] = v ? 1.f : 0.f;
        }
    }
    float acc[COUT];
    #pragma unroll
    for (int co = 0; co < COUT; co++) acc[co] = 0.f;
    int c0 = chunk * CS;
    const float* xb = x + ((long)b * CIN + c0) * HW;
    const float* wb = wf + (long)c0 * COUT * 9;
    #pragma unroll 2
    for (int ci = 0; ci < CS; ci++) {
        const float* xc = xb + (long)ci * HW;
        float t[9];
        #pragma unroll
        for (int k = 0; k < 9; k++) t[k] = xc[off[k]] * msk[k];
        const float* wr = wb + (long)ci * COUT * 9;
        #pragma unroll
        for (int co = 0; co < COUT; co++) {
            const float* wp = wr + co * 9;
            acc[co] += t[0]*wp[0] + t[1]*wp[1] + t[2]*wp[2] + t[3]*wp[3] + t[4]*wp[4]
                     + t[5]*wp[5] + t[6]*wp[6] + t[7]*wp[7] + t[8]*wp[8];
        }
    }
    long pb = ((long)chunk * Bn + b) * COUT * (long)HW + pix;
    #pragma unroll
    for (int co = 0; co < COUT; co++) pbuf[pb + (long)co * HW] = acc[co];
}

// ================= conv reduce: out = bias + sum_chunks partial =================
__global__ void k_convr(const float* __restrict__ pbuf, const float* __restrict__ bias,
                        float* __restrict__ out, int Bn, int COUT, int HW, int nChunk)
{
    long idx = (long)blockIdx.x * TPB + threadIdx.x;
    if (idx >= (long)Bn * COUT * HW) return;
    int pix = idx % HW;
    int co  = (idx / HW) % COUT;
    int b   = idx / ((long)HW * COUT);
    float v = bias[co];
    for (int ch = 0; ch < nChunk; ch++)
        v += pbuf[(((long)ch * Bn + b) * COUT + co) * HW + pix];
    out[idx] = v;
}

// ===== 1x1 conv partials (COUT=64), grid.y = chunk*COG + co-group =====
// Co-split doubles workgroups (latency hiding) without growing pbuf traffic;
// pbuf layout identical to the unsplit version so k_convr is unchanged.
template<typename T, int NCO>
__device__ void conv1x1p_body(const T* __restrict__ x, const float* __restrict__ wf,
                              float* __restrict__ pbuf, int Bn, int CIN, int HW, int CS)
{
    constexpr int COG = 64 / NCO;
    int idx = blockIdx.x * TPB + threadIdx.x;
    if (idx >= Bn * HW) return;
    int chunk = blockIdx.y / COG;
    int cog   = blockIdx.y % COG;
    int co0   = cog * NCO;
    int pix = idx % HW, b = idx / HW;
    float acc[NCO];
    #pragma unroll
    for (int c = 0; c < NCO; c++) acc[c] = 0.f;
    int c0 = chunk * CS;
    const T* xp = x + ((long)b * CIN + c0) * HW + pix;
    const float* wb = wf + (long)c0 * 64 + co0;
    #pragma unroll 4
    for (int ci = 0; ci < CS; ci++) {
        float v = toF(xp[(long)ci * HW]);
        const float* wr = wb + ci * 64;
        #pragma unroll
        for (int c = 0; c < NCO; c++) acc[c] += v * wr[c];
    }
    long pb = ((long)chunk * Bn + b) * 64 * (long)HW + (long)co0 * HW + pix;
    #pragma unroll
    for (int c = 0; c < NCO; c++) pbuf[pb + (long)c * HW] = acc[c];
}
template<int NCO>
__global__ void k_conv1x1p(const void* x, const float* wf, float* pbuf,
                           int Bn, int CIN, int HW, int CS, const int* flag)
{
    if (*flag) conv1x1p_body<float, NCO>((const float*)x, wf, pbuf, Bn, CIN, HW, CS);
    else       conv1x1p_body<bf16, NCO>((const bf16*)x,  wf, pbuf, Bn, CIN, HW, CS);
}

// ================= kernel_normalizer (planar in/out) =================
template<int K, typename OT>
__device__ void knorm_body(const float* __restrict__ mask, float* __restrict__ out,
                           OT* __restrict__ outb, int B, int H, int W)
{
    const int K2 = K * K;
    int HWi = H * W;
    int idx = blockIdx.x * TPB + threadIdx.x;
    if (idx >= B * HWi) return;
    int pix = idx % HWi;
    int b   = idx / HWi;
    long HW = (long)HWi;
    long base = (long)b * K2 * HW + pix;
    float v[K2];
    float m = -1e30f;
    for (int k = 0; k < K2; k++) { v[k] = mask[base + k*HW]; m = fmaxf(m, v[k]); }
    float s2 = 0.f;
    for (int k = 0; k < K2; k++) {
        int i = k / K, j = k % K;
        float hi = (K == 3) ? ((i==1)?1.f:0.08f) : ((i==2)?1.f:((i==1||i==3)?0.54f:0.08f));
        float hj = (K == 3) ? ((j==1)?1.f:0.08f) : ((j==2)?1.f:((j==1||j==3)?0.54f:0.08f));
        v[k] = expf(v[k] - m) * hi * hj;
        s2 += v[k];
    }
    float inv = 1.f / s2;
    for (int k = 0; k < K2; k++) {
        float r = v[k] * inv;
        out[base + k*HW] = r;
        if (outb) stT<OT>(outb, base + k*HW, r);
    }
}
template<int K>
__global__ void k_knorm(const float* mask, float* out, void* outb, int B, int H, int W, const int* flag)
{
    if (*flag) knorm_body<K, float>(mask, out, (float*)outb, B, H, W);
    else       knorm_body<K, bf16>(mask, out, (bf16*)outb, B, H, W);
}

// ================= carafe3 (2*f - carafe), planar mask, 8 channels/thread ============
template<typename TF, typename TO, int NC>
__device__ void carafe3c_body(const TF* __restrict__ feat, const float* __restrict__ mask,
                              TO* __restrict__ out, int Bn)
{
    constexpr int CH = NC / 8;
    int idx = blockIdx.x * TPB + threadIdx.x;
    if (idx >= Bn * CH * 16384) return;
    int px = idx & 16383;
    int cc = (idx >> 14) % CH;
    int b  = (idx >> 14) / CH;
    int wx = px & 127, hy = px >> 7;
    float mk[9]; int off[9];
    #pragma unroll
    for (int i = 0; i < 3; i++) {
        int yy = hy + i - 1; bool vy = (yy >= 0 && yy < 128); int yc = vy ? yy : hy;
        #pragma unroll
        for (int j = 0; j < 3; j++) {
            int xx = wx + j - 1; bool v = vy && (xx >= 0 && xx < 128);
            int xc = (xx >= 0 && xx < 128) ? xx : wx;
            int k = i*3 + j;
            float m = mask[(((long)b*9 + k) << 14) + px];
            mk[k] = v ? m : 0.f;
            off[k] = (yc << 7) + xc;
        }
    }
    long base = ((long)(b * NC + cc * 8) << 14);
    for (int c = 0; c < 8; c++) {
        const TF* fp = feat + base + ((long)c << 14);
        float ctr = 0.f, acc = 0.f;
        #pragma unroll
        for (int k = 0; k < 9; k++) {
            float v = toF(fp[off[k]]);
            if (k == 4) ctr = v;
            acc += v * mk[k];
        }
        stT<TO>(out, base + ((long)c << 14) + px, 2.f * ctr - acc);
    }
}
__global__ void k_carafe3c_ws(const float* feat, const float* mask, float* out, int Bn)
{
    carafe3c_body<float, float, 64>(feat, mask, out, Bn);
}
__global__ void k_carafe3c_io(const void* feat, const float* mask, void* out, long outOff,
                              int Bn, const int* flag)
{
    if (*flag) carafe3c_body<float, float, 256>((const float*)feat, mask, (float*)out + outOff, Bn);
    else       carafe3c_body<bf16, bf16, 256>((const bf16*)feat, mask, (bf16*)out + outOff, Bn);
}

// ===== carafe5 s=2 ws variant: thread = output pixel x channel-group; planar mask =====
template<typename TF, typename TO, bool ADD, int CG>
__device__ void carafe5_body(const TF* __restrict__ feat, const float* __restrict__ mask,
                             const float* __restrict__ add, TO* __restrict__ out,
                             int Bn, int C)
{
    int ng = C / CG;
    int idx = blockIdx.x * TPB + threadIdx.x;
    if (idx >= Bn * ng * 16384) return;
    int px = idx & 16383;
    int gi = (idx >> 14) % ng;
    int b  = (idx >> 14) / ng;
    int X = px & 127, Y = px >> 7;
    int h = Y >> 1, w = X >> 1;
    float mk[25]; int off[25];
    const float* mb = mask + (((long)b * 25) << 14) + px;
    #pragma unroll
    for (int i = 0; i < 5; i++) {
        int yy = h + i - 2; bool vy = (yy >= 0 && yy < 64); int yc = vy ? yy : 0;
        #pragma unroll
        for (int j = 0; j < 5; j++) {
            int xx = w + j - 2; bool v = vy && (xx >= 0 && xx < 64);
            int xc = (xx >= 0 && xx < 64) ? xx : 0;
            int k = i*5 + j;
            mk[k] = v ? mb[(long)k << 14] : 0.f;
            off[k] = (yc << 6) + xc;
        }
    }
    int c0 = gi * CG;
    for (int c = 0; c < CG; c++) {
        long fb = ((long)(b * C + c0 + c) << 12);
        long ob = ((long)(b * C + c0 + c) << 14) + px;
        const TF* fp = feat + fb;
        float acc = ADD ? add[ob] : 0.f;
        #pragma unroll
        for (int k = 0; k < 25; k++) acc += toF(fp[off[k]]) * mk[k];
        stT<TO>(out, ob, acc);
    }
}
template<int CG>
__global__ void k_carafe5_ws(const float* feat, const float* mask, const float* add,
                             float* out, int Bn, int C)
{
    carafe5_body<float, float, true, CG>(feat, mask, add, out, Bn, C);
}

// ================= group norm: slice partial stats (atomic) + apply =================
__global__ void k_gnstat(const float* __restrict__ x, float* __restrict__ stat, int statBase,
                         int S, int N)
{
    int bid = blockIdx.x;
    int bg = bid / S, sl = bid % S;
    int seg = N / S;
    long base = (long)bg * N + (long)sl * seg;
    float s = 0.f, ss = 0.f;
    for (int i = threadIdx.x; i < seg; i += TPB) {
        float v = x[base + i]; s += v; ss += v * v;
    }
    __shared__ float sh[8];
    for (int off = 32; off; off >>= 1) { s += __shfl_down(s, off); ss += __shfl_down(ss, off); }
    int wave = threadIdx.x >> 6, lane = threadIdx.x & 63;
    if (lane == 0) { sh[wave] = s; sh[4 + wave] = ss; }
    __syncthreads();
    if (threadIdx.x == 0) {
        float ts = 0.f, tss = 0.f;
        for (int i = 0; i < TPB/64; i++) { ts += sh[i]; tss += sh[4 + i]; }
        atomicAdd(&stat[statBase + bg*2], ts);
        atomicAdd(&stat[statBase + bg*2 + 1], tss);
    }
}
__global__ void k_gnapply(const float* __restrict__ x, const float* __restrict__ stat, int statBase,
                          const float* __restrict__ gamma, const float* __restrict__ beta,
                          float* __restrict__ out, int G, int Cg, int HW, int Bn)
{
    long idx = (long)blockIdx.x * TPB + threadIdx.x;
    long total = (long)Bn * G * Cg * HW;
    if (idx >= total) return;
    int bgN = Cg * HW;
    int bg = idx / bgN;
    int r  = idx % bgN;
    int g = bg % G;
    int c = g * Cg + r / HW;
    float s = stat[statBase + bg*2], ss = stat[statBase + bg*2 + 1];
    float mean = s / bgN;
    float inv = rsqrtf(ss / bgN - mean * mean + 1e-5f);
    out[idx] = (x[idx] - mean) * inv * gamma[c] + beta[c];
}

// ================= cosine sim partials (dilation 2) + finalize =================
__global__ void k_simp(const float* __restrict__ x, float* __restrict__ pbuf,
                       int Bn, int H, int W, int CS)
{
    int HW = H * W;
    int idx = blockIdx.x * TPB + threadIdx.x;
    if (idx >= Bn * HW) return;
    int chunk = blockIdx.y;
    int pix = idx % HW, b = idx / HW;
    int wx = pix % W, hy = pix / W;
    const int dyv[8] = {-2,-2,-2, 0, 0, 2, 2, 2};
    const int dxv[8] = {-2, 0, 2,-2, 2,-2, 0, 2};
    int off[8]; float msk[8];
    #pragma unroll
    for (int n = 0; n < 8; n++) {
        int yy = hy + dyv[n], xx = wx + dxv[n];
        bool v = (yy >= 0 && yy < H && xx >= 0 && xx < W);
        off[n] = v ? yy * W + xx : pix;
        msk[n] = v ? 1.f : 0.f;
    }
    float dc = 0.f, num[8], dn[8];
    #pragma unroll
    for (int n = 0; n < 8; n++) { num[n] = 0.f; dn[n] = 0.f; }
    const float* xb = x + ((long)b * 64 + chunk * CS) * HW;
    #pragma unroll 2
    for (int ci = 0; ci < CS; ci++) {
        const float* xc = xb + (long)ci * HW;
        float c0 = xc[pix];
        dc += c0 * c0;
        #pragma unroll
        for (int n = 0; n < 8; n++) {
            float v = xc[off[n]] * msk[n];
            num[n] += c0 * v; dn[n] += v * v;
        }
    }
    long base = ((long)chunk * Bn + b) * 17 * (long)HW + pix;
    pbuf[base] = dc;
    #pragma unroll
    for (int n = 0; n < 8; n++) {
        pbuf[base + (long)(1 + n) * HW] = num[n];
        pbuf[base + (long)(9 + n) * HW] = dn[n];
    }
}
__global__ void k_simr(const float* __restrict__ pbuf, float* __restrict__ out,
                       int Bn, int HW, int nChunk)
{
    int idx = blockIdx.x * TPB + threadIdx.x;
    if (idx >= Bn * HW) return;
    int pix = idx % HW, b = idx / HW;
    float dc = 0.f, num[8], dn[8];
    #pragma unroll
    for (int n = 0; n < 8; n++) { num[n] = 0.f; dn[n] = 0.f; }
    for (int ch = 0; ch < nChunk; ch++) {
        long base = ((long)ch * Bn + b) * 17 * (long)HW + pix;
        dc += pbuf[base];
        #pragma unroll
        for (int n = 0; n < 8; n++) {
            num[n] += pbuf[base + (long)(1 + n) * HW];
            dn[n]  += pbuf[base + (long)(9 + n) * HW];
        }
    }
    float nc = fmaxf(sqrtf(dc), 1e-8f);
    #pragma unroll
    for (int n = 0; n < 8; n++)
        out[((long)(b*8 + n)) * HW + pix] = num[n] / (nc * fmaxf(sqrtf(dn[n]), 1e-8f));
}

// ================= offset assembly =================
__global__ void k_offset(const float* __restrict__ lro, const float* __restrict__ hro,
                         const float* __restrict__ lrd, const float* __restrict__ hrd,
                         float* __restrict__ outoff, int B)
{
    int idx = blockIdx.x * TPB + threadIdx.x;
    int total = B * 32 * 64 * 64;
    if (idx >= total) return;
    int wx = idx & 63;
    int hy = (idx >> 6) & 63;
    int o  = (idx >> 12) & 31;
    int b  = idx >> 17;
    int c = o >> 2, p = (o >> 1) & 1, q = o & 1;
    long hridx = ((long)(b*8 + c) * 128 + 2*hy + p) * 128 + 2*wx + q;
    float off = lro[idx] + hro[hridx];
    float dsv = lrd[idx] + hrd[hridx];
    float sg = 1.f / (1.f + expf(-dsv));
    int comp = o >> 4;
    float ip = (comp == 0) ? (q ? 0.25f : -0.25f) : (p ? 0.25f : -0.25f);
    outoff[idx] = off * sg + ip;
}

// ===== grid sample from transposed lrupT[b][pix][256], grid.y = channel half =====
template<typename OT>
__device__ void gridsampleT_body(const unsigned short* __restrict__ lrupT,
                                 const float* __restrict__ offb, OT* __restrict__ out, int Bn)
{
    int idx = blockIdx.x * TPB + threadIdx.x;
    if (idx >= Bn * 4 * 16384) return;
    int ch0 = blockIdx.y << 5;            // 2 halves of 32 channels
    int opix = idx & 16383;
    int g = (idx >> 14) & 3, b = idx >> 16;
    int X = opix & 127, Y = opix >> 7;
    int h = Y >> 1, p = Y & 1, w = X >> 1, q = X & 1;
    int r = g*4 + p*2 + q;
    float offx = offb[((long)(b*32 + r)      << 12) + (h << 6) + w];
    float offy = offb[((long)(b*32 + 16 + r) << 12) + (h << 6) + w];
    float gx = fminf(fmaxf(2.f * (w + 0.5f + offx) - 0.5f, 0.f), 127.f);
    float gy = fminf(fmaxf(2.f * (h + 0.5f + offy) - 0.5f, 0.f), 127.f);
    float x0f = floorf(gx), y0f = floorf(gy);
    float tx = gx - x0f, ty = gy - y0f;
    int x0 = (int)x0f, y0 = (int)y0f;
    int x1 = min(x0 + 1, 127), y1 = min(y0 + 1, 127);
    float w11 = tx * ty, w10 = ty - w11, w01 = tx - w11, w00 = 1.f - tx - ty + w11;
    const unsigned short* base = lrupT + (((long)b << 14) << 8) + (g << 6) + ch0;
    long a00 = ((long)((y0 << 7) + x0)) << 8, a01 = ((long)((y0 << 7) + x1)) << 8;
    long a10 = ((long)((y1 << 7) + x0)) << 8, a11 = ((long)((y1 << 7) + x1)) << 8;
    OT* op = out + ((long)(b * 256 + g * 64 + ch0) << 14) + opix;
    #pragma unroll
    for (int c8 = 0; c8 < 4; c8++) {
        uint4 v00 = *(const uint4*)(base + a00 + c8*8);
        uint4 v01 = *(const uint4*)(base + a01 + c8*8);
        uint4 v10 = *(const uint4*)(base + a10 + c8*8);
        uint4 v11 = *(const uint4*)(base + a11 + c8*8);
        const unsigned short* u00 = (const unsigned short*)&v00;
        const unsigned short* u01 = (const unsigned short*)&v01;
        const unsigned short* u10 = (const unsigned short*)&v10;
        const unsigned short* u11 = (const unsigned short*)&v11;
        #pragma unroll
        for (int t = 0; t < 8; t++) {
            float res = bfu(u00[t])*w00 + bfu(u01[t])*w01 + bfu(u10[t])*w10 + bfu(u11[t])*w11;
            stT<OT>(op, ((long)(c8*8 + t) << 14), res);
        }
    }
}
__global__ void k_gridsampleT(const bf16* lrupT, const float* offb, void* out, long outOff,
                              int Bn, const int* flag)
{
    if (*flag) gridsampleT_body<float>((const unsigned short*)lrupT, offb, (float*)out + outOff, Bn);
    else       gridsampleT_body<bf16 >((const unsigned short*)lrupT, offb, (bf16*)out + outOff, Bn);
}

extern "C" void kernel_launch(void* const* d_in, const int* in_sizes, int n_in,
                              void* d_out, int out_size, void* d_ws, size_t ws_size,
                              hipStream_t stream) {
    const void* hr_feat = d_in[0];
    const void* lr_feat = d_in[1];

    const int B = 2, HH = 128, HL = 64;
    const int HWH = HH*HH, HWL = HL*HL;

    int*   flag = (int*)d_ws;
    float* stat = (float*)d_ws + 4;
    float* P    = (float*)d_ws + 80;
    float* ws   = P + ((P_TOT + 63) & ~63);

    size_t o = 0;
    float* ch0    = ws + o; o += (size_t)B*64*HWH;
    float* clb    = ws + o; o += (size_t)B*64*HWL;
    float* maskHH = ws + o; o += (size_t)B*9*HWH;
    float* tmp9   = ws + o; o += (size_t)B*9*HWH;
    float* chn    = ws + o; o += (size_t)B*64*HWH;
    float* m25a   = ws + o; o += (size_t)B*25*HWH;
    float* m25b   = ws + o; o += (size_t)B*25*HWH;
    float* m25c   = ws + o; o += (size_t)B*25*HWH;
    float* enccl  = ws + o; o += (size_t)B*25*HWL;
    float* enc2cl = ws + o; o += (size_t)B*9*HWL;
    bf16*  lrupT  = (bf16*)(ws + o); o += (size_t)B*256*HWH/2;   // transposed lr_up [b][pix][256]
    float* lrx    = ws + o; o += (size_t)B*64*HWL;
    float* hrsim  = ws + o; o += (size_t)B*8*HWH;
    float* lrsim  = ws + o; o += (size_t)B*8*HWL;
    float* qhro   = ws + o; o += (size_t)B*8*HWH;
    float* qlro   = ws + o; o += (size_t)B*32*HWL;
    float* qhrd   = ws + o; o += (size_t)B*8*HWH;
    float* qlrd   = ws + o; o += (size_t)B*32*HWL;
    float* offb   = ws + o; o += (size_t)B*32*HWL;
    float* hrx   = ch0;     // ch0 dead after step 5
    float* maskH = m25b;    // m25b dead after step 9
    // partial/scratch aliases over verified-dead zones:
    float* pbufA  = maskHH;          // steps 1-2
    float* pbuf3  = tmp9;            // step 3
    float* pbuf6  = m25b;            // step 6
    float* pbufL8 = (float*)lrupT;   // steps 8,11 (before step 15 writes lrupT)
    float* pbufT  = chn;             // steps 18-23
    bf16*  lrfT   = (bf16*)hrsim;    // lr_feat transposed [b][4096][256] bf16 (2.1M ushort
                                     // = 1.05M floats; hrsim..qhro zone dead until step 18)
    (void)ws_size; (void)n_in;

    long out1Off = (long)B*25*HWH;
    long out2Off = out1Off + (long)B*256*HWH;

    const float* pw_hrc = P + P_W_HRC;  const float* pb_hrc = P + P_B_HRC;
    const float* pw_lrc = P + P_W_LRC;  const float* pb_lrc = P + P_B_LRC;
    const float* pw_enc = P + P_W_ENC;  const float* pb_enc = P + P_B_ENC;
    const float* pw_enc2= P + P_W_ENC2; const float* pb_enc2= P + P_B_ENC2;
    const float* pgnhw  = P + P_GNHW;   const float* pgnhb  = P + P_GNHB;
    const float* pgnlw  = P + P_GNLW;   const float* pgnlb  = P + P_GNLB;
    const float* pw_off = P + P_W_OFF;  const float* pb_off = P + P_B_OFF;
    const float* pw_hoff= P + P_W_HOFF; const float* pb_hoff= P + P_B_HOFF;
    const float* pw_ds  = P + P_W_DS;   const float* pb_ds  = P + P_B_DS;
    const float* pw_hds = P + P_W_HDS;  const float* pb_hds = P + P_B_HDS;

    // 0. dtype detect + weight prep + lr_feat transpose (channels-last)
    int nDet = in_sizes[0] < 16384 ? in_sizes[0] : 16384;
    k_detect<<<1, TPB, 0, stream>>>(hr_feat, nDet, flag, stat);
    k_prep<<<nblk(P_TOT), TPB, 0, stream>>>(d_in[2],d_in[3],d_in[4],d_in[5],d_in[6],d_in[7],
        d_in[8],d_in[9],d_in[10],d_in[11],d_in[12],d_in[13],d_in[14],d_in[15],d_in[16],
        d_in[17],d_in[18],d_in[19],d_in[20],d_in[21], P, flag);
    k_transpLR<<<B*4*64, TPB, 0, stream>>>(lr_feat, lrfT, B, flag);

    // 1. ch0 = 1x1(hr_feat): 4 chunks x CS64, co-split x2 (grid.y = 8)
    k_conv1x1p<32><<<dim3(nblk((long)B*HWH),8), TPB, 0, stream>>>(hr_feat, pw_hrc, pbufA, B, 256, HWH, 64, flag);
    k_convr<<<nblk((long)B*64*HWH), TPB, 0, stream>>>(pbufA, pb_hrc, ch0, B, 64, HWH, 4);
    // 2. clb = 1x1(lr_feat): 16 chunks x CS16, co-split x2 (grid.y = 32)
    k_conv1x1p<32><<<dim3(nblk((long)B*HWL),32), TPB, 0, stream>>>(lr_feat, pw_lrc, pbufA, B, 256, HWL, 16, flag);
    k_convr<<<nblk((long)B*64*HWL), TPB, 0, stream>>>(pbufA, pb_lrc, clb, B, 64, HWL, 16);
    // 3. mask_hr_hr: 8 chunks x CS8
    k_conv3x3p<9><<<dim3(nblk((long)B*HWH),8), TPB, 0, stream>>>(ch0, pw_enc2, pbuf3, B, 64, HH, HH, 8);
    k_convr<<<nblk((long)B*9*HWH), TPB, 0, stream>>>(pbuf3, pb_enc2, maskHH, B, 9, HWH, 8);
    // 4-5. mh_init, ch = 2*ch0 - carafe3(ch0)
    k_knorm<3><<<nblk((long)B*HWH), TPB, 0, stream>>>(maskHH, tmp9, nullptr, B, HH, HH, flag);
    k_carafe3c_ws<<<nblk((long)B*8*16384), TPB, 0, stream>>>(ch0, tmp9, chn, B);
    // 6. mask_lr_hr: 8 chunks x CS8
    k_conv3x3p<25><<<dim3(nblk((long)B*HWH),8), TPB, 0, stream>>>(chn, pw_enc, pbuf6, B, 64, HH, HH, 8);
    k_convr<<<nblk((long)B*25*HWH), TPB, 0, stream>>>(pbuf6, pb_enc, m25a, B, 25, HWH, 8);
    // 7. ml_init -> m25b
    k_knorm<5><<<nblk((long)B*HWH), TPB, 0, stream>>>(m25a, m25b, nullptr, B, HH, HH, flag);
    // 8. enccl: 16 chunks x CS4
    k_conv3x3p<25><<<dim3(nblk((long)B*HWL),16), TPB, 0, stream>>>(clb, pw_enc, pbufL8, B, 64, HL, HL, 4);
    k_convr<<<nblk((long)B*25*HWL), TPB, 0, stream>>>(pbufL8, pb_enc, enccl, B, 25, HWL, 16);
    // 9. mask_lr = mask_lr_hr + carafe5(enccl, ml_init): C=25, CG=5
    k_carafe5_ws<5><<<nblk((long)B*5*16384), TPB, 0, stream>>>(enccl, m25b, m25a, m25c, B, 25);
    // 10. mask_lr_n -> m25a + bf16 output 0
    k_knorm<5><<<nblk((long)B*HWH), TPB, 0, stream>>>(m25c, m25a, d_out, B, HH, HH, flag);
    // 11. enc2cl: 16 chunks x CS4
    k_conv3x3p<9><<<dim3(nblk((long)B*HWL),16), TPB, 0, stream>>>(clb, pw_enc2, pbufL8, B, 64, HL, HL, 4);
    k_convr<<<nblk((long)B*9*HWL), TPB, 0, stream>>>(pbufL8, pb_enc2, enc2cl, B, 9, HWL, 16);
    // 12. mask_hr = mask_hr_hr + carafe5(enc2cl, mask_lr_n): C=9, CG=3
    k_carafe5_ws<3><<<nblk((long)B*3*16384), TPB, 0, stream>>>(enc2cl, m25a, maskHH, maskH, B, 9);
    // 13-14. mask_hr_n, hr_out -> output 1
    k_knorm<3><<<nblk((long)B*HWH), TPB, 0, stream>>>(maskH, tmp9, nullptr, B, HH, HH, flag);
    k_carafe3c_io<<<nblk((long)B*32*16384), TPB, 0, stream>>>(hr_feat, tmp9, d_out, out1Off, B, flag);
    // 15. lr_up (transposed): wave=(b,ipix), lane=4-channel group; XCD-swizzled
    k_carafe5T<<<B*4096/4, TPB, 0, stream>>>(lrfT, m25a, lrupT, B);
    // 16-17. group norms
    k_gnstat<<<16*32, TPB, 0, stream>>>(chn, stat, 0, 32, 8*HWH);
    k_gnapply<<<nblk((long)B*64*HWH), TPB, 0, stream>>>(chn, stat, 0, pgnhw, pgnhb, hrx, 8, 8, HWH, B);
    k_gnstat<<<16*8, TPB, 0, stream>>>(clb, stat, 32, 8, 8*HWL);
    k_gnapply<<<nblk((long)B*64*HWL), TPB, 0, stream>>>(clb, stat, 32, pgnlw, pgnlb, lrx, 8, 8, HWL, B);
    // 18. hrsim: 8 chunks x CS8
    k_simp<<<dim3(nblk((long)B*HWH),8), TPB, 0, stream>>>(hrx, pbufT, B, HH, HH, 8);
    k_simr<<<nblk((long)B*HWH), TPB, 0, stream>>>(pbufT, hrsim, B, HWH, 8);
    // 19. lrsim: 16 chunks x CS4
    k_simp<<<dim3(nblk((long)B*HWL),16), TPB, 0, stream>>>(lrx, pbufT, B, HL, HL, 4);
    k_simr<<<nblk((long)B*HWL), TPB, 0, stream>>>(pbufT, lrsim, B, HWL, 16);
    // 20. qhro: 4 chunks x CS2
    k_conv3x3p<8><<<dim3(nblk((long)B*HWH),4), TPB, 0, stream>>>(hrsim, pw_hoff, pbufT, B, 8, HH, HH, 2);
    k_convr<<<nblk((long)B*8*HWH), TPB, 0, stream>>>(pbufT, pb_hoff, qhro, B, 8, HWH, 4);
    // 21. qlro: 8 chunks x CS1
    k_conv3x3p<32><<<dim3(nblk((long)B*HWL),8), TPB, 0, stream>>>(lrsim, pw_off, pbufT, B, 8, HL, HL, 1);
    k_convr<<<nblk((long)B*32*HWL), TPB, 0, stream>>>(pbufT, pb_off, qlro, B, 32, HWL, 8);
    // 22. qhrd: 8 chunks x CS8
    k_conv3x3p<8><<<dim3(nblk((long)B*HWH),8), TPB, 0, stream>>>(hrx, pw_hds, pbufT, B, 64, HH, HH, 8);
    k_convr<<<nblk((long)B*8*HWH), TPB, 0, stream>>>(pbufT, pb_hds, qhrd, B, 8, HWH, 8);
    // 23. qlrd: 16 chunks x CS4
    k_conv3x3p<32><<<dim3(nblk((long)B*HWL),16), TPB, 0, stream>>>(lrx, pw_ds, pbufT, B, 64, HL, HL, 4);
    k_convr<<<nblk((long)B*32*HWL), TPB, 0, stream>>>(pbufT, pb_ds, qlrd, B, 32, HWL, 16);
    // 24. offset assembly
    k_offset<<<nblk((long)B*32*HWL), TPB, 0, stream>>>(qlro, qhro, qlrd, qhrd, offb, B);
    // 25. grid sample from lrupT -> output 2 (2 channel halves)
    k_gridsampleT<<<dim3(nblk((long)B*4*HWH),2), TPB, 0, stream>>>(lrupT, offb, d_out, out2Off, B, flag);
}

// Round 10
// 534.186 us; speedup vs baseline: 2.9905x; 1.0390x over previous
//
#include <hip/hip_runtime.h>
#include <hip/hip_bf16.h>

typedef __hip_bfloat16 bf16;
#define TPB 256

__device__ __forceinline__ float toF(float v){ return v; }
__device__ __forceinline__ float toF(bf16 v){ return __bfloat162float(v); }
__device__ __forceinline__ float bfu(unsigned short u){
    unsigned int x = ((unsigned int)u) << 16;
    return __uint_as_float(x);
}
template<typename T> __device__ __forceinline__ void stT(T* p, long i, float v);
template<> __device__ __forceinline__ void stT<float>(float* p, long i, float v){ p[i] = v; }
template<> __device__ __forceinline__ void stT<bf16>(bf16* p, long i, float v){ p[i] = __float2bfloat16(v); }

__device__ __forceinline__ void st4bf(bf16* p, const float* a){
    bf16 t0 = __float2bfloat16(a[0]);
    bf16 t1 = __float2bfloat16(a[1]);
    bf16 t2 = __float2bfloat16(a[2]);
    bf16 t3 = __float2bfloat16(a[3]);
    ushort4 pk;
    pk.x = *(unsigned short*)&t0;
    pk.y = *(unsigned short*)&t1;
    pk.z = *(unsigned short*)&t2;
    pk.w = *(unsigned short*)&t3;
    *(ushort4*)p = pk;
}

static inline int nblk(long n){ return (int)((n + TPB - 1) / TPB); }

// ================= dtype detection + stat zero =================
__global__ void k_detect(const void* hr, int n, int* flag, float* stat)
{
    if (threadIdx.x < 64) stat[threadIdx.x] = 0.f;
    const unsigned short* u = (const unsigned short*)hr;
    int nan = 0, oz = 0, ot = 0;
    for (int i = threadIdx.x; i < n; i += TPB) {
        unsigned short a = u[i] & 0x7FFF;
        if (a >= 0x7F80) nan++;
        if (i & 1) { ot++; if (a == 0) oz++; }
    }
    __shared__ int s1[TPB], s2[TPB], s3[TPB];
    s1[threadIdx.x] = nan; s2[threadIdx.x] = oz; s3[threadIdx.x] = ot;
    __syncthreads();
    if (threadIdx.x == 0) {
        int a = 0, b = 0, c = 0;
        for (int i = 0; i < TPB; i++) { a += s1[i]; b += s2[i]; c += s3[i]; }
        *flag = (a >= 6 || (long)b * 10 >= (long)c * 9) ? 1 : 0;
    }
}

// ================= weight prep: fp32 + transpose to [ci][co][taps] =================
#define P_W_HRC 0
#define P_B_HRC 16384
#define P_W_LRC 16448
#define P_B_LRC 32832
#define P_W_ENC 32896
#define P_B_ENC 47296
#define P_W_ENC2 47321
#define P_B_ENC2 52505
#define P_GNHW 52514
#define P_GNHB 52578
#define P_GNLW 52642
#define P_GNLB 52706
#define P_W_OFF 52770
#define P_B_OFF 55074
#define P_W_HOFF 55106
#define P_B_HOFF 55682
#define P_W_DS 55690
#define P_B_DS 74122
#define P_W_HDS 74154
#define P_B_HDS 78762
#define P_TOT 78770

__constant__ int c_segsz[20]  = {16384,64,16384,64,14400,25,5184,9,64,64,64,64,2304,32,576,8,18432,32,4608,8};
__constant__ int c_segbase[20]= {P_W_HRC,P_B_HRC,P_W_LRC,P_B_LRC,P_W_ENC,P_B_ENC,P_W_ENC2,P_B_ENC2,
                                 P_GNHW,P_GNHB,P_GNLW,P_GNLB,P_W_OFF,P_B_OFF,P_W_HOFF,P_B_HOFF,
                                 P_W_DS,P_B_DS,P_W_HDS,P_B_HDS};
__constant__ int c_segcin[20] = {256,0,256,0, 64,0, 64,0, 0,0,0,0, 8,0, 8,0, 64,0, 64,0};
__constant__ int c_segcout[20]= { 64,0, 64,0, 25,0,  9,0, 0,0,0,0,32,0, 8,0, 32,0,  8,0};
__constant__ int c_segtap[20] = {  1,0,  1,0,  9,0,  9,0, 0,0,0,0, 9,0, 9,0,  9,0,  9,0};

__global__ void k_prep(const void* p0,const void* p1,const void* p2,const void* p3,
                       const void* p4,const void* p5,const void* p6,const void* p7,
                       const void* p8,const void* p9,const void* p10,const void* p11,
                       const void* p12,const void* p13,const void* p14,const void* p15,
                       const void* p16,const void* p17,const void* p18,const void* p19,
                       float* dst, const int* flag)
{
    int idx = blockIdx.x * TPB + threadIdx.x;
    if (idx >= P_TOT) return;
    int s = 0, off = idx;
    while (off >= c_segsz[s]) { off -= c_segsz[s]; s++; }
    const void* sp;
    switch (s) {
        case 0: sp=p0; break;  case 1: sp=p1; break;  case 2: sp=p2; break;  case 3: sp=p3; break;
        case 4: sp=p4; break;  case 5: sp=p5; break;  case 6: sp=p6; break;  case 7: sp=p7; break;
        case 8: sp=p8; break;  case 9: sp=p9; break;  case 10: sp=p10; break; case 11: sp=p11; break;
        case 12: sp=p12; break; case 13: sp=p13; break; case 14: sp=p14; break; case 15: sp=p15; break;
        case 16: sp=p16; break; case 17: sp=p17; break; case 18: sp=p18; break; default: sp=p19; break;
    }
    float v = (*flag) ? ((const float*)sp)[off] : toF(((const bf16*)sp)[off]);
    int doff = off;
    int cin = c_segcin[s];
    if (cin) {
        int t = c_segtap[s], cout = c_segcout[s];
        int co = off / (cin * t);
        int r  = off % (cin * t);
        int ci = r / t, k = r % t;
        doff = (ci * cout + co) * t + k;
    }
    dst[c_segbase[s] + doff] = v;
}

// ================= lr_feat transpose: [b][256][4096] -> bf16 [b][4096][256] =============
template<typename T>
__device__ void transpLR_body(const T* __restrict__ x, bf16* __restrict__ xT, int Bn)
{
    __shared__ float tile[64][65];
    int bid = blockIdx.x;                 // b * 4 cgroup * 64 pgroup
    int pg = bid & 63;
    int cg = (bid >> 6) & 3;
    int b  = bid >> 8;
    int tid = threadIdx.x;
    int tr = tid >> 6, tc = tid & 63;
    for (int i = 0; i < 16; i++) {
        int c = tr + i * 4;
        tile[c][tc] = toF(x[(((long)(b * 256 + cg * 64 + c)) << 12) + (pg << 6) + tc]);
    }
    __syncthreads();
    for (int i = 0; i < 16; i++) {
        int p = tr + i * 4;
        xT[((((long)b << 12) + (pg << 6) + p) << 8) + (cg << 6) + tc] = __float2bfloat16(tile[tc][p]);
    }
}
__global__ void k_transpLR(const void* x, bf16* xT, int Bn, const int* flag)
{
    if (*flag) transpLR_body<float>((const float*)x, xT, Bn);
    else       transpLR_body<bf16 >((const bf16*)x,  xT, Bn);
}

// ===== carafe5-up channels-last: wave = (b, ipix), lane = 4-channel group =====
__global__ void k_carafe5T(const bf16* __restrict__ featT, const float* __restrict__ mask,
                           bf16* __restrict__ outT, int Bn)
{
    int lane = threadIdx.x & 63;
    int nwg = gridDim.x;
    int bid = blockIdx.x;
    int swz = (nwg & 7) ? bid : ((bid & 7) * (nwg >> 3) + (bid >> 3));
    int wid = (swz << 2) | (threadIdx.x >> 6);
    wid = __builtin_amdgcn_readfirstlane(wid);
    if (wid >= Bn * 4096) return;
    int ipix = wid & 4095;
    int b    = wid >> 12;
    int h = ipix >> 6, w = ipix & 63;
    const bf16*  fb = featT + (((long)b << 12) << 8) + (lane << 2);
    const float* mb = mask + (((long)b * 25) << 14) + (h << 8) + (w << 1);
    float a00[4], a01[4], a10[4], a11[4];
    #pragma unroll
    for (int t = 0; t < 4; t++) { a00[t]=0.f; a01[t]=0.f; a10[t]=0.f; a11[t]=0.f; }
    #pragma unroll
    for (int k = 0; k < 25; k++) {
        const int i = k / 5, j = k % 5;
        int yy = h + i - 2, xx = w + j - 2;
        bool v = (yy >= 0 && yy < 64 && xx >= 0 && xx < 64);
        int yc = v ? yy : 0, xc = v ? xx : 0;
        ushort4 u = *(const ushort4*)(fb + ((long)((yc << 6) + xc) << 8));
        float2 mr0 = *(const float2*)(mb + ((long)k << 14));
        float2 mr1 = *(const float2*)(mb + ((long)k << 14) + 128);
        float m00 = v ? mr0.x : 0.f, m01 = v ? mr0.y : 0.f;
        float m10 = v ? mr1.x : 0.f, m11 = v ? mr1.y : 0.f;
        float f0 = bfu(u.x), f1 = bfu(u.y), f2 = bfu(u.z), f3 = bfu(u.w);
        a00[0] += f0*m00; a00[1] += f1*m00; a00[2] += f2*m00; a00[3] += f3*m00;
        a01[0] += f0*m01; a01[1] += f1*m01; a01[2] += f2*m01; a01[3] += f3*m01;
        a10[0] += f0*m10; a10[1] += f1*m10; a10[2] += f2*m10; a10[3] += f3*m10;
        a11[0] += f0*m11; a11[1] += f1*m11; a11[2] += f2*m11; a11[3] += f3*m11;
    }
    bf16* op = outT + (((long)(b << 14) + (h << 8) + (w << 1)) << 8) + (lane << 2);
    st4bf(op, a00);                       // (2h,   2w)
    st4bf(op + 256, a01);                 // (2h,   2w+1)
    st4bf(op + (128 << 8), a10);          // (2h+1, 2w)
    st4bf(op + (128 << 8) + 256, a11);    // (2h+1, 2w+1)
}

// ===== 3x3 conv partials: grid.y = chunk*COG + co-group (co-split like 1x1) =====
// pbuf layout identical to unsplit version so k_convr is unchanged.
template<int COUT, int NCO>
__global__ void k_conv3x3p(const float* __restrict__ x, const float* __restrict__ wf,
                           float* __restrict__ pbuf, int Bn, int CIN, int H, int W, int CS)
{
    constexpr int COG = COUT / NCO;
    int HW = H * W;
    int idx = blockIdx.x * TPB + threadIdx.x;
    if (idx >= Bn * HW) return;
    int chunk = blockIdx.y / COG;
    int cog   = blockIdx.y % COG;
    int co0   = cog * NCO;
    int pix = idx % HW, b = idx / HW;
    int wx = pix % W, hy = pix / W;
    int off[9]; float msk[9];
    #pragma unroll
    for (int i = 0; i < 3; i++) {
        int yy = hy + i - 1; bool vy = (yy >= 0 && yy < H); int yc = vy ? yy : hy;
        #pragma unroll
        for (int j = 0; j < 3; j++) {
            int xx = wx + j - 1; bool v = vy && (xx >= 0 && xx < W);
            int xc = (xx >= 0 && xx < W) ? xx : wx;
            off[i*3+j] = yc * W + xc; msk[i*3+j] = v ? 1.f : 0.f;
        }
    }
    float acc[NCO];
    #pragma unroll
    for (int c = 0; c < NCO; c++) acc[c] = 0.f;
    int c0 = chunk * CS;
    const float* xb = x + ((long)b * CIN + c0) * HW;
    const float* wb = wf + ((long)c0 * COUT + co0) * 9;
    #pragma unroll 2
    for (int ci = 0; ci < CS; ci++) {
        const float* xc = xb + (long)ci * HW;
        float t[9];
        #pragma unroll
        for (int k = 0; k < 9; k++) t[k] = xc[off[k]] * msk[k];
        const float* wr = wb + (long)ci * COUT * 9;
        #pragma unroll
        for (int c = 0; c < NCO; c++) {
            const float* wp = wr + c * 9;
            acc[c] += t[0]*wp[0] + t[1]*wp[1] + t[2]*wp[2] + t[3]*wp[3] + t[4]*wp[4]
                    + t[5]*wp[5] + t[6]*wp[6] + t[7]*wp[7] + t[8]*wp[8];
        }
    }
    long pb = ((long)chunk * Bn + b) * COUT * (long)HW + (long)co0 * HW + pix;
    #pragma unroll
    for (int c = 0; c < NCO; c++) pbuf[pb + (long)c * HW] = acc[c];
}

// ================= conv reduce: out = bias + sum_chunks partial =================
__global__ void k_convr(const float* __restrict__ pbuf, const float* __restrict__ bias,
                        float* __restrict__ out, int Bn, int COUT, int HW, int nChunk)
{
    long idx = (long)blockIdx.x * TPB + threadIdx.x;
    if (idx >= (long)Bn * COUT * HW) return;
    int pix = idx % HW;
    int co  = (idx / HW) % COUT;
    int b   = idx / ((long)HW * COUT);
    float v = bias[co];
    for (int ch = 0; ch < nChunk; ch++)
        v += pbuf[(((long)ch * Bn + b) * COUT + co) * HW + pix];
    out[idx] = v;
}

// ===== 1x1 conv partials (COUT=64), grid.y = chunk*COG + co-group =====
template<typename T, int NCO>
__device__ void conv1x1p_body(const T* __restrict__ x, const float* __restrict__ wf,
                              float* __restrict__ pbuf, int Bn, int CIN, int HW, int CS)
{
    constexpr int COG = 64 / NCO;
    int idx = blockIdx.x * TPB + threadIdx.x;
    if (idx >= Bn * HW) return;
    int chunk = blockIdx.y / COG;
    int cog   = blockIdx.y % COG;
    int co0   = cog * NCO;
    int pix = idx % HW, b = idx / HW;
    float acc[NCO];
    #pragma unroll
    for (int c = 0; c < NCO; c++) acc[c] = 0.f;
    int c0 = chunk * CS;
    const T* xp = x + ((long)b * CIN + c0) * HW + pix;
    const float* wb = wf + (long)c0 * 64 + co0;
    #pragma unroll 4
    for (int ci = 0; ci < CS; ci++) {
        float v = toF(xp[(long)ci * HW]);
        const float* wr = wb + ci * 64;
        #pragma unroll
        for (int c = 0; c < NCO; c++) acc[c] += v * wr[c];
    }
    long pb = ((long)chunk * Bn + b) * 64 * (long)HW + (long)co0 * HW + pix;
    #pragma unroll
    for (int c = 0; c < NCO; c++) pbuf[pb + (long)c * HW] = acc[c];
}
template<int NCO>
__global__ void k_conv1x1p(const void* x, const float* wf, float* pbuf,
                           int Bn, int CIN, int HW, int CS, const int* flag)
{
    if (*flag) conv1x1p_body<float, NCO>((const float*)x, wf, pbuf, Bn, CIN, HW, CS);
    else       conv1x1p_body<bf16, NCO>((const bf16*)x,  wf, pbuf, Bn, CIN, HW, CS);
}

// ================= kernel_normalizer (planar in/out) =================
template<int K, typename OT>
__device__ void knorm_body(const float* __restrict__ mask, float* __restrict__ out,
                           OT* __restrict__ outb, int B, int H, int W)
{
    const int K2 = K * K;
    int HWi = H * W;
    int idx = blockIdx.x * TPB + threadIdx.x;
    if (idx >= B * HWi) return;
    int pix = idx % HWi;
    int b   = idx / HWi;
    long HW = (long)HWi;
    long base = (long)b * K2 * HW + pix;
    float v[K2];
    float m = -1e30f;
    for (int k = 0; k < K2; k++) { v[k] = mask[base + k*HW]; m = fmaxf(m, v[k]); }
    float s2 = 0.f;
    for (int k = 0; k < K2; k++) {
        int i = k / K, j = k % K;
        float hi = (K == 3) ? ((i==1)?1.f:0.08f) : ((i==2)?1.f:((i==1||i==3)?0.54f:0.08f));
        float hj = (K == 3) ? ((j==1)?1.f:0.08f) : ((j==2)?1.f:((j==1||j==3)?0.54f:0.08f));
        v[k] = expf(v[k] - m) * hi * hj;
        s2 += v[k];
    }
    float inv = 1.f / s2;
    for (int k = 0; k < K2; k++) {
        float r = v[k] * inv;
        out[base + k*HW] = r;
        if (outb) stT<OT>(outb, base + k*HW, r);
    }
}
template<int K>
__global__ void k_knorm(const float* mask, float* out, void* outb, int B, int H, int W, const int* flag)
{
    if (*flag) knorm_body<K, float>(mask, out, (float*)outb, B, H, W);
    else       knorm_body<K, bf16>(mask, out, (bf16*)outb, B, H, W);
}

// ================= carafe3 (2*f - carafe), planar mask, 8 channels/thread ============
template<typename TF, typename TO, int NC>
__device__ void carafe3c_body(const TF* __restrict__ feat, const float* __restrict__ mask,
                              TO* __restrict__ out, int Bn)
{
    constexpr int CH = NC / 8;
    int idx = blockIdx.x * TPB + threadIdx.x;
    if (idx >= Bn * CH * 16384) return;
    int px = idx & 16383;
    int cc = (idx >> 14) % CH;
    int b  = (idx >> 14) / CH;
    int wx = px & 127, hy = px >> 7;
    float mk[9]; int off[9];
    #pragma unroll
    for (int i = 0; i < 3; i++) {
        int yy = hy + i - 1; bool vy = (yy >= 0 && yy < 128); int yc = vy ? yy : hy;
        #pragma unroll
        for (int j = 0; j < 3; j++) {
            int xx = wx + j - 1; bool v = vy && (xx >= 0 && xx < 128);
            int xc = (xx >= 0 && xx < 128) ? xx : wx;
            int k = i*3 + j;
            float m = mask[(((long)b*9 + k) << 14) + px];
            mk[k] = v ? m : 0.f;
            off[k] = (yc << 7) + xc;
        }
    }
    long base = ((long)(b * NC + cc * 8) << 14);
    for (int c = 0; c < 8; c++) {
        const TF* fp = feat + base + ((long)c << 14);
        float ctr = 0.f, acc = 0.f;
        #pragma unroll
        for (int k = 0; k < 9; k++) {
            float v = toF(fp[off[k]]);
            if (k == 4) ctr = v;
            acc += v * mk[k];
        }
        stT<TO>(out, base + ((long)c << 14) + px, 2.f * ctr - acc);
    }
}
__global__ void k_carafe3c_ws(const float* feat, const float* mask, float* out, int Bn)
{
    carafe3c_body<float, float, 64>(feat, mask, out, Bn);
}
__global__ void k_carafe3c_io(const void* feat, const float* mask, void* out, long outOff,
                              int Bn, const int* flag)
{
    if (*flag) carafe3c_body<float, float, 256>((const float*)feat, mask, (float*)out + outOff, Bn);
    else       carafe3c_body<bf16, bf16, 256>((const bf16*)feat, mask, (bf16*)out + outOff, Bn);
}

// ===== carafe5 s=2 ws variant: thread = output pixel x channel-group; planar mask =====
template<typename TF, typename TO, bool ADD, int CG>
__device__ void carafe5_body(const TF* __restrict__ feat, const float* __restrict__ mask,
                             const float* __restrict__ add, TO* __restrict__ out,
                             int Bn, int C)
{
    int ng = C / CG;
    int idx = blockIdx.x * TPB + threadIdx.x;
    if (idx >= Bn * ng * 16384) return;
    int px = idx & 16383;
    int gi = (idx >> 14) % ng;
    int b  = (idx >> 14) / ng;
    int X = px & 127, Y = px >> 7;
    int h = Y >> 1, w = X >> 1;
    float mk[25]; int off[25];
    const float* mb = mask + (((long)b * 25) << 14) + px;
    #pragma unroll
    for (int i = 0; i < 5; i++) {
        int yy = h + i - 2; bool vy = (yy >= 0 && yy < 64); int yc = vy ? yy : 0;
        #pragma unroll
        for (int j = 0; j < 5; j++) {
            int xx = w + j - 2; bool v = vy && (xx >= 0 && xx < 64);
            int xc = (xx >= 0 && xx < 64) ? xx : 0;
            int k = i*5 + j;
            mk[k] = v ? mb[(long)k << 14] : 0.f;
            off[k] = (yc << 6) + xc;
        }
    }
    int c0 = gi * CG;
    for (int c = 0; c < CG; c++) {
        long fb = ((long)(b * C + c0 + c) << 12);
        long ob = ((long)(b * C + c0 + c) << 14) + px;
        const TF* fp = feat + fb;
        float acc = ADD ? add[ob] : 0.f;
        #pragma unroll
        for (int k = 0; k < 25; k++) acc += toF(fp[off[k]]) * mk[k];
        stT<TO>(out, ob, acc);
    }
}
template<int CG>
__global__ void k_carafe5_ws(const float* feat, const float* mask, const float* add,
                             float* out, int Bn, int C)
{
    carafe5_body<float, float, true, CG>(feat, mask, add, out, Bn, C);
}

// ================= group norm: slice partial stats (atomic) + apply =================
__global__ void k_gnstat(const float* __restrict__ x, float* __restrict__ stat, int statBase,
                         int S, int N)
{
    int bid = blockIdx.x;
    int bg = bid / S, sl = bid % S;
    int seg = N / S;
    long base = (long)bg * N + (long)sl * seg;
    float s = 0.f, ss = 0.f;
    for (int i = threadIdx.x; i < seg; i += TPB) {
        float v = x[base + i]; s += v; ss += v * v;
    }
    __shared__ float sh[8];
    for (int off = 32; off; off >>= 1) { s += __shfl_down(s, off); ss += __shfl_down(ss, off); }
    int wave = threadIdx.x >> 6, lane = threadIdx.x & 63;
    if (lane == 0) { sh[wave] = s; sh[4 + wave] = ss; }
    __syncthreads();
    if (threadIdx.x == 0) {
        float ts = 0.f, tss = 0.f;
        for (int i = 0; i < TPB/64; i++) { ts += sh[i]; tss += sh[4 + i]; }
        atomicAdd(&stat[statBase + bg*2], ts);
        atomicAdd(&stat[statBase + bg*2 + 1], tss);
    }
}
__global__ void k_gnapply(const float* __restrict__ x, const float* __restrict__ stat, int statBase,
                          const float* __restrict__ gamma, const float* __restrict__ beta,
                          float* __restrict__ out, int G, int Cg, int HW, int Bn)
{
    long idx = (long)blockIdx.x * TPB + threadIdx.x;
    long total = (long)Bn * G * Cg * HW;
    if (idx >= total) return;
    int bgN = Cg * HW;
    int bg = idx / bgN;
    int r  = idx % bgN;
    int g = bg % G;
    int c = g * Cg + r / HW;
    float s = stat[statBase + bg*2], ss = stat[statBase + bg*2 + 1];
    float mean = s / bgN;
    float inv = rsqrtf(ss / bgN - mean * mean + 1e-5f);
    out[idx] = (x[idx] - mean) * inv * gamma[c] + beta[c];
}

// ================= cosine sim partials (dilation 2) + finalize =================
__global__ void k_simp(const float* __restrict__ x, float* __restrict__ pbuf,
                       int Bn, int H, int W, int CS)
{
    int HW = H * W;
    int idx = blockIdx.x * TPB + threadIdx.x;
    if (idx >= Bn * HW) return;
    int chunk = blockIdx.y;
    int pix = idx % HW, b = idx / HW;
    int wx = pix % W, hy = pix / W;
    const int dyv[8] = {-2,-2,-2, 0, 0, 2, 2, 2};
    const int dxv[8] = {-2, 0, 2,-2, 2,-2, 0, 2};
    int off[8]; float msk[8];
    #pragma unroll
    for (int n = 0; n < 8; n++) {
        int yy = hy + dyv[n], xx = wx + dxv[n];
        bool v = (yy >= 0 && yy < H && xx >= 0 && xx < W);
        off[n] = v ? yy * W + xx : pix;
        msk[n] = v ? 1.f : 0.f;
    }
    float dc = 0.f, num[8], dn[8];
    #pragma unroll
    for (int n = 0; n < 8; n++) { num[n] = 0.f; dn[n] = 0.f; }
    const float* xb = x + ((long)b * 64 + chunk * CS) * HW;
    #pragma unroll 2
    for (int ci = 0; ci < CS; ci++) {
        const float* xc = xb + (long)ci * HW;
        float c0 = xc[pix];
        dc += c0 * c0;
        #pragma unroll
        for (int n = 0; n < 8; n++) {
            float v = xc[off[n]] * msk[n];
            num[n] += c0 * v; dn[n] += v * v;
        }
    }
    long base = ((long)chunk * Bn + b) * 17 * (long)HW + pix;
    pbuf[base] = dc;
    #pragma unroll
    for (int n = 0; n < 8; n++) {
        pbuf[base + (long)(1 + n) * HW] = num[n];
        pbuf[base + (long)(9 + n) * HW] = dn[n];
    }
}
__global__ void k_simr(const float* __restrict__ pbuf, float* __restrict__ out,
                       int Bn, int HW, int nChunk)
{
    int idx = blockIdx.x * TPB + threadIdx.x;
    if (idx >= Bn * HW) return;
    int pix = idx % HW, b = idx / HW;
    float dc = 0.f, num[8], dn[8];
    #pragma unroll
    for (int n = 0; n < 8; n++) { num[n] = 0.f; dn[n] = 0.f; }
    for (int ch = 0; ch < nChunk; ch++) {
        long base = ((long)ch * Bn + b) * 17 * (long)HW + pix;
        dc += pbuf[base];
        #pragma unroll
        for (int n = 0; n < 8; n++) {
            num[n] += pbuf[base + (long)(1 + n) * HW];
            dn[n]  += pbuf[base + (long)(9 + n) * HW];
        }
    }
    float nc = fmaxf(sqrtf(dc), 1e-8f);
    #pragma unroll
    for (int n = 0; n < 8; n++)
        out[((long)(b*8 + n)) * HW + pix] = num[n] / (nc * fmaxf(sqrtf(dn[n]), 1e-8f));
}

// ================= offset assembly =================
__global__ void k_offset(const float* __restrict__ lro, const float* __restrict__ hro,
                         const float* __restrict__ lrd, const float* __restrict__ hrd,
                         float* __restrict__ outoff, int B)
{
    int idx = blockIdx.x * TPB + threadIdx.x;
    int total = B * 32 * 64 * 64;
    if (idx >= total) return;
    int wx = idx & 63;
    int hy = (idx >> 6) & 63;
    int o  = (idx >> 12) & 31;
    int b  = idx >> 17;
    int c = o >> 2, p = (o >> 1) & 1, q = o & 1;
    long hridx = ((long)(b*8 + c) * 128 + 2*hy + p) * 128 + 2*wx + q;
    float off = lro[idx] + hro[hridx];
    float dsv = lrd[idx] + hrd[hridx];
    float sg = 1.f / (1.f + expf(-dsv));
    int comp = o >> 4;
    float ip = (comp == 0) ? (q ? 0.25f : -0.25f) : (p ? 0.25f : -0.25f);
    outoff[idx] = off * sg + ip;
}

// ===== grid sample from transposed lrupT[b][pix][256], grid.y = channel half =====
template<typename OT>
__device__ void gridsampleT_body(const unsigned short* __restrict__ lrupT,
                                 const float* __restrict__ offb, OT* __restrict__ out, int Bn)
{
    int idx = blockIdx.x * TPB + threadIdx.x;
    if (idx >= Bn * 4 * 16384) return;
    int ch0 = blockIdx.y << 5;            // 2 halves of 32 channels
    int opix = idx & 16383;
    int g = (idx >> 14) & 3, b = idx >> 16;
    int X = opix & 127, Y = opix >> 7;
    int h = Y >> 1, p = Y & 1, w = X >> 1, q = X & 1;
    int r = g*4 + p*2 + q;
    float offx = offb[((long)(b*32 + r)      << 12) + (h << 6) + w];
    float offy = offb[((long)(b*32 + 16 + r) << 12) + (h << 6) + w];
    float gx = fminf(fmaxf(2.f * (w + 0.5f + offx) - 0.5f, 0.f), 127.f);
    float gy = fminf(fmaxf(2.f * (h + 0.5f + offy) - 0.5f, 0.f), 127.f);
    float x0f = floorf(gx), y0f = floorf(gy);
    float tx = gx - x0f, ty = gy - y0f;
    int x0 = (int)x0f, y0 = (int)y0f;
    int x1 = min(x0 + 1, 127), y1 = min(y0 + 1, 127);
    float w11 = tx * ty, w10 = ty - w11, w01 = tx - w11, w00 = 1.f - tx - ty + w11;
    const unsigned short* base = lrupT + (((long)b << 14) << 8) + (g << 6) + ch0;
    long a00 = ((long)((y0 << 7) + x0)) << 8, a01 = ((long)((y0 << 7) + x1)) << 8;
    long a10 = ((long)((y1 << 7) + x0)) << 8, a11 = ((long)((y1 << 7) + x1)) << 8;
    OT* op = out + ((long)(b * 256 + g * 64 + ch0) << 14) + opix;
    #pragma unroll
    for (int c8 = 0; c8 < 4; c8++) {
        uint4 v00 = *(const uint4*)(base + a00 + c8*8);
        uint4 v01 = *(const uint4*)(base + a01 + c8*8);
        uint4 v10 = *(const uint4*)(base + a10 + c8*8);
        uint4 v11 = *(const uint4*)(base + a11 + c8*8);
        const unsigned short* u00 = (const unsigned short*)&v00;
        const unsigned short* u01 = (const unsigned short*)&v01;
        const unsigned short* u10 = (const unsigned short*)&v10;
        const unsigned short* u11 = (const unsigned short*)&v11;
        #pragma unroll
        for (int t = 0; t < 8; t++) {
            float res = bfu(u00[t])*w00 + bfu(u01[t])*w01 + bfu(u10[t])*w10 + bfu(u11[t])*w11;
            stT<OT>(op, ((long)(c8*8 + t) << 14), res);
        }
    }
}
__global__ void k_gridsampleT(const bf16* lrupT, const float* offb, void* out, long outOff,
                              int Bn, const int* flag)
{
    if (*flag) gridsampleT_body<float>((const unsigned short*)lrupT, offb, (float*)out + outOff, Bn);
    else       gridsampleT_body<bf16 >((const unsigned short*)lrupT, offb, (bf16*)out + outOff, Bn);
}

extern "C" void kernel_launch(void* const* d_in, const int* in_sizes, int n_in,
                              void* d_out, int out_size, void* d_ws, size_t ws_size,
                              hipStream_t stream) {
    const void* hr_feat = d_in[0];
    const void* lr_feat = d_in[1];

    const int B = 2, HH = 128, HL = 64;
    const int HWH = HH*HH, HWL = HL*HL;

    int*   flag = (int*)d_ws;
    float* stat = (float*)d_ws + 4;
    float* P    = (float*)d_ws + 80;
    float* ws   = P + ((P_TOT + 63) & ~63);

    size_t o = 0;
    float* ch0    = ws + o; o += (size_t)B*64*HWH;
    float* clb    = ws + o; o += (size_t)B*64*HWL;
    float* maskHH = ws + o; o += (size_t)B*9*HWH;
    float* tmp9   = ws + o; o += (size_t)B*9*HWH;
    float* chn    = ws + o; o += (size_t)B*64*HWH;
    float* m25a   = ws + o; o += (size_t)B*25*HWH;
    float* m25b   = ws + o; o += (size_t)B*25*HWH;
    float* m25c   = ws + o; o += (size_t)B*25*HWH;
    float* enccl  = ws + o; o += (size_t)B*25*HWL;
    float* enc2cl = ws + o; o += (size_t)B*9*HWL;
    bf16*  lrupT  = (bf16*)(ws + o); o += (size_t)B*256*HWH/2;   // transposed lr_up [b][pix][256]
    float* lrx    = ws + o; o += (size_t)B*64*HWL;
    float* hrsim  = ws + o; o += (size_t)B*8*HWH;
    float* lrsim  = ws + o; o += (size_t)B*8*HWL;
    float* qhro   = ws + o; o += (size_t)B*8*HWH;
    float* qlro   = ws + o; o += (size_t)B*32*HWL;
    float* qhrd   = ws + o; o += (size_t)B*8*HWH;
    float* qlrd   = ws + o; o += (size_t)B*32*HWL;
    float* offb   = ws + o; o += (size_t)B*32*HWL;
    float* hrx   = ch0;     // ch0 dead after step 5
    float* maskH = m25b;    // m25b dead after step 9
    // partial/scratch aliases over verified-dead zones:
    float* pbufA  = maskHH;          // steps 1-2
    float* pbuf3  = tmp9;            // step 3
    float* pbuf6  = m25b;            // step 6
    float* pbufL8 = (float*)lrupT;   // steps 8,11 (before step 15 writes lrupT)
    float* pbufT  = chn;             // steps 18-23
    bf16*  lrfT   = (bf16*)hrsim;    // lr_feat transposed [b][4096][256] bf16 (2.1M ushort
                                     // = 1.05M floats; hrsim..qhro zone dead until step 18)
    (void)ws_size; (void)n_in;

    long out1Off = (long)B*25*HWH;
    long out2Off = out1Off + (long)B*256*HWH;

    const float* pw_hrc = P + P_W_HRC;  const float* pb_hrc = P + P_B_HRC;
    const float* pw_lrc = P + P_W_LRC;  const float* pb_lrc = P + P_B_LRC;
    const float* pw_enc = P + P_W_ENC;  const float* pb_enc = P + P_B_ENC;
    const float* pw_enc2= P + P_W_ENC2; const float* pb_enc2= P + P_B_ENC2;
    const float* pgnhw  = P + P_GNHW;   const float* pgnhb  = P + P_GNHB;
    const float* pgnlw  = P + P_GNLW;   const float* pgnlb  = P + P_GNLB;
    const float* pw_off = P + P_W_OFF;  const float* pb_off = P + P_B_OFF;
    const float* pw_hoff= P + P_W_HOFF; const float* pb_hoff= P + P_B_HOFF;
    const float* pw_ds  = P + P_W_DS;   const float* pb_ds  = P + P_B_DS;
    const float* pw_hds = P + P_W_HDS;  const float* pb_hds = P + P_B_HDS;

    // 0. dtype detect + weight prep + lr_feat transpose (channels-last)
    int nDet = in_sizes[0] < 16384 ? in_sizes[0] : 16384;
    k_detect<<<1, TPB, 0, stream>>>(hr_feat, nDet, flag, stat);
    k_prep<<<nblk(P_TOT), TPB, 0, stream>>>(d_in[2],d_in[3],d_in[4],d_in[5],d_in[6],d_in[7],
        d_in[8],d_in[9],d_in[10],d_in[11],d_in[12],d_in[13],d_in[14],d_in[15],d_in[16],
        d_in[17],d_in[18],d_in[19],d_in[20],d_in[21], P, flag);
    k_transpLR<<<B*4*64, TPB, 0, stream>>>(lr_feat, lrfT, B, flag);

    // 1. ch0 = 1x1(hr_feat): 4 chunks x CS64, co-split x2 (grid.y = 8)
    k_conv1x1p<32><<<dim3(nblk((long)B*HWH),8), TPB, 0, stream>>>(hr_feat, pw_hrc, pbufA, B, 256, HWH, 64, flag);
    k_convr<<<nblk((long)B*64*HWH), TPB, 0, stream>>>(pbufA, pb_hrc, ch0, B, 64, HWH, 4);
    // 2. clb = 1x1(lr_feat): 16 chunks x CS16, co-split x2 (grid.y = 32)
    k_conv1x1p<32><<<dim3(nblk((long)B*HWL),32), TPB, 0, stream>>>(lr_feat, pw_lrc, pbufA, B, 256, HWL, 16, flag);
    k_convr<<<nblk((long)B*64*HWL), TPB, 0, stream>>>(pbufA, pb_lrc, clb, B, 64, HWL, 16);
    // 3. mask_hr_hr: 8 chunks x CS8, co-split x3 (grid.y = 24)
    k_conv3x3p<9,3><<<dim3(nblk((long)B*HWH),24), TPB, 0, stream>>>(ch0, pw_enc2, pbuf3, B, 64, HH, HH, 8);
    k_convr<<<nblk((long)B*9*HWH), TPB, 0, stream>>>(pbuf3, pb_enc2, maskHH, B, 9, HWH, 8);
    // 4-5. mh_init, ch = 2*ch0 - carafe3(ch0)
    k_knorm<3><<<nblk((long)B*HWH), TPB, 0, stream>>>(maskHH, tmp9, nullptr, B, HH, HH, flag);
    k_carafe3c_ws<<<nblk((long)B*8*16384), TPB, 0, stream>>>(ch0, tmp9, chn, B);
    // 6. mask_lr_hr: 8 chunks x CS8, co-split x5 (grid.y = 40)
    k_conv3x3p<25,5><<<dim3(nblk((long)B*HWH),40), TPB, 0, stream>>>(chn, pw_enc, pbuf6, B, 64, HH, HH, 8);
    k_convr<<<nblk((long)B*25*HWH), TPB, 0, stream>>>(pbuf6, pb_enc, m25a, B, 25, HWH, 8);
    // 7. ml_init -> m25b
    k_knorm<5><<<nblk((long)B*HWH), TPB, 0, stream>>>(m25a, m25b, nullptr, B, HH, HH, flag);
    // 8. enccl: 16 chunks x CS4, co-split x5 (grid.y = 80)
    k_conv3x3p<25,5><<<dim3(nblk((long)B*HWL),80), TPB, 0, stream>>>(clb, pw_enc, pbufL8, B, 64, HL, HL, 4);
    k_convr<<<nblk((long)B*25*HWL), TPB, 0, stream>>>(pbufL8, pb_enc, enccl, B, 25, HWL, 16);
    // 9. mask_lr = mask_lr_hr + carafe5(enccl, ml_init): C=25, CG=5
    k_carafe5_ws<5><<<nblk((long)B*5*16384), TPB, 0, stream>>>(enccl, m25b, m25a, m25c, B, 25);
    // 10. mask_lr_n -> m25a + bf16 output 0
    k_knorm<5><<<nblk((long)B*HWH), TPB, 0, stream>>>(m25c, m25a, d_out, B, HH, HH, flag);
    // 11. enc2cl: 16 chunks x CS4, co-split x3 (grid.y = 48)
    k_conv3x3p<9,3><<<dim3(nblk((long)B*HWL),48), TPB, 0, stream>>>(clb, pw_enc2, pbufL8, B, 64, HL, HL, 4);
    k_convr<<<nblk((long)B*9*HWL), TPB, 0, stream>>>(pbufL8, pb_enc2, enc2cl, B, 9, HWL, 16);
    // 12. mask_hr = mask_hr_hr + carafe5(enc2cl, mask_lr_n): C=9, CG=3
    k_carafe5_ws<3><<<nblk((long)B*3*16384), TPB, 0, stream>>>(enc2cl, m25a, maskHH, maskH, B, 9);
    // 13-14. mask_hr_n, hr_out -> output 1
    k_knorm<3><<<nblk((long)B*HWH), TPB, 0, stream>>>(maskH, tmp9, nullptr, B, HH, HH, flag);
    k_carafe3c_io<<<nblk((long)B*32*16384), TPB, 0, stream>>>(hr_feat, tmp9, d_out, out1Off, B, flag);
    // 15. lr_up (transposed): wave=(b,ipix), lane=4-channel group; XCD-swizzled
    k_carafe5T<<<B*4096/4, TPB, 0, stream>>>(lrfT, m25a, lrupT, B);
    // 16-17. group norms
    k_gnstat<<<16*32, TPB, 0, stream>>>(chn, stat, 0, 32, 8*HWH);
    k_gnapply<<<nblk((long)B*64*HWH), TPB, 0, stream>>>(chn, stat, 0, pgnhw, pgnhb, hrx, 8, 8, HWH, B);
    k_gnstat<<<16*8, TPB, 0, stream>>>(clb, stat, 32, 8, 8*HWL);
    k_gnapply<<<nblk((long)B*64*HWL), TPB, 0, stream>>>(clb, stat, 32, pgnlw, pgnlb, lrx, 8, 8, HWL, B);
    // 18. hrsim: 8 chunks x CS8
    k_simp<<<dim3(nblk((long)B*HWH),8), TPB, 0, stream>>>(hrx, pbufT, B, HH, HH, 8);
    k_simr<<<nblk((long)B*HWH), TPB, 0, stream>>>(pbufT, hrsim, B, HWH, 8);
    // 19. lrsim: 16 chunks x CS4
    k_simp<<<dim3(nblk((long)B*HWL),16), TPB, 0, stream>>>(lrx, pbufT, B, HL, HL, 4);
    k_simr<<<nblk((long)B*HWL), TPB, 0, stream>>>(pbufT, lrsim, B, HWL, 16);
    // 20. qhro: 4 chunks x CS2, co-split x2 (grid.y = 8)
    k_conv3x3p<8,4><<<dim3(nblk((long)B*HWH),8), TPB, 0, stream>>>(hrsim, pw_hoff, pbufT, B, 8, HH, HH, 2);
    k_convr<<<nblk((long)B*8*HWH), TPB, 0, stream>>>(pbufT, pb_hoff, qhro, B, 8, HWH, 4);
    // 21. qlro: 8 chunks x CS1, co-split x4 (grid.y = 32)
    k_conv3x3p<32,8><<<dim3(nblk((long)B*HWL),32), TPB, 0, stream>>>(lrsim, pw_off, pbufT, B, 8, HL, HL, 1);
    k_convr<<<nblk((long)B*32*HWL), TPB, 0, stream>>>(pbufT, pb_off, qlro, B, 32, HWL, 8);
    // 22. qhrd: 8 chunks x CS8, co-split x2 (grid.y = 16)
    k_conv3x3p<8,4><<<dim3(nblk((long)B*HWH),16), TPB, 0, stream>>>(hrx, pw_hds, pbufT, B, 64, HH, HH, 8);
    k_convr<<<nblk((long)B*8*HWH), TPB, 0, stream>>>(pbufT, pb_hds, qhrd, B, 8, HWH, 8);
    // 23. qlrd: 16 chunks x CS4, co-split x4 (grid.y = 64)
    k_conv3x3p<32,8><<<dim3(nblk((long)B*HWL),64), TPB, 0, stream>>>(lrx, pw_ds, pbufT, B, 64, HL, HL, 4);
    k_convr<<<nblk((long)B*32*HWL), TPB, 0, stream>>>(pbufT, pb_ds, qlrd, B, 32, HWL, 16);
    // 24. offset assembly
    k_offset<<<nblk((long)B*32*HWL), TPB, 0, stream>>>(qlro, qhro, qlrd, qhrd, offb, B);
    // 25. grid sample from lrupT -> output 2 (2 channel halves)
    k_gridsampleT<<<dim3(nblk((long)B*4*HWH),2), TPB, 0, stream>>>(lrupT, offb, d_out, out2Off, B, flag);
}